// Round 9
// baseline (931.634 us; speedup 1.0000x reference)
//
#include <hip/hip_runtime.h>
#include <hip/hip_bf16.h>
#include <math.h>

#define TPB 256
typedef __hip_bfloat16 bf16;
typedef short bf16x8 __attribute__((ext_vector_type(8)));   // 8 bf16 (4 VGPRs)
typedef float f32x4 __attribute__((ext_vector_type(4)));

// ---------------- ws layout constants (fp32-element offsets from fw) -------
constexpr long BIASF  = 0;          // 1715 packed fp32 biases (pad to 2048)
constexpr long RB1W1T = 2048;       // res weights bf16 [9][256co][256ci]
constexpr long RB1W2T = 591872;
constexpr long RB2W1T = 1181696;
constexpr long RB2W2T = 1771520;
constexpr long FB     = 2361344;    // multi-use region
constexpr long WB1OT  = 2361344;    // bf16 [160][160] off1 weights (16B aligned)
constexpr long WB1DT  = 2382956;    // bf16 [64][160] dcn1 weights (16B aligned)
constexpr long WO2T   = 2392364;    // bf16 [64co pad][1024] off2 weights
constexpr long WB2T   = 2441516;    // bf16 [128co][1024] deform2 weights (16B aligned)
constexpr long WO3T   = 2572588;    // bf16 [64co pad][2048] off3 weights
constexpr long WB3T   = 2670892;    // bf16 [256co][2048] deform3 weights (16B aligned)
constexpr long OFFB   = 3221504;    // offsets layers 2/3; x4 during layer 1
constexpr long H3F    = 4458496;    // h3 bf16 channels-last, 1048576 floats
constexpr long PSUM   = 5507072;    // IN mean   [2][256] (finalized)
constexpr long PSQ    = 5515264;    // IN rsqrt  [2][256] (finalized)
constexpr long CLBUF  = 5523456;    // channels-last bf16 skip1/skip2 (<=2097152 f)
constexpr long PPART  = 7620608;    // IN partial sums  [4096][32] (dead space)
constexpr long QPART  = 7751680;    // IN partial sumsq [4096][32]
// bias sub-offsets
constexpr long OFF1B = 0,   DCN1B = 147;
constexpr long OFF2B = 211, DCN2B = 259;
constexpr long OFF3B = 387, DCN3B = 435;
constexpr long RB1B1 = 691, RB1B2 = 947;
constexpr long RB2B1 = 1203, RB2B2 = 1459;

// ---- compile-time dtype accessors (BF=1: bf16, BF=0: fp32) ----------------
template<int BF>
__device__ __forceinline__ float ldT(const void* p, long i) {
    if (BF) {
        unsigned short h = ((const unsigned short*)p)[i];
        return __uint_as_float(((unsigned int)h) << 16);
    }
    return ((const float*)p)[i];
}
template<int BF>
__device__ __forceinline__ void stT(void* p, long i, float v) {
    if (BF) ((bf16*)p)[i] = __float2bfloat16(v);
    else    ((float*)p)[i] = v;
}
__device__ __forceinline__ float bitsToF(unsigned short h) {
    return __uint_as_float(((unsigned int)h) << 16);
}
__device__ __forceinline__ unsigned short fToBits(float v) {
    bf16 h = __float2bfloat16(v);
    return *(unsigned short*)&h;
}

// ---- dtype detector (validated rounds 3-9) --------------------------------
__global__ void detect_kernel(const void* __restrict__ x, int* __restrict__ flag) {
    if (threadIdx.x == 0 && blockIdx.x == 0) {
        const unsigned short* u = (const unsigned short*)x;
        int sane = 0;
        for (int i = 0; i < 256; ++i) {
            float v = bitsToF(u[i]);
            float a = fabsf(v);
            if (a > 0.0009f && a < 1100.f) ++sane;
        }
        *flag = (sane >= 224) ? 1 : 0;
    }
}

// ===========================================================================
// Repack: biases -> packed fp32 (grid 2).
// ===========================================================================
struct PtrPack { const void* p[20]; };   // p[10..19]=biases

template<int BF>
__device__ void repack_all_body(PtrPack pp, float* __restrict__ fw)
{
    constexpr int  bcum  [11] = {0,147,211,259,387,435,691,947,1203,1459,1715};
    int j0 = blockIdx.x * 1024 + threadIdx.x * 4;
    #pragma unroll
    for (int q = 0; q < 4; ++q) {
        int j = j0 + q;
        if (j < 1715) {
            int v = 0;
            #pragma unroll
            for (int s = 1; s < 10; ++s) if (j >= bcum[s]) v = s;
            fw[BIASF + j] = ldT<BF>(pp.p[10 + v], j - bcum[v]);
        }
    }
}
__global__ __launch_bounds__(TPB) void repack_all_kernel(
    PtrPack pp, float* fw, const int* dflag) {
    if (*dflag) repack_all_body<1>(pp, fw);
    else        repack_all_body<0>(pp, fw);
}

// ---- conv weights -> bf16 [co][k*CIN+ci] (dst-contiguous writes) ----------
__global__ __launch_bounds__(TPB) void repack_dcn_kernel(
    const void* __restrict__ w2, const void* __restrict__ w3,
    const void* __restrict__ w1o, const void* __restrict__ w1d,
    const void* __restrict__ w2o, const void* __restrict__ w3o,
    float* __restrict__ fw, const int* __restrict__ dflag)
{
    int bf = *dflag;
    unsigned short* wb2 = (unsigned short*)(fw + WB2T);
    unsigned short* wb3 = (unsigned short*)(fw + WB3T);
    unsigned short* wb1o = (unsigned short*)(fw + WB1OT);
    unsigned short* wb1d = (unsigned short*)(fw + WB1DT);
    unsigned short* wb2o = (unsigned short*)(fw + WO2T);
    unsigned short* wb3o = (unsigned short*)(fw + WO3T);
    int b = blockIdx.x;
    if (b < 128) {                              // dcn2: 131072 = 128 blocks
        int e0 = b * 1024 + threadIdx.x * 4;
        #pragma unroll
        for (int j = 0; j < 4; ++j) {
            int e = e0 + j;
            int co = e >> 10, rem = e & 1023, k = rem >> 6, ci = rem & 63;
            long si = ((long)(co * 64 + ci)) * 16 + k;
            float v = bf ? ldT<1>(w2, si) : ldT<0>(w2, si);
            wb2[e] = fToBits(v);
        }
    } else if (b < 640) {                       // dcn3: 524288 = 512 blocks
        int e0 = (b - 128) * 1024 + threadIdx.x * 4;
        #pragma unroll
        for (int j = 0; j < 4; ++j) {
            int e = e0 + j;
            int co = e >> 11, rem = e & 2047, k = rem >> 7, ci = rem & 127;
            long si = ((long)(co * 128 + ci)) * 16 + k;
            float v = bf ? ldT<1>(w3, si) : ldT<0>(w3, si);
            wb3[e] = fToBits(v);
        }
    } else if (b < 665) {                       // off1: 160x160 = 25 blocks
        int e0 = (b - 640) * 1024 + threadIdx.x * 4;
        #pragma unroll
        for (int j = 0; j < 4; ++j) {
            int e = e0 + j;
            int co = e / 160, k = e - co * 160;
            float v = 0.f;
            if (co < 147 && k < 147) {
                long si = (long)co * 147 + k;
                v = bf ? ldT<1>(w1o, si) : ldT<0>(w1o, si);
            }
            wb1o[e] = fToBits(v);
        }
    } else if (b < 675) {                       // dcn1: 64x160 = 10 blocks
        int e0 = (b - 665) * 1024 + threadIdx.x * 4;
        #pragma unroll
        for (int j = 0; j < 4; ++j) {
            int e = e0 + j;
            int co = e / 160, k = e - co * 160;
            float v = 0.f;
            if (k < 147) {
                long si = (long)co * 147 + k;
                v = bf ? ldT<1>(w1d, si) : ldT<0>(w1d, si);
            }
            wb1d[e] = fToBits(v);
        }
    } else if (b < 739) {                       // off2 pad64: 65536 = 64 blocks
        int e0 = (b - 675) * 1024 + threadIdx.x * 4;
        #pragma unroll
        for (int j = 0; j < 4; ++j) {
            int e = e0 + j;
            int co = e >> 10, rem = e & 1023, k = rem >> 6, ci = rem & 63;
            float v = 0.f;
            if (co < 48) {
                long si = ((long)(co * 64 + ci)) * 16 + k;
                v = bf ? ldT<1>(w2o, si) : ldT<0>(w2o, si);
            }
            wb2o[e] = fToBits(v);
        }
    } else {                                    // off3 pad64: 131072 = 128 blocks
        int e0 = (b - 739) * 1024 + threadIdx.x * 4;
        #pragma unroll
        for (int j = 0; j < 4; ++j) {
            int e = e0 + j;
            int co = e >> 11, rem = e & 2047, k = rem >> 7, ci = rem & 127;
            float v = 0.f;
            if (co < 48) {
                long si = ((long)(co * 128 + ci)) * 16 + k;
                v = bf ? ldT<1>(w3o, si) : ldT<0>(w3o, si);
            }
            wb3o[e] = fToBits(v);
        }
    }
}

// ---- res weights: src[co][ci*9+q] (flag dtype) -> bf16 [q][co][ci] --------
struct RbPack { const void* src[4]; };
__global__ __launch_bounds__(TPB) void repack_rb_kernel(
    RbPack rp, float* fw, const int* dflag)
{
    __shared__ unsigned short lw[4 * 2304];
    int b = blockIdx.x;
    int ten = b >> 6;
    int co0 = (b & 63) * 4;
    const void* src = rp.src[ten];
    const long dstOff[4] = {RB1W1T, RB1W2T, RB2W1T, RB2W2T};
    unsigned short* dst = (unsigned short*)(fw + dstOff[ten]);
    int bf = *dflag;
    int t = threadIdx.x;
    for (int e = t; e < 4 * 2304; e += TPB) {
        int coL = e / 2304, i = e - coL * 2304;
        long si = (long)(co0 + coL) * 2304 + i;
        float v = bf ? ldT<1>(src, si) : ldT<0>(src, si);
        lw[e] = fToBits(v);
    }
    __syncthreads();
    for (int e = t; e < 9216; e += TPB) {     // 9216 = 9q * 4co * 256ci
        int ci = e & 255, coL = (e >> 8) & 3, q = e >> 10;
        dst[((long)q * 256 + co0 + coL) * 256 + ci] = lw[coL * 2304 + ci * 9 + q];
    }
}

// ===========================================================================
// x (NCHW flag dtype, 3ch) -> x4 bf16 [n][256][256][4] (ch 3 = 0 pad).
// ===========================================================================
template<int BF>
__device__ void x_to_cl4_body(const void* __restrict__ x, unsigned short* __restrict__ x4)
{
    long gid = (long)blockIdx.x * TPB + threadIdx.x;   // 0..131071
    int n = (int)(gid >> 16); int p = (int)(gid & 65535);
    long xb = (long)n * 3 * 65536 + p;
    unsigned c0 = fToBits(ldT<BF>(x, xb));
    unsigned c1 = fToBits(ldT<BF>(x, xb + 65536));
    unsigned c2 = fToBits(ldT<BF>(x, xb + 131072));
    uint2 v; v.x = c0 | (c1 << 16); v.y = c2;
    *(uint2*)&x4[gid * 4] = v;
}
__global__ __launch_bounds__(TPB) void x_to_cl4_kernel(
    const void* x, unsigned short* x4, const int* dflag)
{
    if (*dflag) x_to_cl4_body<1>(x, x4);
    else        x_to_cl4_body<0>(x, x4);
}

// ===========================================================================
// MFMA fused layer 1 v4 (validated round 8)
// ===========================================================================
template<int BF>
__device__ void layer1_mfma_body(
    const unsigned short* __restrict__ x4all, const unsigned short* __restrict__ wo,
    const unsigned short* __restrict__ wd, const float* __restrict__ bias1,
    const float* __restrict__ bias2, void* __restrict__ out, long obase,
    float* xs, unsigned short* A, float* offs)
{
    int b = blockIdx.x;
    int n = b >> 11;
    int ho = (b >> 3) & 255;
    int wo0 = (b & 7) << 5;
    const unsigned short* x4 = x4all + ((long)n << 16) * 4;
    int t = threadIdx.x;

    // ---- phase 1a: stage x patch [3ci][7ky][40 cols] from x4 (8B loads) --
    for (int e = t; e < 7 * 40; e += TPB) {
        int cc = e % 40, rr = e / 40;
        int yy = ho - 3 + rr; int xx = wo0 - 3 + cc;
        float c0 = 0.f, c1 = 0.f, c2 = 0.f;
        if (cc < 38 && yy >= 0 && yy < 256 && xx >= 0 && xx < 256) {
            uint2 v = *(const uint2*)&x4[((long)yy * 256 + xx) * 4];
            c0 = bitsToF((unsigned short)(v.x & 0xffff));
            c1 = bitsToF((unsigned short)(v.x >> 16));
            c2 = bitsToF((unsigned short)(v.y & 0xffff));
        }
        xs[(0 * 7 + rr) * 40 + cc] = c0;
        xs[(1 * 7 + rr) * 40 + cc] = c1;
        xs[(2 * 7 + rr) * 40 + cc] = c2;
    }
    __syncthreads();

    // ---- phase 1b: im2col -> A[kc][m][32] bf16, k = ci*49+ky*7+kx --------
    for (int e = t; e < 5120; e += TPB) {
        int kin = e & 31, m = (e >> 5) & 31, kc = e >> 10;
        int k = kc * 32 + kin;
        float v = 0.f;
        if (k < 147) {
            int ci = k / 49, q = k - ci * 49;
            int ky = q / 7, kx = q - ky * 7;
            v = xs[(ci * 7 + ky) * 40 + m + kx];
        }
        A[kc * 1024 + m * 32 + kin] = fToBits(v);
    }
    __syncthreads();

    int wv = t >> 6, lane = t & 63;
    int quad = lane >> 4, l16 = lane & 15;
    int mt = wv & 1, ntb = wv >> 1;

    // ---- phase 2: MFMA offset conv (N=160, 10 n-tiles over 2 wave-groups)-
    {
        f32x4 acc[5];
        #pragma unroll
        for (int j = 0; j < 5; ++j) acc[j] = (f32x4){0.f, 0.f, 0.f, 0.f};
        #pragma unroll
        for (int kc = 0; kc < 5; ++kc) {
            bf16x8 a = *(const bf16x8*)&A[(kc * 32 + mt * 16 + l16) * 32 + quad * 8];
            #pragma unroll
            for (int j = 0; j < 5; ++j) {
                int ch = (ntb + 2 * j) * 16 + l16;
                bf16x8 bw = *(const bf16x8*)&wo[ch * 160 + kc * 32 + quad * 8];
                acc[j] = __builtin_amdgcn_mfma_f32_16x16x32_bf16(a, bw, acc[j], 0, 0, 0);
            }
        }
        #pragma unroll
        for (int j = 0; j < 5; ++j) {
            int ch = (ntb + 2 * j) * 16 + l16;
            if (ch < 147) {
                float bv = bias1[ch];
                #pragma unroll
                for (int reg = 0; reg < 4; ++reg) {
                    int m = mt * 16 + quad * 4 + reg;
                    offs[ch * 33 + m] = acc[j][reg] + bv;
                }
            }
        }
    }
    __syncthreads();

    // ---- phase 3: p in lane (coalesced 8B taps); in-place sample write ----
    for (int e = t; e < 49 * 32; e += TPB) {
        int p = e & 31; int k = e >> 5;
        float oy = offs[k * 33 + p];
        float ox = offs[(49 + k) * 33 + p];
        float mr = offs[(98 + k) * 33 + p];
        float m = 1.f / (1.f + expf(-mr));
        float py = (float)(ho - 3 + k / 7) + oy;
        float px = (float)(wo0 + p - 3 + k % 7) + ox;
        float y0f = floorf(py), x0f = floorf(px);
        float wy = py - y0f, wx = px - x0f;
        int y0 = (int)y0f, x0 = (int)x0f;
        bool yv0 = (y0 >= 0) && (y0 < 256);
        bool yv1 = (y0 + 1 >= 0) && (y0 + 1 < 256);
        bool xv0 = (x0 >= 0) && (x0 < 256);
        bool xv1 = (x0 + 1 >= 0) && (x0 + 1 < 256);
        int y0c = min(max(y0, 0), 255), y1c = min(max(y0 + 1, 0), 255);
        int x0c = min(max(x0, 0), 255), x1c = min(max(x0 + 1, 0), 255);
        float w00 = (yv0 && xv0) ? (1.f - wy) * (1.f - wx) * m : 0.f;
        float w01 = (yv0 && xv1) ? (1.f - wy) * wx * m : 0.f;
        float w10 = (yv1 && xv0) ? wy * (1.f - wx) * m : 0.f;
        float w11 = (yv1 && xv1) ? wy * wx * m : 0.f;
        uint2 a00 = *(const uint2*)&x4[((long)y0c * 256 + x0c) * 4];
        uint2 a01 = *(const uint2*)&x4[((long)y0c * 256 + x1c) * 4];
        uint2 a10 = *(const uint2*)&x4[((long)y1c * 256 + x0c) * 4];
        uint2 a11 = *(const uint2*)&x4[((long)y1c * 256 + x1c) * 4];
        float s0 = w00 * bitsToF((unsigned short)(a00.x & 0xffff))
                 + w01 * bitsToF((unsigned short)(a01.x & 0xffff))
                 + w10 * bitsToF((unsigned short)(a10.x & 0xffff))
                 + w11 * bitsToF((unsigned short)(a11.x & 0xffff));
        float s1 = w00 * bitsToF((unsigned short)(a00.x >> 16))
                 + w01 * bitsToF((unsigned short)(a01.x >> 16))
                 + w10 * bitsToF((unsigned short)(a10.x >> 16))
                 + w11 * bitsToF((unsigned short)(a11.x >> 16));
        float s2 = w00 * bitsToF((unsigned short)(a00.y & 0xffff))
                 + w01 * bitsToF((unsigned short)(a01.y & 0xffff))
                 + w10 * bitsToF((unsigned short)(a10.y & 0xffff))
                 + w11 * bitsToF((unsigned short)(a11.y & 0xffff));
        offs[k * 33 + p] = s0;               // in-place, thread-local RAW
        offs[(49 + k) * 33 + p] = s1;
        offs[(98 + k) * 33 + p] = s2;
    }
    __syncthreads();

    // ---- phase 3.5: repack offs(f32) -> A(bf16 MFMA layout) --------------
    for (int e = t; e < 5120; e += TPB) {
        int kin = e & 31, m = (e >> 5) & 31, kc = e >> 10;
        int k = kc * 32 + kin;
        float v = 0.f;
        if (k < 147) v = offs[k * 33 + m];
        A[kc * 1024 + m * 32 + kin] = fToBits(v);
    }
    __syncthreads();

    // ---- phase 4: MFMA deform conv (N=64, 4 n-tiles) ---------------------
    f32x4 acc2[2];
    acc2[0] = (f32x4){0.f, 0.f, 0.f, 0.f};
    acc2[1] = (f32x4){0.f, 0.f, 0.f, 0.f};
    #pragma unroll
    for (int kc = 0; kc < 5; ++kc) {
        bf16x8 a = *(const bf16x8*)&A[(kc * 32 + mt * 16 + l16) * 32 + quad * 8];
        #pragma unroll
        for (int j = 0; j < 2; ++j) {
            int co = (ntb + 2 * j) * 16 + l16;
            bf16x8 bw = *(const bf16x8*)&wd[co * 160 + kc * 32 + quad * 8];
            acc2[j] = __builtin_amdgcn_mfma_f32_16x16x32_bf16(a, bw, acc2[j], 0, 0, 0);
        }
    }
    #pragma unroll
    for (int j = 0; j < 2; ++j) {
        int co = (ntb + 2 * j) * 16 + l16;
        float bv = bias2[co];
        #pragma unroll
        for (int reg = 0; reg < 4; ++reg) {
            int wox = wo0 + mt * 16 + quad * 4 + reg;
            long oi = obase + ((long)(n * 64 + co) * 256 + ho) * 256 + wox;
            stT<BF>(out, oi, acc2[j][reg] + bv);
        }
    }
}

__global__ __launch_bounds__(TPB) void layer1_mfma_kernel(
    const unsigned short* x4, const unsigned short* wo, const unsigned short* wd,
    const float* bias1, const float* bias2, void* out, long obase, const int* dflag)
{
    __shared__ __align__(16) float xs[3 * 7 * 40];
    __shared__ __align__(16) unsigned short A[5120];
    __shared__ __align__(16) float offs[147 * 33];
    if (*dflag) layer1_mfma_body<1>(x4, wo, wd, bias1, bias2, out, obase, xs, A, offs);
    else        layer1_mfma_body<0>(x4, wo, wd, bias1, bias2, out, obase, xs, A, offs);
}

// ===========================================================================
// MFMA offset conv (layers 2/3) — validated round 3.
// ===========================================================================
template<int CIN, int HH, int WW, int HO, int WO>
__global__ __launch_bounds__(TPB) void offconv_mfma_kernel(
    const unsigned short* __restrict__ xcl, const unsigned short* __restrict__ wb,
    const float* __restrict__ bias_f, float* __restrict__ out)
{
    constexpr int S   = 16 * CIN;
    constexpr int KL  = 512 / CIN;       // taps per 512-i chunk
    constexpr int NCH = 16 / KL;
    constexpr int PAIRS_W = (KL * 16) / 4;
    constexpr int TILES = (HO * WO) / 16;

    __shared__ int tp[256];
    __shared__ __align__(16) unsigned short smp[16 * 512];

    int tile = blockIdx.x % TILES;
    int n    = blockIdx.x / TILES;
    int lp0  = tile * 16;

    // ---- fixed-tap address table: one (k,p) per thread ----
    {
        int pr = threadIdx.x;
        int k = pr >> 4, p = pr & 15;
        int lp = lp0 + p;
        int ho = lp / WO, wo = lp - ho * WO;
        int yy = ho * 2 - 1 + (k >> 2);
        int xx = wo * 2 - 1 + (k & 3);
        bool valid = (yy >= 0) && (yy < HH) && (xx >= 0) && (xx < WW);
        tp[pr] = valid ? (yy * WW + xx) * CIN : -1;
    }

    int wv = threadIdx.x >> 6, lane = threadIdx.x & 63;
    int quad = lane >> 4, l16 = lane & 15;
    const unsigned short* xn = xcl + (long)n * HH * WW * CIN;

    f32x4 acc = (f32x4){0.f, 0.f, 0.f, 0.f};

    for (int ch = 0; ch < NCH; ++ch) {
        __syncthreads();
        #pragma unroll 4
        for (int u = 0; u < PAIRS_W; ++u) {
            int prl = wv * PAIRS_W + u;
            int pi  = ch * (KL * 16) + prl;
            int kl = prl >> 4, p = prl & 15;
            int t0 = tp[pi];
            #pragma unroll
            for (int cg = 0; cg < CIN / 64; ++cg) {
                int ci = cg * 64 + lane;
                unsigned short v = (t0 >= 0) ? xn[t0 + ci] : (unsigned short)0;
                int il = kl * CIN + ci;
                smp[((il >> 5) * 16 + p) * 32 + (il & 31)] = v;
            }
        }
        __syncthreads();
        #pragma unroll 4
        for (int kk = 0; kk < 16; ++kk) {
            bf16x8 a = *(const bf16x8*)&smp[(kk * 16 + l16) * 32 + quad * 8];
            int co = wv * 16 + l16;
            bf16x8 b = *(const bf16x8*)&wb[(long)co * S + ch * 512 + kk * 32 + quad * 8];
            acc = __builtin_amdgcn_mfma_f32_16x16x32_bf16(a, b, acc, 0, 0, 0);
        }
    }

    int co = wv * 16 + l16;
    if (co < 48) {
        float bv = bias_f[co];
        #pragma unroll
        for (int reg = 0; reg < 4; ++reg) {
            int lp = lp0 + quad * 4 + reg;
            int ho = lp / WO, wo = lp - ho * WO;
            out[((long)(n * 48 + co) * HO + ho) * WO + wo] = acc[reg] + bv;
        }
    }
}

// ===========================================================================
// NCHW (flag dtype) -> channels-last bf16 transpose. 64 pixels x C per block.
// ===========================================================================
template<int C>
__global__ __launch_bounds__(TPB) void nchw_to_cl_kernel(
    const void* __restrict__ in, long ibase, unsigned short* __restrict__ out,
    int HW, const int* __restrict__ dflag)
{
    __shared__ unsigned short tile[C * 65];
    int bf = *dflag;
    int n   = (blockIdx.x * 64) / HW;
    int px0 = (blockIdx.x * 64) % HW;
    for (int e = threadIdx.x; e < C * 64; e += TPB) {
        int c = e >> 6, p = e & 63;
        long si = ibase + (long)(n * C + c) * HW + px0 + p;
        float v = bf ? ldT<1>(in, si) : ldT<0>(in, si);
        tile[c * 65 + p] = fToBits(v);
    }
    __syncthreads();
    for (int e = threadIdx.x; e < C * 64; e += TPB) {
        int p = e / C, c = e - p * C;
        out[((long)n * HW + px0 + p) * C + c] = tile[c * 65 + p];
    }
}

// ===========================================================================
// MFMA deformable conv v3 (layers 2/3). MODE==1 additionally emits per-wave
// IN partial sums (fused stats; kills the separate cl_stats pass).
// ===========================================================================
template<int MODE, int CIN, int COUT, int NWAVES, int HH, int WW, int HO, int WO>
__global__ __launch_bounds__(NWAVES * 64) void deform_mfma_kernel(
    const unsigned short* __restrict__ xcl, const float* __restrict__ off,
    const unsigned short* __restrict__ wb, const float* __restrict__ bias_f,
    void* __restrict__ outp, long obase, const int* __restrict__ dflag,
    float* __restrict__ P, float* __restrict__ Q)
{
    constexpr int TPBk = NWAVES * 64;
    constexpr int S    = 16 * CIN;       // reduction length
    constexpr int KL   = 512 / CIN;      // kernel-points per 512-i chunk
    constexpr int NCH  = 16 / KL;        // chunks
    constexpr int CH2  = CIN / 2;        // 4B units per (pair, tap)
    constexpr int ITER = (KL * 16 * CH2) / TPBk;   // 4B units per thread/chunk
    constexpr int TILES = (HO * WO) / 16;

    __shared__ __align__(16) int tpw[256][8];      // [pair]{tp0..3, w0..3bits}
    __shared__ __align__(16) unsigned short smp[16 * 512];

    int tile = blockIdx.x % TILES;
    int n    = blockIdx.x / TILES;
    int lp0  = tile * 16;
    int tid  = threadIdx.x;

    // ---- phase A: per-(k,p) offset decode, one pair per thread (first 256)-
    if (tid < 256) {
        int pr = tid;
        int k = pr >> 4, p = pr & 15;
        int lp = lp0 + p;
        int ho = lp / WO, wo = lp - ho * WO;
        long plane = (long)HO * WO;
        const float* offn = off + (long)n * 48 * plane;
        float oy = offn[(long)k * plane + lp];
        float ox = offn[(long)(16 + k) * plane + lp];
        float mr = offn[(long)(32 + k) * plane + lp];
        float m = 1.f / (1.f + expf(-mr));
        float py = (float)(ho * 2 - 1 + (k >> 2)) + oy;
        float px = (float)(wo * 2 - 1 + (k & 3)) + ox;
        float y0f = floorf(py), x0f = floorf(px);
        float wy = py - y0f, wx = px - x0f;
        int y0 = (int)y0f, x0 = (int)x0f;
        bool yv0 = (y0 >= 0) && (y0 < HH);
        bool yv1 = (y0 + 1 >= 0) && (y0 + 1 < HH);
        bool xv0 = (x0 >= 0) && (x0 < WW);
        bool xv1 = (x0 + 1 >= 0) && (x0 + 1 < WW);
        int y0c = min(max(y0, 0), HH - 1), y1c = min(max(y0 + 1, 0), HH - 1);
        int x0c = min(max(x0, 0), WW - 1), x1c = min(max(x0 + 1, 0), WW - 1);
        tpw[pr][0] = (y0c * WW + x0c) * CIN;
        tpw[pr][1] = (y0c * WW + x1c) * CIN;
        tpw[pr][2] = (y1c * WW + x0c) * CIN;
        tpw[pr][3] = (y1c * WW + x1c) * CIN;
        tpw[pr][4] = __float_as_int((yv0 && xv0) ? (1.f - wy) * (1.f - wx) * m : 0.f);
        tpw[pr][5] = __float_as_int((yv0 && xv1) ? (1.f - wy) * wx * m : 0.f);
        tpw[pr][6] = __float_as_int((yv1 && xv0) ? wy * (1.f - wx) * m : 0.f);
        tpw[pr][7] = __float_as_int((yv1 && xv1) ? wy * wx * m : 0.f);
    }

    int wv = tid >> 6, lane = tid & 63;
    int quad = lane >> 4, l16 = lane & 15;
    int cb = (wv & 3) * 32 + (wv >> 2) * (COUT / 2);
    const unsigned short* xn = xcl + (long)n * HH * WW * CIN;

    f32x4 acc[2];
    acc[0] = (f32x4){0.f, 0.f, 0.f, 0.f};
    acc[1] = (f32x4){0.f, 0.f, 0.f, 0.f};

    for (int ch = 0; ch < NCH; ++ch) {
        __syncthreads();   // covers phase A (ch=0) and prev MFMA reads
        #pragma unroll 4
        for (int it = 0; it < ITER; ++it) {
            int e   = it * TPBk + tid;
            int prl = e / CH2;                  // pair within chunk
            int ci  = (e - prl * CH2) * 2;      // even ci
            int pi  = ch * (KL * 16) + prl;
            const int4   tp4 = *(const int4*)&tpw[pi][0];
            const float4 tw4 = *(const float4*)&tpw[pi][4];
            unsigned v0 = *(const unsigned*)(xn + tp4.x + ci);
            unsigned v1 = *(const unsigned*)(xn + tp4.y + ci);
            unsigned v2 = *(const unsigned*)(xn + tp4.z + ci);
            unsigned v3 = *(const unsigned*)(xn + tp4.w + ci);
            float r0 = tw4.x * bitsToF((unsigned short)(v0 & 0xffff))
                     + tw4.y * bitsToF((unsigned short)(v1 & 0xffff))
                     + tw4.z * bitsToF((unsigned short)(v2 & 0xffff))
                     + tw4.w * bitsToF((unsigned short)(v3 & 0xffff));
            float r1 = tw4.x * bitsToF((unsigned short)(v0 >> 16))
                     + tw4.y * bitsToF((unsigned short)(v1 >> 16))
                     + tw4.z * bitsToF((unsigned short)(v2 >> 16))
                     + tw4.w * bitsToF((unsigned short)(v3 >> 16));
            unsigned ov = (unsigned)fToBits(r0) | ((unsigned)fToBits(r1) << 16);
            int il = (prl >> 4) * CIN + ci;     // i within chunk [0,512)
            int p  = prl & 15;
            *(unsigned*)&smp[((il >> 5) * 16 + p) * 32 + (il & 31)] = ov;
        }
        __syncthreads();
        #pragma unroll 4
        for (int kk = 0; kk < 16; ++kk) {
            bf16x8 a = *(const bf16x8*)&smp[(kk * 16 + l16) * 32 + quad * 8];
            #pragma unroll
            for (int f = 0; f < 2; ++f) {
                int co = cb + f * 16 + l16;
                bf16x8 b = *(const bf16x8*)&wb[(long)co * S + ch * 512 + kk * 32 + quad * 8];
                acc[f] = __builtin_amdgcn_mfma_f32_16x16x32_bf16(a, b, acc[f], 0, 0, 0);
            }
        }
    }

    // ---- epilogue: pixel = quad*4+reg, co = cb + f*16 + l16 ----
    if (MODE == 1) {
        unsigned short* oCL = (unsigned short*)outp;
        #pragma unroll
        for (int f = 0; f < 2; ++f) {
            int co = cb + f * 16 + l16;
            float bv = bias_f[co];
            float s = 0.f, q = 0.f;
            #pragma unroll
            for (int reg = 0; reg < 4; ++reg) {
                int lp = lp0 + quad * 4 + reg;
                float v = acc[f][reg] + bv;
                oCL[((long)n * HO * WO + lp) * COUT + co] = fToBits(v);
                s += v; q += v * v;
            }
            s += __shfl_down(s, 16, 64); s += __shfl_down(s, 32, 64);
            q += __shfl_down(q, 16, 64); q += __shfl_down(q, 32, 64);
            if (lane < 16) {
                int row = (int)blockIdx.x * 8 + wv;
                P[row * 32 + f * 16 + l16] = s;
                Q[row * 32 + f * 16 + l16] = q;
            }
        }
    } else {
        int bf = *dflag;
        #pragma unroll
        for (int f = 0; f < 2; ++f) {
            int co = cb + f * 16 + l16;
            float bv = bias_f[co];
            #pragma unroll
            for (int reg = 0; reg < 4; ++reg) {
                int lp = lp0 + quad * 4 + reg;
                int ho = lp / WO, wo = lp - ho * WO;
                long oi = obase + ((long)(n * COUT + co) * HO + ho) * WO + wo;
                if (bf) stT<1>(outp, oi, acc[f][reg] + bv);
                else    stT<0>(outp, oi, acc[f][reg] + bv);
            }
        }
    }
}

// ===========================================================================
// MFMA res-block 3x3 reflect conv v3: fused IN partial sums in epilogue.
// ===========================================================================
__global__ __launch_bounds__(TPB) void resconv_mfma_kernel(
    const unsigned short* __restrict__ X, const unsigned short* __restrict__ W,
    const float* __restrict__ bias_f, bf16* __restrict__ Y,
    float* __restrict__ P, float* __restrict__ Q)
{
    __shared__ __align__(16) unsigned short xs[3 * 66 * 64];   // 25344 B, swizzled
    int b = blockIdx.x;
    int coO = b & 7, r = (b >> 3) & 63, n = b >> 9;
    int t = threadIdx.x;
    int wv = t >> 6;
    int lane = t & 63;
    int quad = lane >> 4, l16 = lane & 15;
    int rows[3];
    rows[0] = (r == 0) ? 1 : r - 1;
    rows[1] = r;
    rows[2] = (r == 63) ? 62 : r + 1;

    f32x4 acc[2];
    acc[0] = (f32x4){0.f, 0.f, 0.f, 0.f};
    acc[1] = (f32x4){0.f, 0.f, 0.f, 0.f};

    long xbase = (long)n * 4096 * 256;

    for (int ci0 = 0; ci0 < 256; ci0 += 64) {
        __syncthreads();
        // stage [3ky][66col][64ci] via 16B loads; swizzled 16B slot per col
        for (int e = t; e < 3 * 66 * 8; e += TPB) {
            int oct = e & 7;
            int col = (e >> 3) % 66;
            int ky  = e / (66 * 8);
            int gx = col - 1;
            gx = (gx < 0) ? 1 : ((gx > 63) ? 62 : gx);
            bf16x8 v = *(const bf16x8*)&X[xbase + ((long)rows[ky] * 64 + gx) * 256 + ci0 + oct * 8];
            int slot = oct ^ (col & 7);
            *(bf16x8*)&xs[((ky * 66 + col) << 6) + slot * 8] = v;
        }
        __syncthreads();
        #pragma unroll
        for (int q = 0; q < 9; ++q) {
            int ky = q / 3, kx = q % 3;
            int col = wv * 16 + l16 + kx;        // lds col = global col +1
            int base = (ky * 66 + col) << 6;
            #pragma unroll
            for (int kh = 0; kh < 2; ++kh) {
                int slot = (kh * 4 + quad) ^ (col & 7);
                bf16x8 a = *(const bf16x8*)&xs[base + slot * 8];
                #pragma unroll
                for (int ct = 0; ct < 2; ++ct) {
                    int co = coO * 32 + ct * 16 + l16;
                    bf16x8 bw = *(const bf16x8*)&W[((long)q * 256 + co) * 256 + ci0 + kh * 32 + quad * 8];
                    acc[ct] = __builtin_amdgcn_mfma_f32_16x16x32_bf16(a, bw, acc[ct], 0, 0, 0);
                }
            }
        }
    }

    long ybase = ((long)n * 4096 + (long)r * 64) * 256;
    #pragma unroll
    for (int ct = 0; ct < 2; ++ct) {
        int co = coO * 32 + ct * 16 + l16;
        float bv = bias_f[co];
        float s = 0.f, q = 0.f;
        #pragma unroll
        for (int reg = 0; reg < 4; ++reg) {
            int px = wv * 16 + quad * 4 + reg;
            float v = acc[ct][reg] + bv;
            Y[ybase + (long)px * 256 + co] = __float2bfloat16(v);
            s += v; q += v * v;
        }
        s += __shfl_down(s, 16, 64); s += __shfl_down(s, 32, 64);
        q += __shfl_down(q, 16, 64); q += __shfl_down(q, 32, 64);
        if (lane < 16) {
            int row = (b << 2) | wv;
            P[row * 32 + ct * 16 + l16] = s;
            Q[row * 32 + ct * 16 + l16] = q;
        }
    }
}

// ===========================================================================
// IN finalize: reduce 256 per-(n,co) partials -> mean + rsqrt.
// MODE 0: resconv layout (b = n*512 + r*8 + coO, row = b*4+wv)
// MODE 1: deform3 layout (b = n*256 + tile, row = b*8+wv(co))
// grid 2 (n), 256 threads (co).
// ===========================================================================
template<int MODE>
__global__ __launch_bounds__(256) void cl_finalize_kernel(
    const float* __restrict__ P, const float* __restrict__ Q,
    float* __restrict__ mvz, float* __restrict__ ivz)
{
    int n = blockIdx.x, co = threadIdx.x;
    float s = 0.f, q = 0.f;
    if (MODE == 0) {
        int coO = co >> 5, col = co & 31;
        for (int j = 0; j < 256; ++j) {
            int r = j >> 2, wv = j & 3;
            int row = ((((n << 9) | (r << 3) | coO)) << 2) | wv;
            s += P[row * 32 + col]; q += Q[row * 32 + col];
        }
    } else {
        int wvf = ((co >> 7) << 2) | ((co >> 5) & 3);
        int col = co & 31;
        for (int tile = 0; tile < 256; ++tile) {
            int row = (((n << 8) | tile) << 3) | wvf;
            s += P[row * 32 + col]; q += Q[row * 32 + col];
        }
    }
    float mean = s / 4096.f;
    mvz[n * 256 + co] = mean;
    ivz[n * 256 + co] = rsqrtf(q / 4096.f - mean * mean + 1e-5f);
}

// ===========================================================================
// Channels-last instance-norm apply kernels (read finalized mv/iv).
// ===========================================================================
__global__ __launch_bounds__(TPB) void cl_apply_kernel(
    unsigned short* __restrict__ X, const float* __restrict__ mvz,
    const float* __restrict__ ivz, int relu)
{
    __shared__ float mv[256], iv[256];
    int y = blockIdx.x & 63, n = blockIdx.x >> 6;
    int t = threadIdx.x;
    mv[t] = mvz[n * 256 + t]; iv[t] = ivz[n * 256 + t];
    __syncthreads();
    unsigned* row = (unsigned*)(X + ((long)n * 4096 + y * 64) * 256);
    for (int e = t; e < 8192; e += TPB) {
        int co = (e * 2) & 255;
        unsigned u = row[e];
        float v0 = (bitsToF((unsigned short)(u & 0xffff)) - mv[co]) * iv[co];
        float v1 = (bitsToF((unsigned short)(u >> 16)) - mv[co + 1]) * iv[co + 1];
        if (relu) { v0 = fmaxf(v0, 0.f); v1 = fmaxf(v1, 0.f); }
        row[e] = (unsigned)fToBits(v0) | ((unsigned)fToBits(v1) << 16);
    }
}

__global__ __launch_bounds__(TPB) void cl_apply_add_kernel(
    const unsigned short* __restrict__ T, unsigned short* __restrict__ H,
    const float* __restrict__ mvz, const float* __restrict__ ivz)
{
    __shared__ float mv[256], iv[256];
    int y = blockIdx.x & 63, n = blockIdx.x >> 6;
    int t = threadIdx.x;
    mv[t] = mvz[n * 256 + t]; iv[t] = ivz[n * 256 + t];
    __syncthreads();
    long base = ((long)n * 4096 + y * 64) * 256;
    const unsigned* tr = (const unsigned*)(T + base);
    unsigned* hr = (unsigned*)(H + base);
    for (int e = t; e < 8192; e += TPB) {
        int co = (e * 2) & 255;
        unsigned ut = tr[e], uh = hr[e];
        float v0 = bitsToF((unsigned short)(uh & 0xffff))
                 + (bitsToF((unsigned short)(ut & 0xffff)) - mv[co]) * iv[co];
        float v1 = bitsToF((unsigned short)(uh >> 16))
                 + (bitsToF((unsigned short)(ut >> 16)) - mv[co + 1]) * iv[co + 1];
        hr[e] = (unsigned)fToBits(v0) | ((unsigned)fToBits(v1) << 16);
    }
}

__global__ __launch_bounds__(TPB) void cl_apply_final_kernel(
    const unsigned short* __restrict__ T, const unsigned short* __restrict__ H,
    void* __restrict__ outp, const float* __restrict__ mvz,
    const float* __restrict__ ivz, const int* __restrict__ dflag)
{
    __shared__ float mv[256], iv[256];
    int y = blockIdx.x & 63, n = blockIdx.x >> 6;
    int t = threadIdx.x;
    mv[t] = mvz[n * 256 + t]; iv[t] = ivz[n * 256 + t];
    __syncthreads();
    int bf = *dflag;
    int x = t & 63, cg = t >> 6;
    for (int co = cg; co < 256; co += 4) {
        long cli = ((long)(n * 64 + y) * 64 + x) * 256 + co;
        float v = bitsToF(H[cli]) + (bitsToF(T[cli]) - mv[co]) * iv[co];
        long oi = (((long)(n * 256 + co)) * 64 + y) * 64 + x;
        if (bf) ((bf16*)outp)[oi] = __float2bfloat16(v);
        else    ((float*)outp)[oi] = v;
    }
}

// ---------------- block reduction (up to 16 waves) -------------------------
__device__ __forceinline__ void reduce2(float& sum, float& sq, float* s1, float* s2)
{
    for (int off = 32; off; off >>= 1) {
        sum += __shfl_down(sum, off, 64);
        sq  += __shfl_down(sq,  off, 64);
    }
    int nw = blockDim.x >> 6;
    int wid = threadIdx.x >> 6;
    if ((threadIdx.x & 63) == 0) { s1[wid] = sum; s2[wid] = sq; }
    __syncthreads();
    sum = 0.f; sq = 0.f;
    for (int w = 0; w < nw; ++w) { sum += s1[w]; sq += s2[w]; }
}

// ---------------- instance norm for skip1/skip2 (d_out, flag dtype) --------
__global__ void instnorm_kernel(
    void* __restrict__ buf, long base0, const int* __restrict__ dflag,
    int HW, int relu)
{
    __shared__ float s1[16], s2[16];
    int bf = *dflag;
    long base = base0 + (long)blockIdx.x * HW;
    float sum = 0.f, sq = 0.f;
    for (int i = threadIdx.x; i < HW; i += blockDim.x) {
        float v = bf ? bitsToF(((const unsigned short*)buf)[base + i])
                     : ((const float*)buf)[base + i];
        sum += v; sq += v * v;
    }
    reduce2(sum, sq, s1, s2);
    float mean = sum / HW;
    float inv = rsqrtf(sq / HW - mean * mean + 1e-5f);
    for (int i = threadIdx.x; i < HW; i += blockDim.x) {
        float v = bf ? bitsToF(((const unsigned short*)buf)[base + i])
                     : ((const float*)buf)[base + i];
        v = (v - mean) * inv;
        if (relu) v = fmaxf(v, 0.f);
        if (bf) ((bf16*)buf)[base + i] = __float2bfloat16(v);
        else    ((float*)buf)[base + i] = v;
    }
}

// ---------------------------------------------------------------------------
extern "C" void kernel_launch(void* const* d_in, const int* in_sizes, int n_in,
                              void* d_out, int out_size, void* d_ws, size_t ws_size,
                              hipStream_t stream) {
    const void* x = d_in[0];

    const long SKIP1 = 2097152;
    const long SKIP2 = 10485760;

    int* dflag = (int*)d_ws;
    float* fw = (float*)((char*)d_ws + 64);

    unsigned short* t1 = (unsigned short*)(fw + FB);
    unsigned short* t2 = (unsigned short*)(fw + FB + 1048576);
    unsigned short* h3 = (unsigned short*)(fw + H3F);
    float* offb = fw + OFFB;
    unsigned short* x4 = (unsigned short*)(fw + OFFB);   // layer-1 only; dead after
    float* mvz = fw + PSUM;
    float* ivz = fw + PSQ;
    float* P = fw + PPART;
    float* Q = fw + QPART;
    unsigned short* clbuf = (unsigned short*)(fw + CLBUF);    // skip1_cl then skip2_cl
    const unsigned short* wb1o = (const unsigned short*)(fw + WB1OT);
    const unsigned short* wb1d = (const unsigned short*)(fw + WB1DT);
    const unsigned short* wb2o = (const unsigned short*)(fw + WO2T);
    const unsigned short* wb3o = (const unsigned short*)(fw + WO3T);
    const unsigned short* wb2 = (const unsigned short*)(fw + WB2T);
    const unsigned short* wb3 = (const unsigned short*)(fw + WB3T);
    const unsigned short* rbw1 = (const unsigned short*)(fw + RB1W1T);
    const unsigned short* rbw2 = (const unsigned short*)(fw + RB1W2T);
    const unsigned short* rbw3 = (const unsigned short*)(fw + RB2W1T);
    const unsigned short* rbw4 = (const unsigned short*)(fw + RB2W2T);

    detect_kernel<<<1, 64, 0, stream>>>(x, dflag);

    // ---- weight/bias repack ----
    PtrPack pp;
    for (int i = 0; i < 10; ++i) pp.p[i] = nullptr;
    pp.p[10] = d_in[2];  pp.p[11] = d_in[4];  pp.p[12] = d_in[6];  pp.p[13] = d_in[8];
    pp.p[14] = d_in[10]; pp.p[15] = d_in[12]; pp.p[16] = d_in[14]; pp.p[17] = d_in[16];
    pp.p[18] = d_in[18]; pp.p[19] = d_in[20];
    repack_all_kernel<<<2, TPB, 0, stream>>>(pp, fw, dflag);
    repack_dcn_kernel<<<867, TPB, 0, stream>>>(
        d_in[7], d_in[11], d_in[1], d_in[3], d_in[5], d_in[9], fw, dflag);
    RbPack rp;
    rp.src[0] = d_in[13]; rp.src[1] = d_in[15]; rp.src[2] = d_in[17]; rp.src[3] = d_in[19];
    repack_rb_kernel<<<256, TPB, 0, stream>>>(rp, fw, dflag);

    // ---- Layer 1 fused MFMA: offsets + deform, 7x7 s1 p3 ----
    x_to_cl4_kernel<<<512, TPB, 0, stream>>>(x, x4, dflag);
    layer1_mfma_kernel<<<4096, TPB, 0, stream>>>(
        x4, wb1o, wb1d, fw + OFF1B, fw + DCN1B, d_out, SKIP1, dflag);
    instnorm_kernel<<<128, 1024, 0, stream>>>(d_out, SKIP1, dflag, 65536, 1);
    // skip1 -> channels-last bf16 for the MFMA conv gathers
    nchw_to_cl_kernel<64><<<2048, TPB, 0, stream>>>(d_out, SKIP1, clbuf, 65536, dflag);

    // ---- Layer 2: 4x4 s2 p1, Cin=64 ----
    offconv_mfma_kernel<64, 256, 256, 128, 128><<<2048, TPB, 0, stream>>>(
        clbuf, wb2o, fw + OFF2B, offb);
    deform_mfma_kernel<0, 64, 128, 4, 256, 256, 128, 128><<<2048, TPB, 0, stream>>>(
        clbuf, offb, wb2, fw + DCN2B, d_out, SKIP2, dflag, nullptr, nullptr);
    instnorm_kernel<<<256, 512, 0, stream>>>(d_out, SKIP2, dflag, 16384, 1);
    // skip2 -> channels-last bf16 (reuses clbuf; skip1_cl is dead now)
    nchw_to_cl_kernel<128><<<512, TPB, 0, stream>>>(d_out, SKIP2, clbuf, 16384, dflag);

    // ---- Layer 3: 4x4 s2 p1, Cin=128; output bf16 channels-last h3 ----
    offconv_mfma_kernel<128, 128, 128, 64, 64><<<512, TPB, 0, stream>>>(
        clbuf, wb3o, fw + OFF3B, offb);
    deform_mfma_kernel<1, 128, 256, 8, 128, 128, 64, 64><<<512, 512, 0, stream>>>(
        clbuf, offb, wb3, fw + DCN3B, h3, 0, dflag, P, Q);
    cl_finalize_kernel<1><<<2, 256, 0, stream>>>(P, Q, mvz, ivz);
    cl_apply_kernel<<<128, TPB, 0, stream>>>(h3, mvz, ivz, 1);

    // ---- Res block 1 (MFMA, fused stats) ----
    resconv_mfma_kernel<<<1024, TPB, 0, stream>>>(h3, rbw1, fw + RB1B1, (bf16*)t1, P, Q);
    cl_finalize_kernel<0><<<2, 256, 0, stream>>>(P, Q, mvz, ivz);
    cl_apply_kernel<<<128, TPB, 0, stream>>>(t1, mvz, ivz, 1);
    resconv_mfma_kernel<<<1024, TPB, 0, stream>>>(t1, rbw2, fw + RB1B2, (bf16*)t2, P, Q);
    cl_finalize_kernel<0><<<2, 256, 0, stream>>>(P, Q, mvz, ivz);
    cl_apply_add_kernel<<<128, TPB, 0, stream>>>(t2, h3, mvz, ivz);

    // ---- Res block 2 (MFMA, fused stats; final writes NCHW d_out) ----
    resconv_mfma_kernel<<<1024, TPB, 0, stream>>>(h3, rbw3, fw + RB2B1, (bf16*)t1, P, Q);
    cl_finalize_kernel<0><<<2, 256, 0, stream>>>(P, Q, mvz, ivz);
    cl_apply_kernel<<<128, TPB, 0, stream>>>(t1, mvz, ivz, 1);
    resconv_mfma_kernel<<<1024, TPB, 0, stream>>>(t1, rbw4, fw + RB2B2, (bf16*)t2, P, Q);
    cl_finalize_kernel<0><<<2, 256, 0, stream>>>(P, Q, mvz, ivz);
    cl_apply_final_kernel<<<128, TPB, 0, stream>>>(t2, h3, d_out, mvz, ivz, dflag);
}

// Round 10
// 885.684 us; speedup vs baseline: 1.0519x; 1.0519x over previous
//
#include <hip/hip_runtime.h>
#include <hip/hip_bf16.h>
#include <math.h>

#define TPB 256
typedef __hip_bfloat16 bf16;
typedef short bf16x8 __attribute__((ext_vector_type(8)));   // 8 bf16 (4 VGPRs)
typedef float f32x4 __attribute__((ext_vector_type(4)));

// ---------------- ws layout constants (fp32-element offsets from fw) -------
constexpr long BIASF  = 0;          // 1715 packed fp32 biases (pad to 2048)
constexpr long RB1W1T = 2048;       // res weights bf16 [9][256co][256ci]
constexpr long RB1W2T = 591872;
constexpr long RB2W1T = 1181696;
constexpr long RB2W2T = 1771520;
constexpr long FB     = 2361344;    // multi-use region
constexpr long WB1OT  = 2361344;    // bf16 [160][160] off1 weights (16B aligned)
constexpr long WB1DT  = 2382956;    // bf16 [64][160] dcn1 weights (16B aligned)
constexpr long WO2T   = 2392364;    // bf16 [64co pad][1024] off2 weights
constexpr long WB2T   = 2441516;    // bf16 [128co][1024] deform2 weights (16B aligned)
constexpr long WO3T   = 2572588;    // bf16 [64co pad][2048] off3 weights
constexpr long WB3T   = 2670892;    // bf16 [256co][2048] deform3 weights (16B aligned)
constexpr long OFFB   = 3221504;    // offsets layers 2/3; x4 during layer 1
constexpr long H3F    = 4458496;    // h3 bf16 channels-last, 1048576 floats
constexpr long CLBUF  = 5523456;    // channels-last bf16 skip1/skip2
constexpr long PST1   = 7620608;    // IN partial sums  [2][64][256]
constexpr long PST2   = 7653376;    // IN partial sumsq [2][64][256]
// bias sub-offsets
constexpr long OFF1B = 0,   DCN1B = 147;
constexpr long OFF2B = 211, DCN2B = 259;
constexpr long OFF3B = 387, DCN3B = 435;
constexpr long RB1B1 = 691, RB1B2 = 947;
constexpr long RB2B1 = 1203, RB2B2 = 1459;

// ---- compile-time dtype accessors (BF=1: bf16, BF=0: fp32) ----------------
template<int BF>
__device__ __forceinline__ float ldT(const void* p, long i) {
    if (BF) {
        unsigned short h = ((const unsigned short*)p)[i];
        return __uint_as_float(((unsigned int)h) << 16);
    }
    return ((const float*)p)[i];
}
template<int BF>
__device__ __forceinline__ void stT(void* p, long i, float v) {
    if (BF) ((bf16*)p)[i] = __float2bfloat16(v);
    else    ((float*)p)[i] = v;
}
__device__ __forceinline__ float bitsToF(unsigned short h) {
    return __uint_as_float(((unsigned int)h) << 16);
}
__device__ __forceinline__ unsigned short fToBits(float v) {
    bf16 h = __float2bfloat16(v);
    return *(unsigned short*)&h;
}

// ---- dtype detector (validated rounds 3-9) --------------------------------
__global__ void detect_kernel(const void* __restrict__ x, int* __restrict__ flag) {
    if (threadIdx.x == 0 && blockIdx.x == 0) {
        const unsigned short* u = (const unsigned short*)x;
        int sane = 0;
        for (int i = 0; i < 256; ++i) {
            float v = bitsToF(u[i]);
            float a = fabsf(v);
            if (a > 0.0009f && a < 1100.f) ++sane;
        }
        *flag = (sane >= 224) ? 1 : 0;
    }
}

// ===========================================================================
// Repack: biases -> packed fp32 (grid 2).
// ===========================================================================
struct PtrPack { const void* p[20]; };   // p[10..19]=biases

template<int BF>
__device__ void repack_all_body(PtrPack pp, float* __restrict__ fw)
{
    constexpr int  bcum  [11] = {0,147,211,259,387,435,691,947,1203,1459,1715};
    int j0 = blockIdx.x * 1024 + threadIdx.x * 4;
    #pragma unroll
    for (int q = 0; q < 4; ++q) {
        int j = j0 + q;
        if (j < 1715) {
            int v = 0;
            #pragma unroll
            for (int s = 1; s < 10; ++s) if (j >= bcum[s]) v = s;
            fw[BIASF + j] = ldT<BF>(pp.p[10 + v], j - bcum[v]);
        }
    }
}
__global__ __launch_bounds__(TPB) void repack_all_kernel(
    PtrPack pp, float* fw, const int* dflag) {
    if (*dflag) repack_all_body<1>(pp, fw);
    else        repack_all_body<0>(pp, fw);
}

// ---- conv weights -> bf16 [co][k*CIN+ci] (dst-contiguous writes) ----------
__global__ __launch_bounds__(TPB) void repack_dcn_kernel(
    const void* __restrict__ w2, const void* __restrict__ w3,
    const void* __restrict__ w1o, const void* __restrict__ w1d,
    const void* __restrict__ w2o, const void* __restrict__ w3o,
    float* __restrict__ fw, const int* __restrict__ dflag)
{
    int bf = *dflag;
    unsigned short* wb2 = (unsigned short*)(fw + WB2T);
    unsigned short* wb3 = (unsigned short*)(fw + WB3T);
    unsigned short* wb1o = (unsigned short*)(fw + WB1OT);
    unsigned short* wb1d = (unsigned short*)(fw + WB1DT);
    unsigned short* wb2o = (unsigned short*)(fw + WO2T);
    unsigned short* wb3o = (unsigned short*)(fw + WO3T);
    int b = blockIdx.x;
    if (b < 128) {                              // dcn2: 131072 = 128 blocks
        int e0 = b * 1024 + threadIdx.x * 4;
        #pragma unroll
        for (int j = 0; j < 4; ++j) {
            int e = e0 + j;
            int co = e >> 10, rem = e & 1023, k = rem >> 6, ci = rem & 63;
            long si = ((long)(co * 64 + ci)) * 16 + k;
            float v = bf ? ldT<1>(w2, si) : ldT<0>(w2, si);
            wb2[e] = fToBits(v);
        }
    } else if (b < 640) {                       // dcn3: 524288 = 512 blocks
        int e0 = (b - 128) * 1024 + threadIdx.x * 4;
        #pragma unroll
        for (int j = 0; j < 4; ++j) {
            int e = e0 + j;
            int co = e >> 11, rem = e & 2047, k = rem >> 7, ci = rem & 127;
            long si = ((long)(co * 128 + ci)) * 16 + k;
            float v = bf ? ldT<1>(w3, si) : ldT<0>(w3, si);
            wb3[e] = fToBits(v);
        }
    } else if (b < 665) {                       // off1: 160x160 = 25 blocks
        int e0 = (b - 640) * 1024 + threadIdx.x * 4;
        #pragma unroll
        for (int j = 0; j < 4; ++j) {
            int e = e0 + j;
            int co = e / 160, k = e - co * 160;
            float v = 0.f;
            if (co < 147 && k < 147) {
                long si = (long)co * 147 + k;
                v = bf ? ldT<1>(w1o, si) : ldT<0>(w1o, si);
            }
            wb1o[e] = fToBits(v);
        }
    } else if (b < 675) {                       // dcn1: 64x160 = 10 blocks
        int e0 = (b - 665) * 1024 + threadIdx.x * 4;
        #pragma unroll
        for (int j = 0; j < 4; ++j) {
            int e = e0 + j;
            int co = e / 160, k = e - co * 160;
            float v = 0.f;
            if (k < 147) {
                long si = (long)co * 147 + k;
                v = bf ? ldT<1>(w1d, si) : ldT<0>(w1d, si);
            }
            wb1d[e] = fToBits(v);
        }
    } else if (b < 739) {                       // off2 pad64: 65536 = 64 blocks
        int e0 = (b - 675) * 1024 + threadIdx.x * 4;
        #pragma unroll
        for (int j = 0; j < 4; ++j) {
            int e = e0 + j;
            int co = e >> 10, rem = e & 1023, k = rem >> 6, ci = rem & 63;
            float v = 0.f;
            if (co < 48) {
                long si = ((long)(co * 64 + ci)) * 16 + k;
                v = bf ? ldT<1>(w2o, si) : ldT<0>(w2o, si);
            }
            wb2o[e] = fToBits(v);
        }
    } else {                                    // off3 pad64: 131072 = 128 blocks
        int e0 = (b - 739) * 1024 + threadIdx.x * 4;
        #pragma unroll
        for (int j = 0; j < 4; ++j) {
            int e = e0 + j;
            int co = e >> 11, rem = e & 2047, k = rem >> 7, ci = rem & 127;
            float v = 0.f;
            if (co < 48) {
                long si = ((long)(co * 128 + ci)) * 16 + k;
                v = bf ? ldT<1>(w3o, si) : ldT<0>(w3o, si);
            }
            wb3o[e] = fToBits(v);
        }
    }
}

// ---- res weights: src[co][ci*9+q] (flag dtype) -> bf16 [q][co][ci] --------
struct RbPack { const void* src[4]; };
__global__ __launch_bounds__(TPB) void repack_rb_kernel(
    RbPack rp, float* fw, const int* dflag)
{
    __shared__ unsigned short lw[4 * 2304];
    int b = blockIdx.x;
    int ten = b >> 6;
    int co0 = (b & 63) * 4;
    const void* src = rp.src[ten];
    const long dstOff[4] = {RB1W1T, RB1W2T, RB2W1T, RB2W2T};
    unsigned short* dst = (unsigned short*)(fw + dstOff[ten]);
    int bf = *dflag;
    int t = threadIdx.x;
    for (int e = t; e < 4 * 2304; e += TPB) {
        int coL = e / 2304, i = e - coL * 2304;
        long si = (long)(co0 + coL) * 2304 + i;
        float v = bf ? ldT<1>(src, si) : ldT<0>(src, si);
        lw[e] = fToBits(v);
    }
    __syncthreads();
    for (int e = t; e < 9216; e += TPB) {     // 9216 = 9q * 4co * 256ci
        int ci = e & 255, coL = (e >> 8) & 3, q = e >> 10;
        dst[((long)q * 256 + co0 + coL) * 256 + ci] = lw[coL * 2304 + ci * 9 + q];
    }
}

// ===========================================================================
// x (NCHW flag dtype, 3ch) -> x4 bf16 [n][256][256][4] (ch 3 = 0 pad).
// ===========================================================================
template<int BF>
__device__ void x_to_cl4_body(const void* __restrict__ x, unsigned short* __restrict__ x4)
{
    long gid = (long)blockIdx.x * TPB + threadIdx.x;   // 0..131071
    int n = (int)(gid >> 16); int p = (int)(gid & 65535);
    long xb = (long)n * 3 * 65536 + p;
    unsigned c0 = fToBits(ldT<BF>(x, xb));
    unsigned c1 = fToBits(ldT<BF>(x, xb + 65536));
    unsigned c2 = fToBits(ldT<BF>(x, xb + 131072));
    uint2 v; v.x = c0 | (c1 << 16); v.y = c2;
    *(uint2*)&x4[gid * 4] = v;
}
__global__ __launch_bounds__(TPB) void x_to_cl4_kernel(
    const void* x, unsigned short* x4, const int* dflag)
{
    if (*dflag) x_to_cl4_body<1>(x, x4);
    else        x_to_cl4_body<0>(x, x4);
}

// ===========================================================================
// MFMA fused layer 1 v4 (validated round 8)
// ===========================================================================
template<int BF>
__device__ void layer1_mfma_body(
    const unsigned short* __restrict__ x4all, const unsigned short* __restrict__ wo,
    const unsigned short* __restrict__ wd, const float* __restrict__ bias1,
    const float* __restrict__ bias2, void* __restrict__ out, long obase,
    float* xs, unsigned short* A, float* offs)
{
    int b = blockIdx.x;
    int n = b >> 11;
    int ho = (b >> 3) & 255;
    int wo0 = (b & 7) << 5;
    const unsigned short* x4 = x4all + ((long)n << 16) * 4;
    int t = threadIdx.x;

    // ---- phase 1a: stage x patch [3ci][7ky][40 cols] from x4 (8B loads) --
    for (int e = t; e < 7 * 40; e += TPB) {
        int cc = e % 40, rr = e / 40;
        int yy = ho - 3 + rr; int xx = wo0 - 3 + cc;
        float c0 = 0.f, c1 = 0.f, c2 = 0.f;
        if (cc < 38 && yy >= 0 && yy < 256 && xx >= 0 && xx < 256) {
            uint2 v = *(const uint2*)&x4[((long)yy * 256 + xx) * 4];
            c0 = bitsToF((unsigned short)(v.x & 0xffff));
            c1 = bitsToF((unsigned short)(v.x >> 16));
            c2 = bitsToF((unsigned short)(v.y & 0xffff));
        }
        xs[(0 * 7 + rr) * 40 + cc] = c0;
        xs[(1 * 7 + rr) * 40 + cc] = c1;
        xs[(2 * 7 + rr) * 40 + cc] = c2;
    }
    __syncthreads();

    // ---- phase 1b: im2col -> A[kc][m][32] bf16, k = ci*49+ky*7+kx --------
    for (int e = t; e < 5120; e += TPB) {
        int kin = e & 31, m = (e >> 5) & 31, kc = e >> 10;
        int k = kc * 32 + kin;
        float v = 0.f;
        if (k < 147) {
            int ci = k / 49, q = k - ci * 49;
            int ky = q / 7, kx = q - ky * 7;
            v = xs[(ci * 7 + ky) * 40 + m + kx];
        }
        A[kc * 1024 + m * 32 + kin] = fToBits(v);
    }
    __syncthreads();

    int wv = t >> 6, lane = t & 63;
    int quad = lane >> 4, l16 = lane & 15;
    int mt = wv & 1, ntb = wv >> 1;

    // ---- phase 2: MFMA offset conv (N=160, 10 n-tiles over 2 wave-groups)-
    {
        f32x4 acc[5];
        #pragma unroll
        for (int j = 0; j < 5; ++j) acc[j] = (f32x4){0.f, 0.f, 0.f, 0.f};
        #pragma unroll
        for (int kc = 0; kc < 5; ++kc) {
            bf16x8 a = *(const bf16x8*)&A[(kc * 32 + mt * 16 + l16) * 32 + quad * 8];
            #pragma unroll
            for (int j = 0; j < 5; ++j) {
                int ch = (ntb + 2 * j) * 16 + l16;
                bf16x8 bw = *(const bf16x8*)&wo[ch * 160 + kc * 32 + quad * 8];
                acc[j] = __builtin_amdgcn_mfma_f32_16x16x32_bf16(a, bw, acc[j], 0, 0, 0);
            }
        }
        #pragma unroll
        for (int j = 0; j < 5; ++j) {
            int ch = (ntb + 2 * j) * 16 + l16;
            if (ch < 147) {
                float bv = bias1[ch];
                #pragma unroll
                for (int reg = 0; reg < 4; ++reg) {
                    int m = mt * 16 + quad * 4 + reg;
                    offs[ch * 33 + m] = acc[j][reg] + bv;
                }
            }
        }
    }
    __syncthreads();

    // ---- phase 3: p in lane (coalesced 8B taps); in-place sample write ----
    for (int e = t; e < 49 * 32; e += TPB) {
        int p = e & 31; int k = e >> 5;
        float oy = offs[k * 33 + p];
        float ox = offs[(49 + k) * 33 + p];
        float mr = offs[(98 + k) * 33 + p];
        float m = 1.f / (1.f + expf(-mr));
        float py = (float)(ho - 3 + k / 7) + oy;
        float px = (float)(wo0 + p - 3 + k % 7) + ox;
        float y0f = floorf(py), x0f = floorf(px);
        float wy = py - y0f, wx = px - x0f;
        int y0 = (int)y0f, x0 = (int)x0f;
        bool yv0 = (y0 >= 0) && (y0 < 256);
        bool yv1 = (y0 + 1 >= 0) && (y0 + 1 < 256);
        bool xv0 = (x0 >= 0) && (x0 < 256);
        bool xv1 = (x0 + 1 >= 0) && (x0 + 1 < 256);
        int y0c = min(max(y0, 0), 255), y1c = min(max(y0 + 1, 0), 255);
        int x0c = min(max(x0, 0), 255), x1c = min(max(x0 + 1, 0), 255);
        float w00 = (yv0 && xv0) ? (1.f - wy) * (1.f - wx) * m : 0.f;
        float w01 = (yv0 && xv1) ? (1.f - wy) * wx * m : 0.f;
        float w10 = (yv1 && xv0) ? wy * (1.f - wx) * m : 0.f;
        float w11 = (yv1 && xv1) ? wy * wx * m : 0.f;
        uint2 a00 = *(const uint2*)&x4[((long)y0c * 256 + x0c) * 4];
        uint2 a01 = *(const uint2*)&x4[((long)y0c * 256 + x1c) * 4];
        uint2 a10 = *(const uint2*)&x4[((long)y1c * 256 + x0c) * 4];
        uint2 a11 = *(const uint2*)&x4[((long)y1c * 256 + x1c) * 4];
        float s0 = w00 * bitsToF((unsigned short)(a00.x & 0xffff))
                 + w01 * bitsToF((unsigned short)(a01.x & 0xffff))
                 + w10 * bitsToF((unsigned short)(a10.x & 0xffff))
                 + w11 * bitsToF((unsigned short)(a11.x & 0xffff));
        float s1 = w00 * bitsToF((unsigned short)(a00.x >> 16))
                 + w01 * bitsToF((unsigned short)(a01.x >> 16))
                 + w10 * bitsToF((unsigned short)(a10.x >> 16))
                 + w11 * bitsToF((unsigned short)(a11.x >> 16));
        float s2 = w00 * bitsToF((unsigned short)(a00.y & 0xffff))
                 + w01 * bitsToF((unsigned short)(a01.y & 0xffff))
                 + w10 * bitsToF((unsigned short)(a10.y & 0xffff))
                 + w11 * bitsToF((unsigned short)(a11.y & 0xffff));
        offs[k * 33 + p] = s0;               // in-place, thread-local RAW
        offs[(49 + k) * 33 + p] = s1;
        offs[(98 + k) * 33 + p] = s2;
    }
    __syncthreads();

    // ---- phase 3.5: repack offs(f32) -> A(bf16 MFMA layout) --------------
    for (int e = t; e < 5120; e += TPB) {
        int kin = e & 31, m = (e >> 5) & 31, kc = e >> 10;
        int k = kc * 32 + kin;
        float v = 0.f;
        if (k < 147) v = offs[k * 33 + m];
        A[kc * 1024 + m * 32 + kin] = fToBits(v);
    }
    __syncthreads();

    // ---- phase 4: MFMA deform conv (N=64, 4 n-tiles) ---------------------
    f32x4 acc2[2];
    acc2[0] = (f32x4){0.f, 0.f, 0.f, 0.f};
    acc2[1] = (f32x4){0.f, 0.f, 0.f, 0.f};
    #pragma unroll
    for (int kc = 0; kc < 5; ++kc) {
        bf16x8 a = *(const bf16x8*)&A[(kc * 32 + mt * 16 + l16) * 32 + quad * 8];
        #pragma unroll
        for (int j = 0; j < 2; ++j) {
            int co = (ntb + 2 * j) * 16 + l16;
            bf16x8 bw = *(const bf16x8*)&wd[co * 160 + kc * 32 + quad * 8];
            acc2[j] = __builtin_amdgcn_mfma_f32_16x16x32_bf16(a, bw, acc2[j], 0, 0, 0);
        }
    }
    #pragma unroll
    for (int j = 0; j < 2; ++j) {
        int co = (ntb + 2 * j) * 16 + l16;
        float bv = bias2[co];
        #pragma unroll
        for (int reg = 0; reg < 4; ++reg) {
            int wox = wo0 + mt * 16 + quad * 4 + reg;
            long oi = obase + ((long)(n * 64 + co) * 256 + ho) * 256 + wox;
            stT<BF>(out, oi, acc2[j][reg] + bv);
        }
    }
}

__global__ __launch_bounds__(TPB) void layer1_mfma_kernel(
    const unsigned short* x4, const unsigned short* wo, const unsigned short* wd,
    const float* bias1, const float* bias2, void* out, long obase, const int* dflag)
{
    __shared__ __align__(16) float xs[3 * 7 * 40];
    __shared__ __align__(16) unsigned short A[5120];
    __shared__ __align__(16) float offs[147 * 33];
    if (*dflag) layer1_mfma_body<1>(x4, wo, wd, bias1, bias2, out, obase, xs, A, offs);
    else        layer1_mfma_body<0>(x4, wo, wd, bias1, bias2, out, obase, xs, A, offs);
}

// ===========================================================================
// MFMA offset conv (layers 2/3) — validated round 3.
// ===========================================================================
template<int CIN, int HH, int WW, int HO, int WO>
__global__ __launch_bounds__(TPB) void offconv_mfma_kernel(
    const unsigned short* __restrict__ xcl, const unsigned short* __restrict__ wb,
    const float* __restrict__ bias_f, float* __restrict__ out)
{
    constexpr int S   = 16 * CIN;
    constexpr int KL  = 512 / CIN;       // taps per 512-i chunk
    constexpr int NCH = 16 / KL;
    constexpr int PAIRS_W = (KL * 16) / 4;
    constexpr int TILES = (HO * WO) / 16;

    __shared__ int tp[256];
    __shared__ __align__(16) unsigned short smp[16 * 512];

    int tile = blockIdx.x % TILES;
    int n    = blockIdx.x / TILES;
    int lp0  = tile * 16;

    // ---- fixed-tap address table: one (k,p) per thread ----
    {
        int pr = threadIdx.x;
        int k = pr >> 4, p = pr & 15;
        int lp = lp0 + p;
        int ho = lp / WO, wo = lp - ho * WO;
        int yy = ho * 2 - 1 + (k >> 2);
        int xx = wo * 2 - 1 + (k & 3);
        bool valid = (yy >= 0) && (yy < HH) && (xx >= 0) && (xx < WW);
        tp[pr] = valid ? (yy * WW + xx) * CIN : -1;
    }

    int wv = threadIdx.x >> 6, lane = threadIdx.x & 63;
    int quad = lane >> 4, l16 = lane & 15;
    const unsigned short* xn = xcl + (long)n * HH * WW * CIN;

    f32x4 acc = (f32x4){0.f, 0.f, 0.f, 0.f};

    for (int ch = 0; ch < NCH; ++ch) {
        __syncthreads();
        #pragma unroll 4
        for (int u = 0; u < PAIRS_W; ++u) {
            int prl = wv * PAIRS_W + u;
            int pi  = ch * (KL * 16) + prl;
            int kl = prl >> 4, p = prl & 15;
            int t0 = tp[pi];
            #pragma unroll
            for (int cg = 0; cg < CIN / 64; ++cg) {
                int ci = cg * 64 + lane;
                unsigned short v = (t0 >= 0) ? xn[t0 + ci] : (unsigned short)0;
                int il = kl * CIN + ci;
                smp[((il >> 5) * 16 + p) * 32 + (il & 31)] = v;
            }
        }
        __syncthreads();
        #pragma unroll 4
        for (int kk = 0; kk < 16; ++kk) {
            bf16x8 a = *(const bf16x8*)&smp[(kk * 16 + l16) * 32 + quad * 8];
            int co = wv * 16 + l16;
            bf16x8 b = *(const bf16x8*)&wb[(long)co * S + ch * 512 + kk * 32 + quad * 8];
            acc = __builtin_amdgcn_mfma_f32_16x16x32_bf16(a, b, acc, 0, 0, 0);
        }
    }

    int co = wv * 16 + l16;
    if (co < 48) {
        float bv = bias_f[co];
        #pragma unroll
        for (int reg = 0; reg < 4; ++reg) {
            int lp = lp0 + quad * 4 + reg;
            int ho = lp / WO, wo = lp - ho * WO;
            out[((long)(n * 48 + co) * HO + ho) * WO + wo] = acc[reg] + bv;
        }
    }
}

// ===========================================================================
// NCHW (flag dtype) -> channels-last bf16 transpose. 64 pixels x C per block.
// ===========================================================================
template<int C>
__global__ __launch_bounds__(TPB) void nchw_to_cl_kernel(
    const void* __restrict__ in, long ibase, unsigned short* __restrict__ out,
    int HW, const int* __restrict__ dflag)
{
    __shared__ unsigned short tile[C * 65];
    int bf = *dflag;
    int n   = (blockIdx.x * 64) / HW;
    int px0 = (blockIdx.x * 64) % HW;
    for (int e = threadIdx.x; e < C * 64; e += TPB) {
        int c = e >> 6, p = e & 63;
        long si = ibase + (long)(n * C + c) * HW + px0 + p;
        float v = bf ? ldT<1>(in, si) : ldT<0>(in, si);
        tile[c * 65 + p] = fToBits(v);
    }
    __syncthreads();
    for (int e = threadIdx.x; e < C * 64; e += TPB) {
        int p = e / C, c = e - p * C;
        out[((long)n * HW + px0 + p) * C + c] = tile[c * 65 + p];
    }
}

// ===========================================================================
// MFMA deformable conv v2 (layers 2/3) — validated round 5/8 (no fused stats).
// ===========================================================================
template<int MODE, int CIN, int COUT, int NWAVES, int HH, int WW, int HO, int WO>
__global__ __launch_bounds__(NWAVES * 64) void deform_mfma_kernel(
    const unsigned short* __restrict__ xcl, const float* __restrict__ off,
    const unsigned short* __restrict__ wb, const float* __restrict__ bias_f,
    void* __restrict__ outp, long obase, const int* __restrict__ dflag)
{
    constexpr int TPBk = NWAVES * 64;
    constexpr int S    = 16 * CIN;       // reduction length
    constexpr int KL   = 512 / CIN;      // kernel-points per 512-i chunk
    constexpr int NCH  = 16 / KL;        // chunks
    constexpr int CH2  = CIN / 2;        // 4B units per (pair, tap)
    constexpr int ITER = (KL * 16 * CH2) / TPBk;   // 4B units per thread/chunk
    constexpr int TILES = (HO * WO) / 16;

    __shared__ __align__(16) int tpw[256][8];      // [pair]{tp0..3, w0..3bits}
    __shared__ __align__(16) unsigned short smp[16 * 512];

    int tile = blockIdx.x % TILES;
    int n    = blockIdx.x / TILES;
    int lp0  = tile * 16;
    int tid  = threadIdx.x;

    // ---- phase A: per-(k,p) offset decode, one pair per thread (first 256)-
    if (tid < 256) {
        int pr = tid;
        int k = pr >> 4, p = pr & 15;
        int lp = lp0 + p;
        int ho = lp / WO, wo = lp - ho * WO;
        long plane = (long)HO * WO;
        const float* offn = off + (long)n * 48 * plane;
        float oy = offn[(long)k * plane + lp];
        float ox = offn[(long)(16 + k) * plane + lp];
        float mr = offn[(long)(32 + k) * plane + lp];
        float m = 1.f / (1.f + expf(-mr));
        float py = (float)(ho * 2 - 1 + (k >> 2)) + oy;
        float px = (float)(wo * 2 - 1 + (k & 3)) + ox;
        float y0f = floorf(py), x0f = floorf(px);
        float wy = py - y0f, wx = px - x0f;
        int y0 = (int)y0f, x0 = (int)x0f;
        bool yv0 = (y0 >= 0) && (y0 < HH);
        bool yv1 = (y0 + 1 >= 0) && (y0 + 1 < HH);
        bool xv0 = (x0 >= 0) && (x0 < WW);
        bool xv1 = (x0 + 1 >= 0) && (x0 + 1 < WW);
        int y0c = min(max(y0, 0), HH - 1), y1c = min(max(y0 + 1, 0), HH - 1);
        int x0c = min(max(x0, 0), WW - 1), x1c = min(max(x0 + 1, 0), WW - 1);
        tpw[pr][0] = (y0c * WW + x0c) * CIN;
        tpw[pr][1] = (y0c * WW + x1c) * CIN;
        tpw[pr][2] = (y1c * WW + x0c) * CIN;
        tpw[pr][3] = (y1c * WW + x1c) * CIN;
        tpw[pr][4] = __float_as_int((yv0 && xv0) ? (1.f - wy) * (1.f - wx) * m : 0.f);
        tpw[pr][5] = __float_as_int((yv0 && xv1) ? (1.f - wy) * wx * m : 0.f);
        tpw[pr][6] = __float_as_int((yv1 && xv0) ? wy * (1.f - wx) * m : 0.f);
        tpw[pr][7] = __float_as_int((yv1 && xv1) ? wy * wx * m : 0.f);
    }

    int wv = tid >> 6, lane = tid & 63;
    int quad = lane >> 4, l16 = lane & 15;
    int cb = (wv & 3) * 32 + (wv >> 2) * (COUT / 2);
    const unsigned short* xn = xcl + (long)n * HH * WW * CIN;

    f32x4 acc[2];
    acc[0] = (f32x4){0.f, 0.f, 0.f, 0.f};
    acc[1] = (f32x4){0.f, 0.f, 0.f, 0.f};

    for (int ch = 0; ch < NCH; ++ch) {
        __syncthreads();   // covers phase A (ch=0) and prev MFMA reads
        #pragma unroll 4
        for (int it = 0; it < ITER; ++it) {
            int e   = it * TPBk + tid;
            int prl = e / CH2;                  // pair within chunk
            int ci  = (e - prl * CH2) * 2;      // even ci
            int pi  = ch * (KL * 16) + prl;
            const int4   tp4 = *(const int4*)&tpw[pi][0];
            const float4 tw4 = *(const float4*)&tpw[pi][4];
            unsigned v0 = *(const unsigned*)(xn + tp4.x + ci);
            unsigned v1 = *(const unsigned*)(xn + tp4.y + ci);
            unsigned v2 = *(const unsigned*)(xn + tp4.z + ci);
            unsigned v3 = *(const unsigned*)(xn + tp4.w + ci);
            float r0 = tw4.x * bitsToF((unsigned short)(v0 & 0xffff))
                     + tw4.y * bitsToF((unsigned short)(v1 & 0xffff))
                     + tw4.z * bitsToF((unsigned short)(v2 & 0xffff))
                     + tw4.w * bitsToF((unsigned short)(v3 & 0xffff));
            float r1 = tw4.x * bitsToF((unsigned short)(v0 >> 16))
                     + tw4.y * bitsToF((unsigned short)(v1 >> 16))
                     + tw4.z * bitsToF((unsigned short)(v2 >> 16))
                     + tw4.w * bitsToF((unsigned short)(v3 >> 16));
            unsigned ov = (unsigned)fToBits(r0) | ((unsigned)fToBits(r1) << 16);
            int il = (prl >> 4) * CIN + ci;     // i within chunk [0,512)
            int p  = prl & 15;
            *(unsigned*)&smp[((il >> 5) * 16 + p) * 32 + (il & 31)] = ov;
        }
        __syncthreads();
        #pragma unroll 4
        for (int kk = 0; kk < 16; ++kk) {
            bf16x8 a = *(const bf16x8*)&smp[(kk * 16 + l16) * 32 + quad * 8];
            #pragma unroll
            for (int f = 0; f < 2; ++f) {
                int co = cb + f * 16 + l16;
                bf16x8 b = *(const bf16x8*)&wb[(long)co * S + ch * 512 + kk * 32 + quad * 8];
                acc[f] = __builtin_amdgcn_mfma_f32_16x16x32_bf16(a, b, acc[f], 0, 0, 0);
            }
        }
    }

    // ---- epilogue: pixel = quad*4+reg, co = cb + f*16 + l16 ----
    if (MODE == 1) {
        unsigned short* oCL = (unsigned short*)outp;
        #pragma unroll
        for (int f = 0; f < 2; ++f) {
            int co = cb + f * 16 + l16;
            float bv = bias_f[co];
            #pragma unroll
            for (int reg = 0; reg < 4; ++reg) {
                int lp = lp0 + quad * 4 + reg;
                oCL[((long)n * HO * WO + lp) * COUT + co] = fToBits(acc[f][reg] + bv);
            }
        }
    } else {
        int bf = *dflag;
        #pragma unroll
        for (int f = 0; f < 2; ++f) {
            int co = cb + f * 16 + l16;
            float bv = bias_f[co];
            #pragma unroll
            for (int reg = 0; reg < 4; ++reg) {
                int lp = lp0 + quad * 4 + reg;
                int ho = lp / WO, wo = lp - ho * WO;
                long oi = obase + ((long)(n * COUT + co) * HO + ho) * WO + wo;
                if (bf) stT<1>(outp, oi, acc[f][reg] + bv);
                else    stT<0>(outp, oi, acc[f][reg] + bv);
            }
        }
    }
}

// ===========================================================================
// MFMA res-block 3x3 reflect conv v2 (validated round 4/8, no fused stats)
// ===========================================================================
__global__ __launch_bounds__(TPB) void resconv_mfma_kernel(
    const unsigned short* __restrict__ X, const unsigned short* __restrict__ W,
    const float* __restrict__ bias_f, bf16* __restrict__ Y)
{
    __shared__ __align__(16) unsigned short xs[3 * 66 * 64];   // 25344 B, swizzled
    int b = blockIdx.x;
    int coO = b & 7, r = (b >> 3) & 63, n = b >> 9;
    int t = threadIdx.x;
    int wv = t >> 6;
    int lane = t & 63;
    int quad = lane >> 4, l16 = lane & 15;
    int rows[3];
    rows[0] = (r == 0) ? 1 : r - 1;
    rows[1] = r;
    rows[2] = (r == 63) ? 62 : r + 1;

    f32x4 acc[2];
    acc[0] = (f32x4){0.f, 0.f, 0.f, 0.f};
    acc[1] = (f32x4){0.f, 0.f, 0.f, 0.f};

    long xbase = (long)n * 4096 * 256;

    for (int ci0 = 0; ci0 < 256; ci0 += 64) {
        __syncthreads();
        // stage [3ky][66col][64ci] via 16B loads; swizzled 16B slot per col
        for (int e = t; e < 3 * 66 * 8; e += TPB) {
            int oct = e & 7;
            int col = (e >> 3) % 66;
            int ky  = e / (66 * 8);
            int gx = col - 1;
            gx = (gx < 0) ? 1 : ((gx > 63) ? 62 : gx);
            bf16x8 v = *(const bf16x8*)&X[xbase + ((long)rows[ky] * 64 + gx) * 256 + ci0 + oct * 8];
            int slot = oct ^ (col & 7);
            *(bf16x8*)&xs[((ky * 66 + col) << 6) + slot * 8] = v;
        }
        __syncthreads();
        #pragma unroll
        for (int q = 0; q < 9; ++q) {
            int ky = q / 3, kx = q % 3;
            int col = wv * 16 + l16 + kx;        // lds col = global col +1
            int base = (ky * 66 + col) << 6;
            #pragma unroll
            for (int kh = 0; kh < 2; ++kh) {
                int slot = (kh * 4 + quad) ^ (col & 7);
                bf16x8 a = *(const bf16x8*)&xs[base + slot * 8];
                #pragma unroll
                for (int ct = 0; ct < 2; ++ct) {
                    int co = coO * 32 + ct * 16 + l16;
                    bf16x8 bw = *(const bf16x8*)&W[((long)q * 256 + co) * 256 + ci0 + kh * 32 + quad * 8];
                    acc[ct] = __builtin_amdgcn_mfma_f32_16x16x32_bf16(a, bw, acc[ct], 0, 0, 0);
                }
            }
        }
    }

    long ybase = ((long)n * 4096 + (long)r * 64) * 256;
    #pragma unroll
    for (int ct = 0; ct < 2; ++ct) {
        int co = coO * 32 + ct * 16 + l16;
        float bv = bias_f[co];
        #pragma unroll
        for (int reg = 0; reg < 4; ++reg) {
            int px = wv * 16 + quad * 4 + reg;
            Y[ybase + (long)px * 256 + co] = __float2bfloat16(acc[ct][reg] + bv);
        }
    }
}

// ===========================================================================
// Channels-last instance-norm: WIDE partial stats (grid 128 = n*64 + chunk,
// 64 positions each; 4x the parallelism and 1/4 the chain length of the
// grid-32 version) + apply kernels summing 64 partials.
// ===========================================================================
__global__ __launch_bounds__(TPB) void cl_stats_kernel(
    const unsigned short* __restrict__ X, float* __restrict__ psum, float* __restrict__ psq)
{
    int blk = blockIdx.x;
    int chunk = blk & 63, n = blk >> 6;
    int co = threadIdx.x;
    float s = 0.f, sq = 0.f;
    const unsigned short* p = X + ((long)n * 4096 + chunk * 64) * 256 + co;
    #pragma unroll 8
    for (int i = 0; i < 64; ++i) {
        float v = bitsToF(p[(long)i * 256]);
        s += v; sq += v * v;
    }
    psum[(n * 64 + chunk) * 256 + co] = s;
    psq [(n * 64 + chunk) * 256 + co] = sq;
}

__device__ __forceinline__ void cl_load_stats(
    const float* psum, const float* psq, int n, float* mv, float* iv)
{
    int t = threadIdx.x;   // t = channel
    float s = 0.f, sq = 0.f;
    #pragma unroll 8
    for (int c = 0; c < 64; ++c) {
        s  += psum[(n * 64 + c) * 256 + t];
        sq += psq [(n * 64 + c) * 256 + t];
    }
    float mean = s / 4096.f;
    mv[t] = mean;
    iv[t] = rsqrtf(sq / 4096.f - mean * mean + 1e-5f);
    __syncthreads();
}

// grid 128 = n*64 + y; in-place X = relu?((X-m)*inv), uint-vectorized
__global__ __launch_bounds__(TPB) void cl_apply_kernel(
    unsigned short* __restrict__ X, const float* __restrict__ psum,
    const float* __restrict__ psq, int relu)
{
    __shared__ float mv[256], iv[256];
    int y = blockIdx.x & 63, n = blockIdx.x >> 6;
    cl_load_stats(psum, psq, n, mv, iv);
    unsigned* row = (unsigned*)(X + ((long)n * 4096 + y * 64) * 256);
    for (int e = threadIdx.x; e < 8192; e += TPB) {
        int co = (e * 2) & 255;
        unsigned u = row[e];
        float v0 = (bitsToF((unsigned short)(u & 0xffff)) - mv[co]) * iv[co];
        float v1 = (bitsToF((unsigned short)(u >> 16)) - mv[co + 1]) * iv[co + 1];
        if (relu) { v0 = fmaxf(v0, 0.f); v1 = fmaxf(v1, 0.f); }
        row[e] = (unsigned)fToBits(v0) | ((unsigned)fToBits(v1) << 16);
    }
}

// grid 128; H += IN(T), uint-vectorized
__global__ __launch_bounds__(TPB) void cl_apply_add_kernel(
    const unsigned short* __restrict__ T, unsigned short* __restrict__ H,
    const float* __restrict__ psum, const float* __restrict__ psq)
{
    __shared__ float mv[256], iv[256];
    int y = blockIdx.x & 63, n = blockIdx.x >> 6;
    cl_load_stats(psum, psq, n, mv, iv);
    long base = ((long)n * 4096 + y * 64) * 256;
    const unsigned* tr = (const unsigned*)(T + base);
    unsigned* hr = (unsigned*)(H + base);
    for (int e = threadIdx.x; e < 8192; e += TPB) {
        int co = (e * 2) & 255;
        unsigned ut = tr[e], uh = hr[e];
        float v0 = bitsToF((unsigned short)(uh & 0xffff))
                 + (bitsToF((unsigned short)(ut & 0xffff)) - mv[co]) * iv[co];
        float v1 = bitsToF((unsigned short)(uh >> 16))
                 + (bitsToF((unsigned short)(ut >> 16)) - mv[co + 1]) * iv[co + 1];
        hr[e] = (unsigned)fToBits(v0) | ((unsigned)fToBits(v1) << 16);
    }
}

// grid 128; out(NCHW, flag dtype) = H + IN(T)   (transposes channels-last)
__global__ __launch_bounds__(TPB) void cl_apply_final_kernel(
    const unsigned short* __restrict__ T, const unsigned short* __restrict__ H,
    void* __restrict__ outp, const float* __restrict__ psum,
    const float* __restrict__ psq, const int* __restrict__ dflag)
{
    __shared__ float mv[256], iv[256];
    int y = blockIdx.x & 63, n = blockIdx.x >> 6;
    cl_load_stats(psum, psq, n, mv, iv);
    int bf = *dflag;
    int x = threadIdx.x & 63, cg = threadIdx.x >> 6;
    for (int co = cg; co < 256; co += 4) {
        long cli = ((long)(n * 64 + y) * 64 + x) * 256 + co;
        float v = bitsToF(H[cli]) + (bitsToF(T[cli]) - mv[co]) * iv[co];
        long oi = (((long)(n * 256 + co)) * 64 + y) * 64 + x;
        if (bf) ((bf16*)outp)[oi] = __float2bfloat16(v);
        else    ((float*)outp)[oi] = v;
    }
}

// ---------------- block reduction (up to 16 waves) -------------------------
__device__ __forceinline__ void reduce2(float& sum, float& sq, float* s1, float* s2)
{
    for (int off = 32; off; off >>= 1) {
        sum += __shfl_down(sum, off, 64);
        sq  += __shfl_down(sq,  off, 64);
    }
    int nw = blockDim.x >> 6;
    int wid = threadIdx.x >> 6;
    if ((threadIdx.x & 63) == 0) { s1[wid] = sum; s2[wid] = sq; }
    __syncthreads();
    sum = 0.f; sq = 0.f;
    for (int w = 0; w < nw; ++w) { sum += s1[w]; sq += s2[w]; }
}

// ---------------- instance norm for skip1/skip2 (d_out, flag dtype) --------
__global__ void instnorm_kernel(
    void* __restrict__ buf, long base0, const int* __restrict__ dflag,
    int HW, int relu)
{
    __shared__ float s1[16], s2[16];
    int bf = *dflag;
    long base = base0 + (long)blockIdx.x * HW;
    float sum = 0.f, sq = 0.f;
    for (int i = threadIdx.x; i < HW; i += blockDim.x) {
        float v = bf ? bitsToF(((const unsigned short*)buf)[base + i])
                     : ((const float*)buf)[base + i];
        sum += v; sq += v * v;
    }
    reduce2(sum, sq, s1, s2);
    float mean = sum / HW;
    float inv = rsqrtf(sq / HW - mean * mean + 1e-5f);
    for (int i = threadIdx.x; i < HW; i += blockDim.x) {
        float v = bf ? bitsToF(((const unsigned short*)buf)[base + i])
                     : ((const float*)buf)[base + i];
        v = (v - mean) * inv;
        if (relu) v = fmaxf(v, 0.f);
        if (bf) ((bf16*)buf)[base + i] = __float2bfloat16(v);
        else    ((float*)buf)[base + i] = v;
    }
}

// ---------------------------------------------------------------------------
extern "C" void kernel_launch(void* const* d_in, const int* in_sizes, int n_in,
                              void* d_out, int out_size, void* d_ws, size_t ws_size,
                              hipStream_t stream) {
    const void* x = d_in[0];

    const long SKIP1 = 2097152;
    const long SKIP2 = 10485760;

    int* dflag = (int*)d_ws;
    float* fw = (float*)((char*)d_ws + 64);

    unsigned short* t1 = (unsigned short*)(fw + FB);
    unsigned short* t2 = (unsigned short*)(fw + FB + 1048576);
    unsigned short* h3 = (unsigned short*)(fw + H3F);
    float* offb = fw + OFFB;
    unsigned short* x4 = (unsigned short*)(fw + OFFB);   // layer-1 only; dead after
    float* psum = fw + PST1;
    float* psq  = fw + PST2;
    unsigned short* clbuf = (unsigned short*)(fw + CLBUF);    // skip1_cl then skip2_cl
    const unsigned short* wb1o = (const unsigned short*)(fw + WB1OT);
    const unsigned short* wb1d = (const unsigned short*)(fw + WB1DT);
    const unsigned short* wb2o = (const unsigned short*)(fw + WO2T);
    const unsigned short* wb3o = (const unsigned short*)(fw + WO3T);
    const unsigned short* wb2 = (const unsigned short*)(fw + WB2T);
    const unsigned short* wb3 = (const unsigned short*)(fw + WB3T);
    const unsigned short* rbw1 = (const unsigned short*)(fw + RB1W1T);
    const unsigned short* rbw2 = (const unsigned short*)(fw + RB1W2T);
    const unsigned short* rbw3 = (const unsigned short*)(fw + RB2W1T);
    const unsigned short* rbw4 = (const unsigned short*)(fw + RB2W2T);

    detect_kernel<<<1, 64, 0, stream>>>(x, dflag);

    // ---- weight/bias repack ----
    PtrPack pp;
    for (int i = 0; i < 10; ++i) pp.p[i] = nullptr;
    pp.p[10] = d_in[2];  pp.p[11] = d_in[4];  pp.p[12] = d_in[6];  pp.p[13] = d_in[8];
    pp.p[14] = d_in[10]; pp.p[15] = d_in[12]; pp.p[16] = d_in[14]; pp.p[17] = d_in[16];
    pp.p[18] = d_in[18]; pp.p[19] = d_in[20];
    repack_all_kernel<<<2, TPB, 0, stream>>>(pp, fw, dflag);
    repack_dcn_kernel<<<867, TPB, 0, stream>>>(
        d_in[7], d_in[11], d_in[1], d_in[3], d_in[5], d_in[9], fw, dflag);
    RbPack rp;
    rp.src[0] = d_in[13]; rp.src[1] = d_in[15]; rp.src[2] = d_in[17]; rp.src[3] = d_in[19];
    repack_rb_kernel<<<256, TPB, 0, stream>>>(rp, fw, dflag);

    // ---- Layer 1 fused MFMA: offsets + deform, 7x7 s1 p3 ----
    x_to_cl4_kernel<<<512, TPB, 0, stream>>>(x, x4, dflag);
    layer1_mfma_kernel<<<4096, TPB, 0, stream>>>(
        x4, wb1o, wb1d, fw + OFF1B, fw + DCN1B, d_out, SKIP1, dflag);
    instnorm_kernel<<<128, 1024, 0, stream>>>(d_out, SKIP1, dflag, 65536, 1);
    // skip1 -> channels-last bf16 for the MFMA conv gathers
    nchw_to_cl_kernel<64><<<2048, TPB, 0, stream>>>(d_out, SKIP1, clbuf, 65536, dflag);

    // ---- Layer 2: 4x4 s2 p1, Cin=64 ----
    offconv_mfma_kernel<64, 256, 256, 128, 128><<<2048, TPB, 0, stream>>>(
        clbuf, wb2o, fw + OFF2B, offb);
    deform_mfma_kernel<0, 64, 128, 4, 256, 256, 128, 128><<<2048, TPB, 0, stream>>>(
        clbuf, offb, wb2, fw + DCN2B, d_out, SKIP2, dflag);
    instnorm_kernel<<<256, 512, 0, stream>>>(d_out, SKIP2, dflag, 16384, 1);
    // skip2 -> channels-last bf16 (reuses clbuf; skip1_cl is dead now)
    nchw_to_cl_kernel<128><<<512, TPB, 0, stream>>>(d_out, SKIP2, clbuf, 16384, dflag);

    // ---- Layer 3: 4x4 s2 p1, Cin=128; output bf16 channels-last h3 ----
    offconv_mfma_kernel<128, 128, 128, 64, 64><<<512, TPB, 0, stream>>>(
        clbuf, wb3o, fw + OFF3B, offb);
    deform_mfma_kernel<1, 128, 256, 8, 128, 128, 64, 64><<<512, 512, 0, stream>>>(
        clbuf, offb, wb3, fw + DCN3B, h3, 0, dflag);
    cl_stats_kernel<<<128, TPB, 0, stream>>>(h3, psum, psq);
    cl_apply_kernel<<<128, TPB, 0, stream>>>(h3, psum, psq, 1);

    // ---- Res block 1 (MFMA) ----
    resconv_mfma_kernel<<<1024, TPB, 0, stream>>>(h3, rbw1, fw + RB1B1, (bf16*)t1);
    cl_stats_kernel<<<128, TPB, 0, stream>>>(t1, psum, psq);
    cl_apply_kernel<<<128, TPB, 0, stream>>>(t1, psum, psq, 1);
    resconv_mfma_kernel<<<1024, TPB, 0, stream>>>(t1, rbw2, fw + RB1B2, (bf16*)t2);
    cl_stats_kernel<<<128, TPB, 0, stream>>>(t2, psum, psq);
    cl_apply_add_kernel<<<128, TPB, 0, stream>>>(t2, h3, psum, psq);

    // ---- Res block 2 (MFMA; final writes NCHW d_out per flag) ----
    resconv_mfma_kernel<<<1024, TPB, 0, stream>>>(h3, rbw3, fw + RB2B1, (bf16*)t1);
    cl_stats_kernel<<<128, TPB, 0, stream>>>(t1, psum, psq);
    cl_apply_kernel<<<128, TPB, 0, stream>>>(t1, psum, psq, 1);
    resconv_mfma_kernel<<<1024, TPB, 0, stream>>>(t1, rbw4, fw + RB2B2, (bf16*)t2);
    cl_stats_kernel<<<128, TPB, 0, stream>>>(t2, psum, psq);
    cl_apply_final_kernel<<<128, TPB, 0, stream>>>(t2, h3, d_out, psum, psq, dflag);
}

// Round 11
// 870.937 us; speedup vs baseline: 1.0697x; 1.0169x over previous
//
#include <hip/hip_runtime.h>
#include <hip/hip_bf16.h>
#include <math.h>

#define TPB 256
typedef __hip_bfloat16 bf16;
typedef short bf16x8 __attribute__((ext_vector_type(8)));   // 8 bf16 (4 VGPRs)
typedef float f32x4 __attribute__((ext_vector_type(4)));

// ---------------- ws layout constants (fp32-element offsets from fw) -------
constexpr long BIASF  = 0;          // 1715 packed fp32 biases (pad to 2048)
constexpr long RB1W1T = 2048;       // res weights bf16 [9][256co][256ci]
constexpr long RB1W2T = 591872;
constexpr long RB2W1T = 1181696;
constexpr long RB2W2T = 1771520;
constexpr long FB     = 2361344;    // multi-use region
constexpr long WB1OT  = 2361344;    // bf16 [160][160] off1 weights (16B aligned)
constexpr long WB1DT  = 2382956;    // bf16 [64][160] dcn1 weights (16B aligned)
constexpr long WO2T   = 2392364;    // bf16 [64co pad][1024] off2 weights
constexpr long WB2T   = 2441516;    // bf16 [128co][1024] deform2 weights (16B aligned)
constexpr long WO3T   = 2572588;    // bf16 [64co pad][2048] off3 weights
constexpr long WB3T   = 2670892;    // bf16 [256co][2048] deform3 weights (16B aligned)
constexpr long OFFB   = 3221504;    // offsets layers 2/3; x4 during layer 1
constexpr long H3F    = 4458496;    // h3 bf16 channels-last, 1048576 floats
constexpr long CLBUF  = 5523456;    // channels-last bf16 skip1/skip2
constexpr long PST1   = 7620608;    // IN partial sums  [2][64][256]
constexpr long PST2   = 7653376;    // IN partial sumsq [2][64][256]
// bias sub-offsets
constexpr long OFF1B = 0,   DCN1B = 147;
constexpr long OFF2B = 211, DCN2B = 259;
constexpr long OFF3B = 387, DCN3B = 435;
constexpr long RB1B1 = 691, RB1B2 = 947;
constexpr long RB2B1 = 1203, RB2B2 = 1459;

// ---- compile-time dtype accessors (BF=1: bf16, BF=0: fp32) ----------------
template<int BF>
__device__ __forceinline__ float ldT(const void* p, long i) {
    if (BF) {
        unsigned short h = ((const unsigned short*)p)[i];
        return __uint_as_float(((unsigned int)h) << 16);
    }
    return ((const float*)p)[i];
}
template<int BF>
__device__ __forceinline__ void stT(void* p, long i, float v) {
    if (BF) ((bf16*)p)[i] = __float2bfloat16(v);
    else    ((float*)p)[i] = v;
}
__device__ __forceinline__ float bitsToF(unsigned short h) {
    return __uint_as_float(((unsigned int)h) << 16);
}
__device__ __forceinline__ unsigned short fToBits(float v) {
    bf16 h = __float2bfloat16(v);
    return *(unsigned short*)&h;
}

// ---- dtype detector (validated rounds 3-9) --------------------------------
__global__ void detect_kernel(const void* __restrict__ x, int* __restrict__ flag) {
    if (threadIdx.x == 0 && blockIdx.x == 0) {
        const unsigned short* u = (const unsigned short*)x;
        int sane = 0;
        for (int i = 0; i < 256; ++i) {
            float v = bitsToF(u[i]);
            float a = fabsf(v);
            if (a > 0.0009f && a < 1100.f) ++sane;
        }
        *flag = (sane >= 224) ? 1 : 0;
    }
}

// ===========================================================================
// Repack: biases -> packed fp32 (grid 2).
// ===========================================================================
struct PtrPack { const void* p[20]; };   // p[10..19]=biases

template<int BF>
__device__ void repack_all_body(PtrPack pp, float* __restrict__ fw)
{
    constexpr int  bcum  [11] = {0,147,211,259,387,435,691,947,1203,1459,1715};
    int j0 = blockIdx.x * 1024 + threadIdx.x * 4;
    #pragma unroll
    for (int q = 0; q < 4; ++q) {
        int j = j0 + q;
        if (j < 1715) {
            int v = 0;
            #pragma unroll
            for (int s = 1; s < 10; ++s) if (j >= bcum[s]) v = s;
            fw[BIASF + j] = ldT<BF>(pp.p[10 + v], j - bcum[v]);
        }
    }
}
__global__ __launch_bounds__(TPB) void repack_all_kernel(
    PtrPack pp, float* fw, const int* dflag) {
    if (*dflag) repack_all_body<1>(pp, fw);
    else        repack_all_body<0>(pp, fw);
}

// ---- conv weights -> bf16 [co][k*CIN+ci] (dst-contiguous writes) ----------
__global__ __launch_bounds__(TPB) void repack_dcn_kernel(
    const void* __restrict__ w2, const void* __restrict__ w3,
    const void* __restrict__ w1o, const void* __restrict__ w1d,
    const void* __restrict__ w2o, const void* __restrict__ w3o,
    float* __restrict__ fw, const int* __restrict__ dflag)
{
    int bf = *dflag;
    unsigned short* wb2 = (unsigned short*)(fw + WB2T);
    unsigned short* wb3 = (unsigned short*)(fw + WB3T);
    unsigned short* wb1o = (unsigned short*)(fw + WB1OT);
    unsigned short* wb1d = (unsigned short*)(fw + WB1DT);
    unsigned short* wb2o = (unsigned short*)(fw + WO2T);
    unsigned short* wb3o = (unsigned short*)(fw + WO3T);
    int b = blockIdx.x;
    if (b < 128) {                              // dcn2: 131072 = 128 blocks
        int e0 = b * 1024 + threadIdx.x * 4;
        #pragma unroll
        for (int j = 0; j < 4; ++j) {
            int e = e0 + j;
            int co = e >> 10, rem = e & 1023, k = rem >> 6, ci = rem & 63;
            long si = ((long)(co * 64 + ci)) * 16 + k;
            float v = bf ? ldT<1>(w2, si) : ldT<0>(w2, si);
            wb2[e] = fToBits(v);
        }
    } else if (b < 640) {                       // dcn3: 524288 = 512 blocks
        int e0 = (b - 128) * 1024 + threadIdx.x * 4;
        #pragma unroll
        for (int j = 0; j < 4; ++j) {
            int e = e0 + j;
            int co = e >> 11, rem = e & 2047, k = rem >> 7, ci = rem & 127;
            long si = ((long)(co * 128 + ci)) * 16 + k;
            float v = bf ? ldT<1>(w3, si) : ldT<0>(w3, si);
            wb3[e] = fToBits(v);
        }
    } else if (b < 665) {                       // off1: 160x160 = 25 blocks
        int e0 = (b - 640) * 1024 + threadIdx.x * 4;
        #pragma unroll
        for (int j = 0; j < 4; ++j) {
            int e = e0 + j;
            int co = e / 160, k = e - co * 160;
            float v = 0.f;
            if (co < 147 && k < 147) {
                long si = (long)co * 147 + k;
                v = bf ? ldT<1>(w1o, si) : ldT<0>(w1o, si);
            }
            wb1o[e] = fToBits(v);
        }
    } else if (b < 675) {                       // dcn1: 64x160 = 10 blocks
        int e0 = (b - 665) * 1024 + threadIdx.x * 4;
        #pragma unroll
        for (int j = 0; j < 4; ++j) {
            int e = e0 + j;
            int co = e / 160, k = e - co * 160;
            float v = 0.f;
            if (k < 147) {
                long si = (long)co * 147 + k;
                v = bf ? ldT<1>(w1d, si) : ldT<0>(w1d, si);
            }
            wb1d[e] = fToBits(v);
        }
    } else if (b < 739) {                       // off2 pad64: 65536 = 64 blocks
        int e0 = (b - 675) * 1024 + threadIdx.x * 4;
        #pragma unroll
        for (int j = 0; j < 4; ++j) {
            int e = e0 + j;
            int co = e >> 10, rem = e & 1023, k = rem >> 6, ci = rem & 63;
            float v = 0.f;
            if (co < 48) {
                long si = ((long)(co * 64 + ci)) * 16 + k;
                v = bf ? ldT<1>(w2o, si) : ldT<0>(w2o, si);
            }
            wb2o[e] = fToBits(v);
        }
    } else {                                    // off3 pad64: 131072 = 128 blocks
        int e0 = (b - 739) * 1024 + threadIdx.x * 4;
        #pragma unroll
        for (int j = 0; j < 4; ++j) {
            int e = e0 + j;
            int co = e >> 11, rem = e & 2047, k = rem >> 7, ci = rem & 127;
            float v = 0.f;
            if (co < 48) {
                long si = ((long)(co * 128 + ci)) * 16 + k;
                v = bf ? ldT<1>(w3o, si) : ldT<0>(w3o, si);
            }
            wb3o[e] = fToBits(v);
        }
    }
}

// ---- res weights: src[co][ci*9+q] (flag dtype) -> bf16 [q][co][ci] --------
struct RbPack { const void* src[4]; };
__global__ __launch_bounds__(TPB) void repack_rb_kernel(
    RbPack rp, float* fw, const int* dflag)
{
    __shared__ unsigned short lw[4 * 2304];
    int b = blockIdx.x;
    int ten = b >> 6;
    int co0 = (b & 63) * 4;
    const void* src = rp.src[ten];
    const long dstOff[4] = {RB1W1T, RB1W2T, RB2W1T, RB2W2T};
    unsigned short* dst = (unsigned short*)(fw + dstOff[ten]);
    int bf = *dflag;
    int t = threadIdx.x;
    for (int e = t; e < 4 * 2304; e += TPB) {
        int coL = e / 2304, i = e - coL * 2304;
        long si = (long)(co0 + coL) * 2304 + i;
        float v = bf ? ldT<1>(src, si) : ldT<0>(src, si);
        lw[e] = fToBits(v);
    }
    __syncthreads();
    for (int e = t; e < 9216; e += TPB) {     // 9216 = 9q * 4co * 256ci
        int ci = e & 255, coL = (e >> 8) & 3, q = e >> 10;
        dst[((long)q * 256 + co0 + coL) * 256 + ci] = lw[coL * 2304 + ci * 9 + q];
    }
}

// ===========================================================================
// x (NCHW flag dtype, 3ch) -> x4 bf16 [n][256][256][4] (ch 3 = 0 pad).
// ===========================================================================
template<int BF>
__device__ void x_to_cl4_body(const void* __restrict__ x, unsigned short* __restrict__ x4)
{
    long gid = (long)blockIdx.x * TPB + threadIdx.x;   // 0..131071
    int n = (int)(gid >> 16); int p = (int)(gid & 65535);
    long xb = (long)n * 3 * 65536 + p;
    unsigned c0 = fToBits(ldT<BF>(x, xb));
    unsigned c1 = fToBits(ldT<BF>(x, xb + 65536));
    unsigned c2 = fToBits(ldT<BF>(x, xb + 131072));
    uint2 v; v.x = c0 | (c1 << 16); v.y = c2;
    *(uint2*)&x4[gid * 4] = v;
}
__global__ __launch_bounds__(TPB) void x_to_cl4_kernel(
    const void* x, unsigned short* x4, const int* dflag)
{
    if (*dflag) x_to_cl4_body<1>(x, x4);
    else        x_to_cl4_body<0>(x, x4);
}

// ===========================================================================
// MFMA fused layer 1 v4 (validated round 8)
// ===========================================================================
template<int BF>
__device__ void layer1_mfma_body(
    const unsigned short* __restrict__ x4all, const unsigned short* __restrict__ wo,
    const unsigned short* __restrict__ wd, const float* __restrict__ bias1,
    const float* __restrict__ bias2, void* __restrict__ out, long obase,
    float* xs, unsigned short* A, float* offs)
{
    int b = blockIdx.x;
    int n = b >> 11;
    int ho = (b >> 3) & 255;
    int wo0 = (b & 7) << 5;
    const unsigned short* x4 = x4all + ((long)n << 16) * 4;
    int t = threadIdx.x;

    // ---- phase 1a: stage x patch [3ci][7ky][40 cols] from x4 (8B loads) --
    for (int e = t; e < 7 * 40; e += TPB) {
        int cc = e % 40, rr = e / 40;
        int yy = ho - 3 + rr; int xx = wo0 - 3 + cc;
        float c0 = 0.f, c1 = 0.f, c2 = 0.f;
        if (cc < 38 && yy >= 0 && yy < 256 && xx >= 0 && xx < 256) {
            uint2 v = *(const uint2*)&x4[((long)yy * 256 + xx) * 4];
            c0 = bitsToF((unsigned short)(v.x & 0xffff));
            c1 = bitsToF((unsigned short)(v.x >> 16));
            c2 = bitsToF((unsigned short)(v.y & 0xffff));
        }
        xs[(0 * 7 + rr) * 40 + cc] = c0;
        xs[(1 * 7 + rr) * 40 + cc] = c1;
        xs[(2 * 7 + rr) * 40 + cc] = c2;
    }
    __syncthreads();

    // ---- phase 1b: im2col -> A[kc][m][32] bf16, k = ci*49+ky*7+kx --------
    for (int e = t; e < 5120; e += TPB) {
        int kin = e & 31, m = (e >> 5) & 31, kc = e >> 10;
        int k = kc * 32 + kin;
        float v = 0.f;
        if (k < 147) {
            int ci = k / 49, q = k - ci * 49;
            int ky = q / 7, kx = q - ky * 7;
            v = xs[(ci * 7 + ky) * 40 + m + kx];
        }
        A[kc * 1024 + m * 32 + kin] = fToBits(v);
    }
    __syncthreads();

    int wv = t >> 6, lane = t & 63;
    int quad = lane >> 4, l16 = lane & 15;
    int mt = wv & 1, ntb = wv >> 1;

    // ---- phase 2: MFMA offset conv (N=160, 10 n-tiles over 2 wave-groups)-
    {
        f32x4 acc[5];
        #pragma unroll
        for (int j = 0; j < 5; ++j) acc[j] = (f32x4){0.f, 0.f, 0.f, 0.f};
        #pragma unroll
        for (int kc = 0; kc < 5; ++kc) {
            bf16x8 a = *(const bf16x8*)&A[(kc * 32 + mt * 16 + l16) * 32 + quad * 8];
            #pragma unroll
            for (int j = 0; j < 5; ++j) {
                int ch = (ntb + 2 * j) * 16 + l16;
                bf16x8 bw = *(const bf16x8*)&wo[ch * 160 + kc * 32 + quad * 8];
                acc[j] = __builtin_amdgcn_mfma_f32_16x16x32_bf16(a, bw, acc[j], 0, 0, 0);
            }
        }
        #pragma unroll
        for (int j = 0; j < 5; ++j) {
            int ch = (ntb + 2 * j) * 16 + l16;
            if (ch < 147) {
                float bv = bias1[ch];
                #pragma unroll
                for (int reg = 0; reg < 4; ++reg) {
                    int m = mt * 16 + quad * 4 + reg;
                    offs[ch * 33 + m] = acc[j][reg] + bv;
                }
            }
        }
    }
    __syncthreads();

    // ---- phase 3: p in lane (coalesced 8B taps); in-place sample write ----
    for (int e = t; e < 49 * 32; e += TPB) {
        int p = e & 31; int k = e >> 5;
        float oy = offs[k * 33 + p];
        float ox = offs[(49 + k) * 33 + p];
        float mr = offs[(98 + k) * 33 + p];
        float m = 1.f / (1.f + expf(-mr));
        float py = (float)(ho - 3 + k / 7) + oy;
        float px = (float)(wo0 + p - 3 + k % 7) + ox;
        float y0f = floorf(py), x0f = floorf(px);
        float wy = py - y0f, wx = px - x0f;
        int y0 = (int)y0f, x0 = (int)x0f;
        bool yv0 = (y0 >= 0) && (y0 < 256);
        bool yv1 = (y0 + 1 >= 0) && (y0 + 1 < 256);
        bool xv0 = (x0 >= 0) && (x0 < 256);
        bool xv1 = (x0 + 1 >= 0) && (x0 + 1 < 256);
        int y0c = min(max(y0, 0), 255), y1c = min(max(y0 + 1, 0), 255);
        int x0c = min(max(x0, 0), 255), x1c = min(max(x0 + 1, 0), 255);
        float w00 = (yv0 && xv0) ? (1.f - wy) * (1.f - wx) * m : 0.f;
        float w01 = (yv0 && xv1) ? (1.f - wy) * wx * m : 0.f;
        float w10 = (yv1 && xv0) ? wy * (1.f - wx) * m : 0.f;
        float w11 = (yv1 && xv1) ? wy * wx * m : 0.f;
        uint2 a00 = *(const uint2*)&x4[((long)y0c * 256 + x0c) * 4];
        uint2 a01 = *(const uint2*)&x4[((long)y0c * 256 + x1c) * 4];
        uint2 a10 = *(const uint2*)&x4[((long)y1c * 256 + x0c) * 4];
        uint2 a11 = *(const uint2*)&x4[((long)y1c * 256 + x1c) * 4];
        float s0 = w00 * bitsToF((unsigned short)(a00.x & 0xffff))
                 + w01 * bitsToF((unsigned short)(a01.x & 0xffff))
                 + w10 * bitsToF((unsigned short)(a10.x & 0xffff))
                 + w11 * bitsToF((unsigned short)(a11.x & 0xffff));
        float s1 = w00 * bitsToF((unsigned short)(a00.x >> 16))
                 + w01 * bitsToF((unsigned short)(a01.x >> 16))
                 + w10 * bitsToF((unsigned short)(a10.x >> 16))
                 + w11 * bitsToF((unsigned short)(a11.x >> 16));
        float s2 = w00 * bitsToF((unsigned short)(a00.y & 0xffff))
                 + w01 * bitsToF((unsigned short)(a01.y & 0xffff))
                 + w10 * bitsToF((unsigned short)(a10.y & 0xffff))
                 + w11 * bitsToF((unsigned short)(a11.y & 0xffff));
        offs[k * 33 + p] = s0;               // in-place, thread-local RAW
        offs[(49 + k) * 33 + p] = s1;
        offs[(98 + k) * 33 + p] = s2;
    }
    __syncthreads();

    // ---- phase 3.5: repack offs(f32) -> A(bf16 MFMA layout) --------------
    for (int e = t; e < 5120; e += TPB) {
        int kin = e & 31, m = (e >> 5) & 31, kc = e >> 10;
        int k = kc * 32 + kin;
        float v = 0.f;
        if (k < 147) v = offs[k * 33 + m];
        A[kc * 1024 + m * 32 + kin] = fToBits(v);
    }
    __syncthreads();

    // ---- phase 4: MFMA deform conv (N=64, 4 n-tiles) ---------------------
    f32x4 acc2[2];
    acc2[0] = (f32x4){0.f, 0.f, 0.f, 0.f};
    acc2[1] = (f32x4){0.f, 0.f, 0.f, 0.f};
    #pragma unroll
    for (int kc = 0; kc < 5; ++kc) {
        bf16x8 a = *(const bf16x8*)&A[(kc * 32 + mt * 16 + l16) * 32 + quad * 8];
        #pragma unroll
        for (int j = 0; j < 2; ++j) {
            int co = (ntb + 2 * j) * 16 + l16;
            bf16x8 bw = *(const bf16x8*)&wd[co * 160 + kc * 32 + quad * 8];
            acc2[j] = __builtin_amdgcn_mfma_f32_16x16x32_bf16(a, bw, acc2[j], 0, 0, 0);
        }
    }
    #pragma unroll
    for (int j = 0; j < 2; ++j) {
        int co = (ntb + 2 * j) * 16 + l16;
        float bv = bias2[co];
        #pragma unroll
        for (int reg = 0; reg < 4; ++reg) {
            int wox = wo0 + mt * 16 + quad * 4 + reg;
            long oi = obase + ((long)(n * 64 + co) * 256 + ho) * 256 + wox;
            stT<BF>(out, oi, acc2[j][reg] + bv);
        }
    }
}

__global__ __launch_bounds__(TPB) void layer1_mfma_kernel(
    const unsigned short* x4, const unsigned short* wo, const unsigned short* wd,
    const float* bias1, const float* bias2, void* out, long obase, const int* dflag)
{
    __shared__ __align__(16) float xs[3 * 7 * 40];
    __shared__ __align__(16) unsigned short A[5120];
    __shared__ __align__(16) float offs[147 * 33];
    if (*dflag) layer1_mfma_body<1>(x4, wo, wd, bias1, bias2, out, obase, xs, A, offs);
    else        layer1_mfma_body<0>(x4, wo, wd, bias1, bias2, out, obase, xs, A, offs);
}

// ===========================================================================
// MFMA offset conv (layers 2/3) v2: staging vectorized to 8B uint2
// (4 channels per load; was scalar 2B — 4x fewer memory instructions).
// ===========================================================================
template<int CIN, int HH, int WW, int HO, int WO>
__global__ __launch_bounds__(TPB) void offconv_mfma_kernel(
    const unsigned short* __restrict__ xcl, const unsigned short* __restrict__ wb,
    const float* __restrict__ bias_f, float* __restrict__ out)
{
    constexpr int S   = 16 * CIN;
    constexpr int KL  = 512 / CIN;       // taps per 512-i chunk
    constexpr int NCH = 16 / KL;
    constexpr int CH4 = CIN / 4;         // 8B units per (pair, tap)
    constexpr int UN  = (KL * 16 * CH4) / TPB;   // 8B units per thread/chunk
    constexpr int TILES = (HO * WO) / 16;

    __shared__ int tp[256];
    __shared__ __align__(16) unsigned short smp[16 * 512];

    int tile = blockIdx.x % TILES;
    int n    = blockIdx.x / TILES;
    int lp0  = tile * 16;

    // ---- fixed-tap address table: one (k,p) per thread ----
    {
        int pr = threadIdx.x;
        int k = pr >> 4, p = pr & 15;
        int lp = lp0 + p;
        int ho = lp / WO, wo = lp - ho * WO;
        int yy = ho * 2 - 1 + (k >> 2);
        int xx = wo * 2 - 1 + (k & 3);
        bool valid = (yy >= 0) && (yy < HH) && (xx >= 0) && (xx < WW);
        tp[pr] = valid ? (yy * WW + xx) * CIN : -1;
    }

    int wv = threadIdx.x >> 6, lane = threadIdx.x & 63;
    int quad = lane >> 4, l16 = lane & 15;
    const unsigned short* xn = xcl + (long)n * HH * WW * CIN;

    f32x4 acc = (f32x4){0.f, 0.f, 0.f, 0.f};

    for (int ch = 0; ch < NCH; ++ch) {
        __syncthreads();
        #pragma unroll
        for (int u = 0; u < UN; ++u) {
            int e   = u * TPB + threadIdx.x;
            int prl = e / CH4;
            int ci  = (e - prl * CH4) * 4;
            int pi  = ch * (KL * 16) + prl;
            int kl = prl >> 4, p = prl & 15;
            int t0 = tp[pi];
            uint2 v = (t0 >= 0) ? *(const uint2*)(xn + t0 + ci) : (uint2){0u, 0u};
            int il = kl * CIN + ci;
            *(uint2*)&smp[((il >> 5) * 16 + p) * 32 + (il & 31)] = v;
        }
        __syncthreads();
        #pragma unroll 4
        for (int kk = 0; kk < 16; ++kk) {
            bf16x8 a = *(const bf16x8*)&smp[(kk * 16 + l16) * 32 + quad * 8];
            int co = wv * 16 + l16;
            bf16x8 b = *(const bf16x8*)&wb[(long)co * S + ch * 512 + kk * 32 + quad * 8];
            acc = __builtin_amdgcn_mfma_f32_16x16x32_bf16(a, b, acc, 0, 0, 0);
        }
    }

    int co = wv * 16 + l16;
    if (co < 48) {
        float bv = bias_f[co];
        #pragma unroll
        for (int reg = 0; reg < 4; ++reg) {
            int lp = lp0 + quad * 4 + reg;
            int ho = lp / WO, wo = lp - ho * WO;
            out[((long)(n * 48 + co) * HO + ho) * WO + wo] = acc[reg] + bv;
        }
    }
}

// ===========================================================================
// NCHW (flag dtype) -> channels-last bf16 transpose. 64 pixels x C per block.
// ===========================================================================
template<int C>
__global__ __launch_bounds__(TPB) void nchw_to_cl_kernel(
    const void* __restrict__ in, long ibase, unsigned short* __restrict__ out,
    int HW, const int* __restrict__ dflag)
{
    __shared__ unsigned short tile[C * 65];
    int bf = *dflag;
    int n   = (blockIdx.x * 64) / HW;
    int px0 = (blockIdx.x * 64) % HW;
    for (int e = threadIdx.x; e < C * 64; e += TPB) {
        int c = e >> 6, p = e & 63;
        long si = ibase + (long)(n * C + c) * HW + px0 + p;
        float v = bf ? ldT<1>(in, si) : ldT<0>(in, si);
        tile[c * 65 + p] = fToBits(v);
    }
    __syncthreads();
    for (int e = threadIdx.x; e < C * 64; e += TPB) {
        int p = e / C, c = e - p * C;
        out[((long)n * HW + px0 + p) * C + c] = tile[c * 65 + p];
    }
}

// ===========================================================================
// MFMA deformable conv v3 (layers 2/3): gather vectorized to 8B uint2
// (4 channels per tap load; ITER halved vs v2). Tap base multiple of CIN
// (>=64) and ci multiple of 4 keep all loads 8B-aligned.
// ===========================================================================
template<int MODE, int CIN, int COUT, int NWAVES, int HH, int WW, int HO, int WO>
__global__ __launch_bounds__(NWAVES * 64) void deform_mfma_kernel(
    const unsigned short* __restrict__ xcl, const float* __restrict__ off,
    const unsigned short* __restrict__ wb, const float* __restrict__ bias_f,
    void* __restrict__ outp, long obase, const int* __restrict__ dflag)
{
    constexpr int TPBk = NWAVES * 64;
    constexpr int S    = 16 * CIN;       // reduction length
    constexpr int KL   = 512 / CIN;      // kernel-points per 512-i chunk
    constexpr int NCH  = 16 / KL;        // chunks
    constexpr int CH4  = CIN / 4;        // 8B units per (pair, tap)
    constexpr int ITER = (KL * 16 * CH4) / TPBk;   // 8B units per thread/chunk
    constexpr int TILES = (HO * WO) / 16;

    __shared__ __align__(16) int tpw[256][8];      // [pair]{tp0..3, w0..3bits}
    __shared__ __align__(16) unsigned short smp[16 * 512];

    int tile = blockIdx.x % TILES;
    int n    = blockIdx.x / TILES;
    int lp0  = tile * 16;
    int tid  = threadIdx.x;

    // ---- phase A: per-(k,p) offset decode, one pair per thread (first 256)-
    if (tid < 256) {
        int pr = tid;
        int k = pr >> 4, p = pr & 15;
        int lp = lp0 + p;
        int ho = lp / WO, wo = lp - ho * WO;
        long plane = (long)HO * WO;
        const float* offn = off + (long)n * 48 * plane;
        float oy = offn[(long)k * plane + lp];
        float ox = offn[(long)(16 + k) * plane + lp];
        float mr = offn[(long)(32 + k) * plane + lp];
        float m = 1.f / (1.f + expf(-mr));
        float py = (float)(ho * 2 - 1 + (k >> 2)) + oy;
        float px = (float)(wo * 2 - 1 + (k & 3)) + ox;
        float y0f = floorf(py), x0f = floorf(px);
        float wy = py - y0f, wx = px - x0f;
        int y0 = (int)y0f, x0 = (int)x0f;
        bool yv0 = (y0 >= 0) && (y0 < HH);
        bool yv1 = (y0 + 1 >= 0) && (y0 + 1 < HH);
        bool xv0 = (x0 >= 0) && (x0 < WW);
        bool xv1 = (x0 + 1 >= 0) && (x0 + 1 < WW);
        int y0c = min(max(y0, 0), HH - 1), y1c = min(max(y0 + 1, 0), HH - 1);
        int x0c = min(max(x0, 0), WW - 1), x1c = min(max(x0 + 1, 0), WW - 1);
        tpw[pr][0] = (y0c * WW + x0c) * CIN;
        tpw[pr][1] = (y0c * WW + x1c) * CIN;
        tpw[pr][2] = (y1c * WW + x0c) * CIN;
        tpw[pr][3] = (y1c * WW + x1c) * CIN;
        tpw[pr][4] = __float_as_int((yv0 && xv0) ? (1.f - wy) * (1.f - wx) * m : 0.f);
        tpw[pr][5] = __float_as_int((yv0 && xv1) ? (1.f - wy) * wx * m : 0.f);
        tpw[pr][6] = __float_as_int((yv1 && xv0) ? wy * (1.f - wx) * m : 0.f);
        tpw[pr][7] = __float_as_int((yv1 && xv1) ? wy * wx * m : 0.f);
    }

    int wv = tid >> 6, lane = tid & 63;
    int quad = lane >> 4, l16 = lane & 15;
    int cb = (wv & 3) * 32 + (wv >> 2) * (COUT / 2);
    const unsigned short* xn = xcl + (long)n * HH * WW * CIN;

    f32x4 acc[2];
    acc[0] = (f32x4){0.f, 0.f, 0.f, 0.f};
    acc[1] = (f32x4){0.f, 0.f, 0.f, 0.f};

    for (int ch = 0; ch < NCH; ++ch) {
        __syncthreads();   // covers phase A (ch=0) and prev MFMA reads
        #pragma unroll
        for (int it = 0; it < ITER; ++it) {
            int e   = it * TPBk + tid;
            int prl = e / CH4;                  // pair within chunk
            int ci  = (e - prl * CH4) * 4;      // ci multiple of 4
            int pi  = ch * (KL * 16) + prl;
            const int4   tp4 = *(const int4*)&tpw[pi][0];
            const float4 tw4 = *(const float4*)&tpw[pi][4];
            uint2 u0 = *(const uint2*)(xn + tp4.x + ci);
            uint2 u1 = *(const uint2*)(xn + tp4.y + ci);
            uint2 u2 = *(const uint2*)(xn + tp4.z + ci);
            uint2 u3 = *(const uint2*)(xn + tp4.w + ci);
            float r0 = tw4.x * bitsToF((unsigned short)(u0.x & 0xffff))
                     + tw4.y * bitsToF((unsigned short)(u1.x & 0xffff))
                     + tw4.z * bitsToF((unsigned short)(u2.x & 0xffff))
                     + tw4.w * bitsToF((unsigned short)(u3.x & 0xffff));
            float r1 = tw4.x * bitsToF((unsigned short)(u0.x >> 16))
                     + tw4.y * bitsToF((unsigned short)(u1.x >> 16))
                     + tw4.z * bitsToF((unsigned short)(u2.x >> 16))
                     + tw4.w * bitsToF((unsigned short)(u3.x >> 16));
            float r2 = tw4.x * bitsToF((unsigned short)(u0.y & 0xffff))
                     + tw4.y * bitsToF((unsigned short)(u1.y & 0xffff))
                     + tw4.z * bitsToF((unsigned short)(u2.y & 0xffff))
                     + tw4.w * bitsToF((unsigned short)(u3.y & 0xffff));
            float r3 = tw4.x * bitsToF((unsigned short)(u0.y >> 16))
                     + tw4.y * bitsToF((unsigned short)(u1.y >> 16))
                     + tw4.z * bitsToF((unsigned short)(u2.y >> 16))
                     + tw4.w * bitsToF((unsigned short)(u3.y >> 16));
            uint2 ov;
            ov.x = (unsigned)fToBits(r0) | ((unsigned)fToBits(r1) << 16);
            ov.y = (unsigned)fToBits(r2) | ((unsigned)fToBits(r3) << 16);
            int il = (prl >> 4) * CIN + ci;     // i within chunk [0,512)
            int p  = prl & 15;
            *(uint2*)&smp[((il >> 5) * 16 + p) * 32 + (il & 31)] = ov;
        }
        __syncthreads();
        #pragma unroll 4
        for (int kk = 0; kk < 16; ++kk) {
            bf16x8 a = *(const bf16x8*)&smp[(kk * 16 + l16) * 32 + quad * 8];
            #pragma unroll
            for (int f = 0; f < 2; ++f) {
                int co = cb + f * 16 + l16;
                bf16x8 b = *(const bf16x8*)&wb[(long)co * S + ch * 512 + kk * 32 + quad * 8];
                acc[f] = __builtin_amdgcn_mfma_f32_16x16x32_bf16(a, b, acc[f], 0, 0, 0);
            }
        }
    }

    // ---- epilogue: pixel = quad*4+reg, co = cb + f*16 + l16 ----
    if (MODE == 1) {
        unsigned short* oCL = (unsigned short*)outp;
        #pragma unroll
        for (int f = 0; f < 2; ++f) {
            int co = cb + f * 16 + l16;
            float bv = bias_f[co];
            #pragma unroll
            for (int reg = 0; reg < 4; ++reg) {
                int lp = lp0 + quad * 4 + reg;
                oCL[((long)n * HO * WO + lp) * COUT + co] = fToBits(acc[f][reg] + bv);
            }
        }
    } else {
        int bf = *dflag;
        #pragma unroll
        for (int f = 0; f < 2; ++f) {
            int co = cb + f * 16 + l16;
            float bv = bias_f[co];
            #pragma unroll
            for (int reg = 0; reg < 4; ++reg) {
                int lp = lp0 + quad * 4 + reg;
                int ho = lp / WO, wo = lp - ho * WO;
                long oi = obase + ((long)(n * COUT + co) * HO + ho) * WO + wo;
                if (bf) stT<1>(outp, oi, acc[f][reg] + bv);
                else    stT<0>(outp, oi, acc[f][reg] + bv);
            }
        }
    }
}

// ===========================================================================
// MFMA res-block 3x3 reflect conv v2 (validated round 4/8)
// ===========================================================================
__global__ __launch_bounds__(TPB) void resconv_mfma_kernel(
    const unsigned short* __restrict__ X, const unsigned short* __restrict__ W,
    const float* __restrict__ bias_f, bf16* __restrict__ Y)
{
    __shared__ __align__(16) unsigned short xs[3 * 66 * 64];   // 25344 B, swizzled
    int b = blockIdx.x;
    int coO = b & 7, r = (b >> 3) & 63, n = b >> 9;
    int t = threadIdx.x;
    int wv = t >> 6;
    int lane = t & 63;
    int quad = lane >> 4, l16 = lane & 15;
    int rows[3];
    rows[0] = (r == 0) ? 1 : r - 1;
    rows[1] = r;
    rows[2] = (r == 63) ? 62 : r + 1;

    f32x4 acc[2];
    acc[0] = (f32x4){0.f, 0.f, 0.f, 0.f};
    acc[1] = (f32x4){0.f, 0.f, 0.f, 0.f};

    long xbase = (long)n * 4096 * 256;

    for (int ci0 = 0; ci0 < 256; ci0 += 64) {
        __syncthreads();
        // stage [3ky][66col][64ci] via 16B loads; swizzled 16B slot per col
        for (int e = t; e < 3 * 66 * 8; e += TPB) {
            int oct = e & 7;
            int col = (e >> 3) % 66;
            int ky  = e / (66 * 8);
            int gx = col - 1;
            gx = (gx < 0) ? 1 : ((gx > 63) ? 62 : gx);
            bf16x8 v = *(const bf16x8*)&X[xbase + ((long)rows[ky] * 64 + gx) * 256 + ci0 + oct * 8];
            int slot = oct ^ (col & 7);
            *(bf16x8*)&xs[((ky * 66 + col) << 6) + slot * 8] = v;
        }
        __syncthreads();
        #pragma unroll
        for (int q = 0; q < 9; ++q) {
            int ky = q / 3, kx = q % 3;
            int col = wv * 16 + l16 + kx;        // lds col = global col +1
            int base = (ky * 66 + col) << 6;
            #pragma unroll
            for (int kh = 0; kh < 2; ++kh) {
                int slot = (kh * 4 + quad) ^ (col & 7);
                bf16x8 a = *(const bf16x8*)&xs[base + slot * 8];
                #pragma unroll
                for (int ct = 0; ct < 2; ++ct) {
                    int co = coO * 32 + ct * 16 + l16;
                    bf16x8 bw = *(const bf16x8*)&W[((long)q * 256 + co) * 256 + ci0 + kh * 32 + quad * 8];
                    acc[ct] = __builtin_amdgcn_mfma_f32_16x16x32_bf16(a, bw, acc[ct], 0, 0, 0);
                }
            }
        }
    }

    long ybase = ((long)n * 4096 + (long)r * 64) * 256;
    #pragma unroll
    for (int ct = 0; ct < 2; ++ct) {
        int co = coO * 32 + ct * 16 + l16;
        float bv = bias_f[co];
        #pragma unroll
        for (int reg = 0; reg < 4; ++reg) {
            int px = wv * 16 + quad * 4 + reg;
            Y[ybase + (long)px * 256 + co] = __float2bfloat16(acc[ct][reg] + bv);
        }
    }
}

// ===========================================================================
// Channels-last instance-norm: WIDE partial stats (validated round 10)
// ===========================================================================
__global__ __launch_bounds__(TPB) void cl_stats_kernel(
    const unsigned short* __restrict__ X, float* __restrict__ psum, float* __restrict__ psq)
{
    int blk = blockIdx.x;
    int chunk = blk & 63, n = blk >> 6;
    int co = threadIdx.x;
    float s = 0.f, sq = 0.f;
    const unsigned short* p = X + ((long)n * 4096 + chunk * 64) * 256 + co;
    #pragma unroll 8
    for (int i = 0; i < 64; ++i) {
        float v = bitsToF(p[(long)i * 256]);
        s += v; sq += v * v;
    }
    psum[(n * 64 + chunk) * 256 + co] = s;
    psq [(n * 64 + chunk) * 256 + co] = sq;
}

__device__ __forceinline__ void cl_load_stats(
    const float* psum, const float* psq, int n, float* mv, float* iv)
{
    int t = threadIdx.x;   // t = channel
    float s = 0.f, sq = 0.f;
    #pragma unroll 8
    for (int c = 0; c < 64; ++c) {
        s  += psum[(n * 64 + c) * 256 + t];
        sq += psq [(n * 64 + c) * 256 + t];
    }
    float mean = s / 4096.f;
    mv[t] = mean;
    iv[t] = rsqrtf(sq / 4096.f - mean * mean + 1e-5f);
    __syncthreads();
}

// grid 128 = n*64 + y; in-place X = relu?((X-m)*inv), uint-vectorized
__global__ __launch_bounds__(TPB) void cl_apply_kernel(
    unsigned short* __restrict__ X, const float* __restrict__ psum,
    const float* __restrict__ psq, int relu)
{
    __shared__ float mv[256], iv[256];
    int y = blockIdx.x & 63, n = blockIdx.x >> 6;
    cl_load_stats(psum, psq, n, mv, iv);
    unsigned* row = (unsigned*)(X + ((long)n * 4096 + y * 64) * 256);
    for (int e = threadIdx.x; e < 8192; e += TPB) {
        int co = (e * 2) & 255;
        unsigned u = row[e];
        float v0 = (bitsToF((unsigned short)(u & 0xffff)) - mv[co]) * iv[co];
        float v1 = (bitsToF((unsigned short)(u >> 16)) - mv[co + 1]) * iv[co + 1];
        if (relu) { v0 = fmaxf(v0, 0.f); v1 = fmaxf(v1, 0.f); }
        row[e] = (unsigned)fToBits(v0) | ((unsigned)fToBits(v1) << 16);
    }
}

// grid 128; H += IN(T), uint-vectorized
__global__ __launch_bounds__(TPB) void cl_apply_add_kernel(
    const unsigned short* __restrict__ T, unsigned short* __restrict__ H,
    const float* __restrict__ psum, const float* __restrict__ psq)
{
    __shared__ float mv[256], iv[256];
    int y = blockIdx.x & 63, n = blockIdx.x >> 6;
    cl_load_stats(psum, psq, n, mv, iv);
    long base = ((long)n * 4096 + y * 64) * 256;
    const unsigned* tr = (const unsigned*)(T + base);
    unsigned* hr = (unsigned*)(H + base);
    for (int e = threadIdx.x; e < 8192; e += TPB) {
        int co = (e * 2) & 255;
        unsigned ut = tr[e], uh = hr[e];
        float v0 = bitsToF((unsigned short)(uh & 0xffff))
                 + (bitsToF((unsigned short)(ut & 0xffff)) - mv[co]) * iv[co];
        float v1 = bitsToF((unsigned short)(uh >> 16))
                 + (bitsToF((unsigned short)(ut >> 16)) - mv[co + 1]) * iv[co + 1];
        hr[e] = (unsigned)fToBits(v0) | ((unsigned)fToBits(v1) << 16);
    }
}

// grid 128; out(NCHW, flag dtype) = H + IN(T)   (transposes channels-last)
__global__ __launch_bounds__(TPB) void cl_apply_final_kernel(
    const unsigned short* __restrict__ T, const unsigned short* __restrict__ H,
    void* __restrict__ outp, const float* __restrict__ psum,
    const float* __restrict__ psq, const int* __restrict__ dflag)
{
    __shared__ float mv[256], iv[256];
    int y = blockIdx.x & 63, n = blockIdx.x >> 6;
    cl_load_stats(psum, psq, n, mv, iv);
    int bf = *dflag;
    int x = threadIdx.x & 63, cg = threadIdx.x >> 6;
    for (int co = cg; co < 256; co += 4) {
        long cli = ((long)(n * 64 + y) * 64 + x) * 256 + co;
        float v = bitsToF(H[cli]) + (bitsToF(T[cli]) - mv[co]) * iv[co];
        long oi = (((long)(n * 256 + co)) * 64 + y) * 64 + x;
        if (bf) ((bf16*)outp)[oi] = __float2bfloat16(v);
        else    ((float*)outp)[oi] = v;
    }
}

// ---------------- block reduction (up to 16 waves) -------------------------
__device__ __forceinline__ void reduce2(float& sum, float& sq, float* s1, float* s2)
{
    for (int off = 32; off; off >>= 1) {
        sum += __shfl_down(sum, off, 64);
        sq  += __shfl_down(sq,  off, 64);
    }
    int nw = blockDim.x >> 6;
    int wid = threadIdx.x >> 6;
    if ((threadIdx.x & 63) == 0) { s1[wid] = sum; s2[wid] = sq; }
    __syncthreads();
    sum = 0.f; sq = 0.f;
    for (int w = 0; w < nw; ++w) { sum += s1[w]; sq += s2[w]; }
}

// ---------------- instance norm for skip1/skip2 (d_out, flag dtype) --------
__global__ void instnorm_kernel(
    void* __restrict__ buf, long base0, const int* __restrict__ dflag,
    int HW, int relu)
{
    __shared__ float s1[16], s2[16];
    int bf = *dflag;
    long base = base0 + (long)blockIdx.x * HW;
    float sum = 0.f, sq = 0.f;
    for (int i = threadIdx.x; i < HW; i += blockDim.x) {
        float v = bf ? bitsToF(((const unsigned short*)buf)[base + i])
                     : ((const float*)buf)[base + i];
        sum += v; sq += v * v;
    }
    reduce2(sum, sq, s1, s2);
    float mean = sum / HW;
    float inv = rsqrtf(sq / HW - mean * mean + 1e-5f);
    for (int i = threadIdx.x; i < HW; i += blockDim.x) {
        float v = bf ? bitsToF(((const unsigned short*)buf)[base + i])
                     : ((const float*)buf)[base + i];
        v = (v - mean) * inv;
        if (relu) v = fmaxf(v, 0.f);
        if (bf) ((bf16*)buf)[base + i] = __float2bfloat16(v);
        else    ((float*)buf)[base + i] = v;
    }
}

// ---------------------------------------------------------------------------
extern "C" void kernel_launch(void* const* d_in, const int* in_sizes, int n_in,
                              void* d_out, int out_size, void* d_ws, size_t ws_size,
                              hipStream_t stream) {
    const void* x = d_in[0];

    const long SKIP1 = 2097152;
    const long SKIP2 = 10485760;

    int* dflag = (int*)d_ws;
    float* fw = (float*)((char*)d_ws + 64);

    unsigned short* t1 = (unsigned short*)(fw + FB);
    unsigned short* t2 = (unsigned short*)(fw + FB + 1048576);
    unsigned short* h3 = (unsigned short*)(fw + H3F);
    float* offb = fw + OFFB;
    unsigned short* x4 = (unsigned short*)(fw + OFFB);   // layer-1 only; dead after
    float* psum = fw + PST1;
    float* psq  = fw + PST2;
    unsigned short* clbuf = (unsigned short*)(fw + CLBUF);    // skip1_cl then skip2_cl
    const unsigned short* wb1o = (const unsigned short*)(fw + WB1OT);
    const unsigned short* wb1d = (const unsigned short*)(fw + WB1DT);
    const unsigned short* wb2o = (const unsigned short*)(fw + WO2T);
    const unsigned short* wb3o = (const unsigned short*)(fw + WO3T);
    const unsigned short* wb2 = (const unsigned short*)(fw + WB2T);
    const unsigned short* wb3 = (const unsigned short*)(fw + WB3T);
    const unsigned short* rbw1 = (const unsigned short*)(fw + RB1W1T);
    const unsigned short* rbw2 = (const unsigned short*)(fw + RB1W2T);
    const unsigned short* rbw3 = (const unsigned short*)(fw + RB2W1T);
    const unsigned short* rbw4 = (const unsigned short*)(fw + RB2W2T);

    detect_kernel<<<1, 64, 0, stream>>>(x, dflag);

    // ---- weight/bias repack ----
    PtrPack pp;
    for (int i = 0; i < 10; ++i) pp.p[i] = nullptr;
    pp.p[10] = d_in[2];  pp.p[11] = d_in[4];  pp.p[12] = d_in[6];  pp.p[13] = d_in[8];
    pp.p[14] = d_in[10]; pp.p[15] = d_in[12]; pp.p[16] = d_in[14]; pp.p[17] = d_in[16];
    pp.p[18] = d_in[18]; pp.p[19] = d_in[20];
    repack_all_kernel<<<2, TPB, 0, stream>>>(pp, fw, dflag);
    repack_dcn_kernel<<<867, TPB, 0, stream>>>(
        d_in[7], d_in[11], d_in[1], d_in[3], d_in[5], d_in[9], fw, dflag);
    RbPack rp;
    rp.src[0] = d_in[13]; rp.src[1] = d_in[15]; rp.src[2] = d_in[17]; rp.src[3] = d_in[19];
    repack_rb_kernel<<<256, TPB, 0, stream>>>(rp, fw, dflag);

    // ---- Layer 1 fused MFMA: offsets + deform, 7x7 s1 p3 ----
    x_to_cl4_kernel<<<512, TPB, 0, stream>>>(x, x4, dflag);
    layer1_mfma_kernel<<<4096, TPB, 0, stream>>>(
        x4, wb1o, wb1d, fw + OFF1B, fw + DCN1B, d_out, SKIP1, dflag);
    instnorm_kernel<<<128, 1024, 0, stream>>>(d_out, SKIP1, dflag, 65536, 1);
    // skip1 -> channels-last bf16 for the MFMA conv gathers
    nchw_to_cl_kernel<64><<<2048, TPB, 0, stream>>>(d_out, SKIP1, clbuf, 65536, dflag);

    // ---- Layer 2: 4x4 s2 p1, Cin=64 ----
    offconv_mfma_kernel<64, 256, 256, 128, 128><<<2048, TPB, 0, stream>>>(
        clbuf, wb2o, fw + OFF2B, offb);
    deform_mfma_kernel<0, 64, 128, 4, 256, 256, 128, 128><<<2048, TPB, 0, stream>>>(
        clbuf, offb, wb2, fw + DCN2B, d_out, SKIP2, dflag);
    instnorm_kernel<<<256, 512, 0, stream>>>(d_out, SKIP2, dflag, 16384, 1);
    // skip2 -> channels-last bf16 (reuses clbuf; skip1_cl is dead now)
    nchw_to_cl_kernel<128><<<512, TPB, 0, stream>>>(d_out, SKIP2, clbuf, 16384, dflag);

    // ---- Layer 3: 4x4 s2 p1, Cin=128; output bf16 channels-last h3 ----
    offconv_mfma_kernel<128, 128, 128, 64, 64><<<512, TPB, 0, stream>>>(
        clbuf, wb3o, fw + OFF3B, offb);
    deform_mfma_kernel<1, 128, 256, 8, 128, 128, 64, 64><<<512, 512, 0, stream>>>(
        clbuf, offb, wb3, fw + DCN3B, h3, 0, dflag);
    cl_stats_kernel<<<128, TPB, 0, stream>>>(h3, psum, psq);
    cl_apply_kernel<<<128, TPB, 0, stream>>>(h3, psum, psq, 1);

    // ---- Res block 1 (MFMA) ----
    resconv_mfma_kernel<<<1024, TPB, 0, stream>>>(h3, rbw1, fw + RB1B1, (bf16*)t1);
    cl_stats_kernel<<<128, TPB, 0, stream>>>(t1, psum, psq);
    cl_apply_kernel<<<128, TPB, 0, stream>>>(t1, psum, psq, 1);
    resconv_mfma_kernel<<<1024, TPB, 0, stream>>>(t1, rbw2, fw + RB1B2, (bf16*)t2);
    cl_stats_kernel<<<128, TPB, 0, stream>>>(t2, psum, psq);
    cl_apply_add_kernel<<<128, TPB, 0, stream>>>(t2, h3, psum, psq);

    // ---- Res block 2 (MFMA; final writes NCHW d_out per flag) ----
    resconv_mfma_kernel<<<1024, TPB, 0, stream>>>(h3, rbw3, fw + RB2B1, (bf16*)t1);
    cl_stats_kernel<<<128, TPB, 0, stream>>>(t1, psum, psq);
    cl_apply_kernel<<<128, TPB, 0, stream>>>(t1, psum, psq, 1);
    resconv_mfma_kernel<<<1024, TPB, 0, stream>>>(t1, rbw4, fw + RB2B2, (bf16*)t2);
    cl_stats_kernel<<<128, TPB, 0, stream>>>(t2, psum, psq);
    cl_apply_final_kernel<<<128, TPB, 0, stream>>>(t2, h3, d_out, psum, psq, dflag);
}

// Round 14
// 868.079 us; speedup vs baseline: 1.0732x; 1.0033x over previous
//
#include <hip/hip_runtime.h>
#include <hip/hip_bf16.h>
#include <math.h>

#define TPB 256
typedef __hip_bfloat16 bf16;
typedef short bf16x8 __attribute__((ext_vector_type(8)));   // 8 bf16 (4 VGPRs)
typedef float f32x4 __attribute__((ext_vector_type(4)));

// ---------------- ws layout constants (fp32-element offsets from fw) -------
constexpr long BIASF  = 0;          // 1715 packed fp32 biases (pad to 2048)
constexpr long RB1W1T = 2048;       // res weights bf16 [9][256co][256ci]
constexpr long RB1W2T = 591872;
constexpr long RB2W1T = 1181696;
constexpr long RB2W2T = 1771520;
constexpr long FB     = 2361344;    // multi-use region
constexpr long WB1OT  = 2361344;    // bf16 [160][160] off1 weights (16B aligned)
constexpr long WB1DT  = 2382956;    // bf16 [64][160] dcn1 weights (16B aligned)
constexpr long WO2T   = 2392364;    // bf16 [64co pad][1024] off2 weights
constexpr long WB2T   = 2441516;    // bf16 [128co][1024] deform2 weights (16B aligned)
constexpr long WO3T   = 2572588;    // bf16 [64co pad][2048] off3 weights
constexpr long WB3T   = 2670892;    // bf16 [256co][2048] deform3 weights (16B aligned)
constexpr long OFFB   = 3221504;    // offsets layers 2/3; x4 during layer 1
constexpr long H3F    = 4458496;    // h3 bf16 channels-last, 1048576 floats
constexpr long CLBUF  = 5523456;    // channels-last bf16 skip1/skip2
constexpr long PST1   = 7620608;    // IN partial sums  [2][64][256]
constexpr long PST2   = 7653376;    // IN partial sumsq [2][64][256]
// bias sub-offsets
constexpr long OFF1B = 0,   DCN1B = 147;
constexpr long OFF2B = 211, DCN2B = 259;
constexpr long OFF3B = 387, DCN3B = 435;
constexpr long RB1B1 = 691, RB1B2 = 947;
constexpr long RB2B1 = 1203, RB2B2 = 1459;

// ---- compile-time dtype accessors (BF=1: bf16, BF=0: fp32) ----------------
template<int BF>
__device__ __forceinline__ float ldT(const void* p, long i) {
    if (BF) {
        unsigned short h = ((const unsigned short*)p)[i];
        return __uint_as_float(((unsigned int)h) << 16);
    }
    return ((const float*)p)[i];
}
template<int BF>
__device__ __forceinline__ void stT(void* p, long i, float v) {
    if (BF) ((bf16*)p)[i] = __float2bfloat16(v);
    else    ((float*)p)[i] = v;
}
__device__ __forceinline__ float bitsToF(unsigned short h) {
    return __uint_as_float(((unsigned int)h) << 16);
}
__device__ __forceinline__ unsigned short fToBits(float v) {
    bf16 h = __float2bfloat16(v);
    return *(unsigned short*)&h;
}

// ---- dtype detector (validated rounds 3-9) --------------------------------
__global__ void detect_kernel(const void* __restrict__ x, int* __restrict__ flag) {
    if (threadIdx.x == 0 && blockIdx.x == 0) {
        const unsigned short* u = (const unsigned short*)x;
        int sane = 0;
        for (int i = 0; i < 256; ++i) {
            float v = bitsToF(u[i]);
            float a = fabsf(v);
            if (a > 0.0009f && a < 1100.f) ++sane;
        }
        *flag = (sane >= 224) ? 1 : 0;
    }
}

// ===========================================================================
// Repack: biases -> packed fp32 (grid 2).
// ===========================================================================
struct PtrPack { const void* p[20]; };   // p[10..19]=biases

template<int BF>
__device__ void repack_all_body(PtrPack pp, float* __restrict__ fw)
{
    constexpr int  bcum  [11] = {0,147,211,259,387,435,691,947,1203,1459,1715};
    int j0 = blockIdx.x * 1024 + threadIdx.x * 4;
    #pragma unroll
    for (int q = 0; q < 4; ++q) {
        int j = j0 + q;
        if (j < 1715) {
            int v = 0;
            #pragma unroll
            for (int s = 1; s < 10; ++s) if (j >= bcum[s]) v = s;
            fw[BIASF + j] = ldT<BF>(pp.p[10 + v], j - bcum[v]);
        }
    }
}
__global__ __launch_bounds__(TPB) void repack_all_kernel(
    PtrPack pp, float* fw, const int* dflag) {
    if (*dflag) repack_all_body<1>(pp, fw);
    else        repack_all_body<0>(pp, fw);
}

// ---- conv weights -> bf16 [co][k*CIN+ci] (dst-contiguous writes) ----------
__global__ __launch_bounds__(TPB) void repack_dcn_kernel(
    const void* __restrict__ w2, const void* __restrict__ w3,
    const void* __restrict__ w1o, const void* __restrict__ w1d,
    const void* __restrict__ w2o, const void* __restrict__ w3o,
    float* __restrict__ fw, const int* __restrict__ dflag)
{
    int bf = *dflag;
    unsigned short* wb2 = (unsigned short*)(fw + WB2T);
    unsigned short* wb3 = (unsigned short*)(fw + WB3T);
    unsigned short* wb1o = (unsigned short*)(fw + WB1OT);
    unsigned short* wb1d = (unsigned short*)(fw + WB1DT);
    unsigned short* wb2o = (unsigned short*)(fw + WO2T);
    unsigned short* wb3o = (unsigned short*)(fw + WO3T);
    int b = blockIdx.x;
    if (b < 128) {                              // dcn2: 131072 = 128 blocks
        int e0 = b * 1024 + threadIdx.x * 4;
        #pragma unroll
        for (int j = 0; j < 4; ++j) {
            int e = e0 + j;
            int co = e >> 10, rem = e & 1023, k = rem >> 6, ci = rem & 63;
            long si = ((long)(co * 64 + ci)) * 16 + k;
            float v = bf ? ldT<1>(w2, si) : ldT<0>(w2, si);
            wb2[e] = fToBits(v);
        }
    } else if (b < 640) {                       // dcn3: 524288 = 512 blocks
        int e0 = (b - 128) * 1024 + threadIdx.x * 4;
        #pragma unroll
        for (int j = 0; j < 4; ++j) {
            int e = e0 + j;
            int co = e >> 11, rem = e & 2047, k = rem >> 7, ci = rem & 127;
            long si = ((long)(co * 128 + ci)) * 16 + k;
            float v = bf ? ldT<1>(w3, si) : ldT<0>(w3, si);
            wb3[e] = fToBits(v);
        }
    } else if (b < 665) {                       // off1: 160x160 = 25 blocks
        int e0 = (b - 640) * 1024 + threadIdx.x * 4;
        #pragma unroll
        for (int j = 0; j < 4; ++j) {
            int e = e0 + j;
            int co = e / 160, k = e - co * 160;
            float v = 0.f;
            if (co < 147 && k < 147) {
                long si = (long)co * 147 + k;
                v = bf ? ldT<1>(w1o, si) : ldT<0>(w1o, si);
            }
            wb1o[e] = fToBits(v);
        }
    } else if (b < 675) {                       // dcn1: 64x160 = 10 blocks
        int e0 = (b - 665) * 1024 + threadIdx.x * 4;
        #pragma unroll
        for (int j = 0; j < 4; ++j) {
            int e = e0 + j;
            int co = e / 160, k = e - co * 160;
            float v = 0.f;
            if (k < 147) {
                long si = (long)co * 147 + k;
                v = bf ? ldT<1>(w1d, si) : ldT<0>(w1d, si);
            }
            wb1d[e] = fToBits(v);
        }
    } else if (b < 739) {                       // off2 pad64: 65536 = 64 blocks
        int e0 = (b - 675) * 1024 + threadIdx.x * 4;
        #pragma unroll
        for (int j = 0; j < 4; ++j) {
            int e = e0 + j;
            int co = e >> 10, rem = e & 1023, k = rem >> 6, ci = rem & 63;
            float v = 0.f;
            if (co < 48) {
                long si = ((long)(co * 64 + ci)) * 16 + k;
                v = bf ? ldT<1>(w2o, si) : ldT<0>(w2o, si);
            }
            wb2o[e] = fToBits(v);
        }
    } else {                                    // off3 pad64: 131072 = 128 blocks
        int e0 = (b - 739) * 1024 + threadIdx.x * 4;
        #pragma unroll
        for (int j = 0; j < 4; ++j) {
            int e = e0 + j;
            int co = e >> 11, rem = e & 2047, k = rem >> 7, ci = rem & 127;
            float v = 0.f;
            if (co < 48) {
                long si = ((long)(co * 128 + ci)) * 16 + k;
                v = bf ? ldT<1>(w3o, si) : ldT<0>(w3o, si);
            }
            wb3o[e] = fToBits(v);
        }
    }
}

// ---- res weights: src[co][ci*9+q] (flag dtype) -> bf16 [q][co][ci] --------
struct RbPack { const void* src[4]; };
__global__ __launch_bounds__(TPB) void repack_rb_kernel(
    RbPack rp, float* fw, const int* dflag)
{
    __shared__ unsigned short lw[4 * 2304];
    int b = blockIdx.x;
    int ten = b >> 6;
    int co0 = (b & 63) * 4;
    const void* src = rp.src[ten];
    const long dstOff[4] = {RB1W1T, RB1W2T, RB2W1T, RB2W2T};
    unsigned short* dst = (unsigned short*)(fw + dstOff[ten]);
    int bf = *dflag;
    int t = threadIdx.x;
    for (int e = t; e < 4 * 2304; e += TPB) {
        int coL = e / 2304, i = e - coL * 2304;
        long si = (long)(co0 + coL) * 2304 + i;
        float v = bf ? ldT<1>(src, si) : ldT<0>(src, si);
        lw[e] = fToBits(v);
    }
    __syncthreads();
    for (int e = t; e < 9216; e += TPB) {     // 9216 = 9q * 4co * 256ci
        int ci = e & 255, coL = (e >> 8) & 3, q = e >> 10;
        dst[((long)q * 256 + co0 + coL) * 256 + ci] = lw[coL * 2304 + ci * 9 + q];
    }
}

// ===========================================================================
// x (NCHW flag dtype, 3ch) -> x4 bf16 [n][256][256][4] (ch 3 = 0 pad).
// ===========================================================================
template<int BF>
__device__ void x_to_cl4_body(const void* __restrict__ x, unsigned short* __restrict__ x4)
{
    long gid = (long)blockIdx.x * TPB + threadIdx.x;   // 0..131071
    int n = (int)(gid >> 16); int p = (int)(gid & 65535);
    long xb = (long)n * 3 * 65536 + p;
    unsigned c0 = fToBits(ldT<BF>(x, xb));
    unsigned c1 = fToBits(ldT<BF>(x, xb + 65536));
    unsigned c2 = fToBits(ldT<BF>(x, xb + 131072));
    uint2 v; v.x = c0 | (c1 << 16); v.y = c2;
    *(uint2*)&x4[gid * 4] = v;
}
__global__ __launch_bounds__(TPB) void x_to_cl4_kernel(
    const void* x, unsigned short* x4, const int* dflag)
{
    if (*dflag) x_to_cl4_body<1>(x, x4);
    else        x_to_cl4_body<0>(x, x4);
}

// ===========================================================================
// MFMA fused layer 1 v4 (validated round 8)
// ===========================================================================
template<int BF>
__device__ void layer1_mfma_body(
    const unsigned short* __restrict__ x4all, const unsigned short* __restrict__ wo,
    const unsigned short* __restrict__ wd, const float* __restrict__ bias1,
    const float* __restrict__ bias2, void* __restrict__ out, long obase,
    float* xs, unsigned short* A, float* offs)
{
    int b = blockIdx.x;
    int n = b >> 11;
    int ho = (b >> 3) & 255;
    int wo0 = (b & 7) << 5;
    const unsigned short* x4 = x4all + ((long)n << 16) * 4;
    int t = threadIdx.x;

    // ---- phase 1a: stage x patch [3ci][7ky][40 cols] from x4 (8B loads) --
    for (int e = t; e < 7 * 40; e += TPB) {
        int cc = e % 40, rr = e / 40;
        int yy = ho - 3 + rr; int xx = wo0 - 3 + cc;
        float c0 = 0.f, c1 = 0.f, c2 = 0.f;
        if (cc < 38 && yy >= 0 && yy < 256 && xx >= 0 && xx < 256) {
            uint2 v = *(const uint2*)&x4[((long)yy * 256 + xx) * 4];
            c0 = bitsToF((unsigned short)(v.x & 0xffff));
            c1 = bitsToF((unsigned short)(v.x >> 16));
            c2 = bitsToF((unsigned short)(v.y & 0xffff));
        }
        xs[(0 * 7 + rr) * 40 + cc] = c0;
        xs[(1 * 7 + rr) * 40 + cc] = c1;
        xs[(2 * 7 + rr) * 40 + cc] = c2;
    }
    __syncthreads();

    // ---- phase 1b: im2col -> A[kc][m][32] bf16, k = ci*49+ky*7+kx --------
    for (int e = t; e < 5120; e += TPB) {
        int kin = e & 31, m = (e >> 5) & 31, kc = e >> 10;
        int k = kc * 32 + kin;
        float v = 0.f;
        if (k < 147) {
            int ci = k / 49, q = k - ci * 49;
            int ky = q / 7, kx = q - ky * 7;
            v = xs[(ci * 7 + ky) * 40 + m + kx];
        }
        A[kc * 1024 + m * 32 + kin] = fToBits(v);
    }
    __syncthreads();

    int wv = t >> 6, lane = t & 63;
    int quad = lane >> 4, l16 = lane & 15;
    int mt = wv & 1, ntb = wv >> 1;

    // ---- phase 2: MFMA offset conv (N=160, 10 n-tiles over 2 wave-groups)-
    {
        f32x4 acc[5];
        #pragma unroll
        for (int j = 0; j < 5; ++j) acc[j] = (f32x4){0.f, 0.f, 0.f, 0.f};
        #pragma unroll
        for (int kc = 0; kc < 5; ++kc) {
            bf16x8 a = *(const bf16x8*)&A[(kc * 32 + mt * 16 + l16) * 32 + quad * 8];
            #pragma unroll
            for (int j = 0; j < 5; ++j) {
                int ch = (ntb + 2 * j) * 16 + l16;
                bf16x8 bw = *(const bf16x8*)&wo[ch * 160 + kc * 32 + quad * 8];
                acc[j] = __builtin_amdgcn_mfma_f32_16x16x32_bf16(a, bw, acc[j], 0, 0, 0);
            }
        }
        #pragma unroll
        for (int j = 0; j < 5; ++j) {
            int ch = (ntb + 2 * j) * 16 + l16;
            if (ch < 147) {
                float bv = bias1[ch];
                #pragma unroll
                for (int reg = 0; reg < 4; ++reg) {
                    int m = mt * 16 + quad * 4 + reg;
                    offs[ch * 33 + m] = acc[j][reg] + bv;
                }
            }
        }
    }
    __syncthreads();

    // ---- phase 3: p in lane (coalesced 8B taps); in-place sample write ----
    for (int e = t; e < 49 * 32; e += TPB) {
        int p = e & 31; int k = e >> 5;
        float oy = offs[k * 33 + p];
        float ox = offs[(49 + k) * 33 + p];
        float mr = offs[(98 + k) * 33 + p];
        float m = 1.f / (1.f + expf(-mr));
        float py = (float)(ho - 3 + k / 7) + oy;
        float px = (float)(wo0 + p - 3 + k % 7) + ox;
        float y0f = floorf(py), x0f = floorf(px);
        float wy = py - y0f, wx = px - x0f;
        int y0 = (int)y0f, x0 = (int)x0f;
        bool yv0 = (y0 >= 0) && (y0 < 256);
        bool yv1 = (y0 + 1 >= 0) && (y0 + 1 < 256);
        bool xv0 = (x0 >= 0) && (x0 < 256);
        bool xv1 = (x0 + 1 >= 0) && (x0 + 1 < 256);
        int y0c = min(max(y0, 0), 255), y1c = min(max(y0 + 1, 0), 255);
        int x0c = min(max(x0, 0), 255), x1c = min(max(x0 + 1, 0), 255);
        float w00 = (yv0 && xv0) ? (1.f - wy) * (1.f - wx) * m : 0.f;
        float w01 = (yv0 && xv1) ? (1.f - wy) * wx * m : 0.f;
        float w10 = (yv1 && xv0) ? wy * (1.f - wx) * m : 0.f;
        float w11 = (yv1 && xv1) ? wy * wx * m : 0.f;
        uint2 a00 = *(const uint2*)&x4[((long)y0c * 256 + x0c) * 4];
        uint2 a01 = *(const uint2*)&x4[((long)y0c * 256 + x1c) * 4];
        uint2 a10 = *(const uint2*)&x4[((long)y1c * 256 + x0c) * 4];
        uint2 a11 = *(const uint2*)&x4[((long)y1c * 256 + x1c) * 4];
        float s0 = w00 * bitsToF((unsigned short)(a00.x & 0xffff))
                 + w01 * bitsToF((unsigned short)(a01.x & 0xffff))
                 + w10 * bitsToF((unsigned short)(a10.x & 0xffff))
                 + w11 * bitsToF((unsigned short)(a11.x & 0xffff));
        float s1 = w00 * bitsToF((unsigned short)(a00.x >> 16))
                 + w01 * bitsToF((unsigned short)(a01.x >> 16))
                 + w10 * bitsToF((unsigned short)(a10.x >> 16))
                 + w11 * bitsToF((unsigned short)(a11.x >> 16));
        float s2 = w00 * bitsToF((unsigned short)(a00.y & 0xffff))
                 + w01 * bitsToF((unsigned short)(a01.y & 0xffff))
                 + w10 * bitsToF((unsigned short)(a10.y & 0xffff))
                 + w11 * bitsToF((unsigned short)(a11.y & 0xffff));
        offs[k * 33 + p] = s0;               // in-place, thread-local RAW
        offs[(49 + k) * 33 + p] = s1;
        offs[(98 + k) * 33 + p] = s2;
    }
    __syncthreads();

    // ---- phase 3.5: repack offs(f32) -> A(bf16 MFMA layout) --------------
    for (int e = t; e < 5120; e += TPB) {
        int kin = e & 31, m = (e >> 5) & 31, kc = e >> 10;
        int k = kc * 32 + kin;
        float v = 0.f;
        if (k < 147) v = offs[k * 33 + m];
        A[kc * 1024 + m * 32 + kin] = fToBits(v);
    }
    __syncthreads();

    // ---- phase 4: MFMA deform conv (N=64, 4 n-tiles) ---------------------
    f32x4 acc2[2];
    acc2[0] = (f32x4){0.f, 0.f, 0.f, 0.f};
    acc2[1] = (f32x4){0.f, 0.f, 0.f, 0.f};
    #pragma unroll
    for (int kc = 0; kc < 5; ++kc) {
        bf16x8 a = *(const bf16x8*)&A[(kc * 32 + mt * 16 + l16) * 32 + quad * 8];
        #pragma unroll
        for (int j = 0; j < 2; ++j) {
            int co = (ntb + 2 * j) * 16 + l16;
            bf16x8 bw = *(const bf16x8*)&wd[co * 160 + kc * 32 + quad * 8];
            acc2[j] = __builtin_amdgcn_mfma_f32_16x16x32_bf16(a, bw, acc2[j], 0, 0, 0);
        }
    }
    #pragma unroll
    for (int j = 0; j < 2; ++j) {
        int co = (ntb + 2 * j) * 16 + l16;
        float bv = bias2[co];
        #pragma unroll
        for (int reg = 0; reg < 4; ++reg) {
            int wox = wo0 + mt * 16 + quad * 4 + reg;
            long oi = obase + ((long)(n * 64 + co) * 256 + ho) * 256 + wox;
            stT<BF>(out, oi, acc2[j][reg] + bv);
        }
    }
}

__global__ __launch_bounds__(TPB) void layer1_mfma_kernel(
    const unsigned short* x4, const unsigned short* wo, const unsigned short* wd,
    const float* bias1, const float* bias2, void* out, long obase, const int* dflag)
{
    __shared__ __align__(16) float xs[3 * 7 * 40];
    __shared__ __align__(16) unsigned short A[5120];
    __shared__ __align__(16) float offs[147 * 33];
    if (*dflag) layer1_mfma_body<1>(x4, wo, wd, bias1, bias2, out, obase, xs, A, offs);
    else        layer1_mfma_body<0>(x4, wo, wd, bias1, bias2, out, obase, xs, A, offs);
}

// ===========================================================================
// MFMA offset conv (layers 2/3) v2: staging vectorized to 8B uint2
// (4 channels per load; was scalar 2B — 4x fewer memory instructions).
// ===========================================================================
template<int CIN, int HH, int WW, int HO, int WO>
__global__ __launch_bounds__(TPB) void offconv_mfma_kernel(
    const unsigned short* __restrict__ xcl, const unsigned short* __restrict__ wb,
    const float* __restrict__ bias_f, float* __restrict__ out)
{
    constexpr int S   = 16 * CIN;
    constexpr int KL  = 512 / CIN;       // taps per 512-i chunk
    constexpr int NCH = 16 / KL;
    constexpr int CH4 = CIN / 4;         // 8B units per (pair, tap)
    constexpr int UN  = (KL * 16 * CH4) / TPB;   // 8B units per thread/chunk
    constexpr int TILES = (HO * WO) / 16;

    __shared__ int tp[256];
    __shared__ __align__(16) unsigned short smp[16 * 512];

    int tile = blockIdx.x % TILES;
    int n    = blockIdx.x / TILES;
    int lp0  = tile * 16;

    // ---- fixed-tap address table: one (k,p) per thread ----
    {
        int pr = threadIdx.x;
        int k = pr >> 4, p = pr & 15;
        int lp = lp0 + p;
        int ho = lp / WO, wo = lp - ho * WO;
        int yy = ho * 2 - 1 + (k >> 2);
        int xx = wo * 2 - 1 + (k & 3);
        bool valid = (yy >= 0) && (yy < HH) && (xx >= 0) && (xx < WW);
        tp[pr] = valid ? (yy * WW + xx) * CIN : -1;
    }

    int wv = threadIdx.x >> 6, lane = threadIdx.x & 63;
    int quad = lane >> 4, l16 = lane & 15;
    const unsigned short* xn = xcl + (long)n * HH * WW * CIN;

    f32x4 acc = (f32x4){0.f, 0.f, 0.f, 0.f};

    for (int ch = 0; ch < NCH; ++ch) {
        __syncthreads();
        #pragma unroll
        for (int u = 0; u < UN; ++u) {
            int e   = u * TPB + threadIdx.x;
            int prl = e / CH4;
            int ci  = (e - prl * CH4) * 4;
            int pi  = ch * (KL * 16) + prl;
            int kl = prl >> 4, p = prl & 15;
            int t0 = tp[pi];
            uint2 v = (t0 >= 0) ? *(const uint2*)(xn + t0 + ci) : (uint2){0u, 0u};
            int il = kl * CIN + ci;
            *(uint2*)&smp[((il >> 5) * 16 + p) * 32 + (il & 31)] = v;
        }
        __syncthreads();
        #pragma unroll 4
        for (int kk = 0; kk < 16; ++kk) {
            bf16x8 a = *(const bf16x8*)&smp[(kk * 16 + l16) * 32 + quad * 8];
            int co = wv * 16 + l16;
            bf16x8 b = *(const bf16x8*)&wb[(long)co * S + ch * 512 + kk * 32 + quad * 8];
            acc = __builtin_amdgcn_mfma_f32_16x16x32_bf16(a, b, acc, 0, 0, 0);
        }
    }

    int co = wv * 16 + l16;
    if (co < 48) {
        float bv = bias_f[co];
        #pragma unroll
        for (int reg = 0; reg < 4; ++reg) {
            int lp = lp0 + quad * 4 + reg;
            int ho = lp / WO, wo = lp - ho * WO;
            out[((long)(n * 48 + co) * HO + ho) * WO + wo] = acc[reg] + bv;
        }
    }
}

// ===========================================================================
// NCHW (flag dtype) -> channels-last bf16 transpose. 64 pixels x C per block.
// ===========================================================================
template<int C>
__global__ __launch_bounds__(TPB) void nchw_to_cl_kernel(
    const void* __restrict__ in, long ibase, unsigned short* __restrict__ out,
    int HW, const int* __restrict__ dflag)
{
    __shared__ unsigned short tile[C * 65];
    int bf = *dflag;
    int n   = (blockIdx.x * 64) / HW;
    int px0 = (blockIdx.x * 64) % HW;
    for (int e = threadIdx.x; e < C * 64; e += TPB) {
        int c = e >> 6, p = e & 63;
        long si = ibase + (long)(n * C + c) * HW + px0 + p;
        float v = bf ? ldT<1>(in, si) : ldT<0>(in, si);
        tile[c * 65 + p] = fToBits(v);
    }
    __syncthreads();
    for (int e = threadIdx.x; e < C * 64; e += TPB) {
        int p = e / C, c = e - p * C;
        out[((long)n * HW + px0 + p) * C + c] = tile[c * 65 + p];
    }
}

// ===========================================================================
// MFMA deformable conv v3 (layers 2/3): gather vectorized to 8B uint2
// (4 channels per tap load; ITER halved vs v2). Tap base multiple of CIN
// (>=64) and ci multiple of 4 keep all loads 8B-aligned.
// ===========================================================================
template<int MODE, int CIN, int COUT, int NWAVES, int HH, int WW, int HO, int WO>
__global__ __launch_bounds__(NWAVES * 64) void deform_mfma_kernel(
    const unsigned short* __restrict__ xcl, const float* __restrict__ off,
    const unsigned short* __restrict__ wb, const float* __restrict__ bias_f,
    void* __restrict__ outp, long obase, const int* __restrict__ dflag)
{
    constexpr int TPBk = NWAVES * 64;
    constexpr int S    = 16 * CIN;       // reduction length
    constexpr int KL   = 512 / CIN;      // kernel-points per 512-i chunk
    constexpr int NCH  = 16 / KL;        // chunks
    constexpr int CH4  = CIN / 4;        // 8B units per (pair, tap)
    constexpr int ITER = (KL * 16 * CH4) / TPBk;   // 8B units per thread/chunk
    constexpr int TILES = (HO * WO) / 16;

    __shared__ __align__(16) int tpw[256][8];      // [pair]{tp0..3, w0..3bits}
    __shared__ __align__(16) unsigned short smp[16 * 512];

    int tile = blockIdx.x % TILES;
    int n    = blockIdx.x / TILES;
    int lp0  = tile * 16;
    int tid  = threadIdx.x;

    // ---- phase A: per-(k,p) offset decode, one pair per thread (first 256)-
    if (tid < 256) {
        int pr = tid;
        int k = pr >> 4, p = pr & 15;
        int lp = lp0 + p;
        int ho = lp / WO, wo = lp - ho * WO;
        long plane = (long)HO * WO;
        const float* offn = off + (long)n * 48 * plane;
        float oy = offn[(long)k * plane + lp];
        float ox = offn[(long)(16 + k) * plane + lp];
        float mr = offn[(long)(32 + k) * plane + lp];
        float m = 1.f / (1.f + expf(-mr));
        float py = (float)(ho * 2 - 1 + (k >> 2)) + oy;
        float px = (float)(wo * 2 - 1 + (k & 3)) + ox;
        float y0f = floorf(py), x0f = floorf(px);
        float wy = py - y0f, wx = px - x0f;
        int y0 = (int)y0f, x0 = (int)x0f;
        bool yv0 = (y0 >= 0) && (y0 < HH);
        bool yv1 = (y0 + 1 >= 0) && (y0 + 1 < HH);
        bool xv0 = (x0 >= 0) && (x0 < WW);
        bool xv1 = (x0 + 1 >= 0) && (x0 + 1 < WW);
        int y0c = min(max(y0, 0), HH - 1), y1c = min(max(y0 + 1, 0), HH - 1);
        int x0c = min(max(x0, 0), WW - 1), x1c = min(max(x0 + 1, 0), WW - 1);
        tpw[pr][0] = (y0c * WW + x0c) * CIN;
        tpw[pr][1] = (y0c * WW + x1c) * CIN;
        tpw[pr][2] = (y1c * WW + x0c) * CIN;
        tpw[pr][3] = (y1c * WW + x1c) * CIN;
        tpw[pr][4] = __float_as_int((yv0 && xv0) ? (1.f - wy) * (1.f - wx) * m : 0.f);
        tpw[pr][5] = __float_as_int((yv0 && xv1) ? (1.f - wy) * wx * m : 0.f);
        tpw[pr][6] = __float_as_int((yv1 && xv0) ? wy * (1.f - wx) * m : 0.f);
        tpw[pr][7] = __float_as_int((yv1 && xv1) ? wy * wx * m : 0.f);
    }

    int wv = tid >> 6, lane = tid & 63;
    int quad = lane >> 4, l16 = lane & 15;
    int cb = (wv & 3) * 32 + (wv >> 2) * (COUT / 2);
    const unsigned short* xn = xcl + (long)n * HH * WW * CIN;

    f32x4 acc[2];
    acc[0] = (f32x4){0.f, 0.f, 0.f, 0.f};
    acc[1] = (f32x4){0.f, 0.f, 0.f, 0.f};

    for (int ch = 0; ch < NCH; ++ch) {
        __syncthreads();   // covers phase A (ch=0) and prev MFMA reads
        #pragma unroll
        for (int it = 0; it < ITER; ++it) {
            int e   = it * TPBk + tid;
            int prl = e / CH4;                  // pair within chunk
            int ci  = (e - prl * CH4) * 4;      // ci multiple of 4
            int pi  = ch * (KL * 16) + prl;
            const int4   tp4 = *(const int4*)&tpw[pi][0];
            const float4 tw4 = *(const float4*)&tpw[pi][4];
            uint2 u0 = *(const uint2*)(xn + tp4.x + ci);
            uint2 u1 = *(const uint2*)(xn + tp4.y + ci);
            uint2 u2 = *(const uint2*)(xn + tp4.z + ci);
            uint2 u3 = *(const uint2*)(xn + tp4.w + ci);
            float r0 = tw4.x * bitsToF((unsigned short)(u0.x & 0xffff))
                     + tw4.y * bitsToF((unsigned short)(u1.x & 0xffff))
                     + tw4.z * bitsToF((unsigned short)(u2.x & 0xffff))
                     + tw4.w * bitsToF((unsigned short)(u3.x & 0xffff));
            float r1 = tw4.x * bitsToF((unsigned short)(u0.x >> 16))
                     + tw4.y * bitsToF((unsigned short)(u1.x >> 16))
                     + tw4.z * bitsToF((unsigned short)(u2.x >> 16))
                     + tw4.w * bitsToF((unsigned short)(u3.x >> 16));
            float r2 = tw4.x * bitsToF((unsigned short)(u0.y & 0xffff))
                     + tw4.y * bitsToF((unsigned short)(u1.y & 0xffff))
                     + tw4.z * bitsToF((unsigned short)(u2.y & 0xffff))
                     + tw4.w * bitsToF((unsigned short)(u3.y & 0xffff));
            float r3 = tw4.x * bitsToF((unsigned short)(u0.y >> 16))
                     + tw4.y * bitsToF((unsigned short)(u1.y >> 16))
                     + tw4.z * bitsToF((unsigned short)(u2.y >> 16))
                     + tw4.w * bitsToF((unsigned short)(u3.y >> 16));
            uint2 ov;
            ov.x = (unsigned)fToBits(r0) | ((unsigned)fToBits(r1) << 16);
            ov.y = (unsigned)fToBits(r2) | ((unsigned)fToBits(r3) << 16);
            int il = (prl >> 4) * CIN + ci;     // i within chunk [0,512)
            int p  = prl & 15;
            *(uint2*)&smp[((il >> 5) * 16 + p) * 32 + (il & 31)] = ov;
        }
        __syncthreads();
        #pragma unroll 4
        for (int kk = 0; kk < 16; ++kk) {
            bf16x8 a = *(const bf16x8*)&smp[(kk * 16 + l16) * 32 + quad * 8];
            #pragma unroll
            for (int f = 0; f < 2; ++f) {
                int co = cb + f * 16 + l16;
                bf16x8 b = *(const bf16x8*)&wb[(long)co * S + ch * 512 + kk * 32 + quad * 8];
                acc[f] = __builtin_amdgcn_mfma_f32_16x16x32_bf16(a, b, acc[f], 0, 0, 0);
            }
        }
    }

    // ---- epilogue: pixel = quad*4+reg, co = cb + f*16 + l16 ----
    if (MODE == 1) {
        unsigned short* oCL = (unsigned short*)outp;
        #pragma unroll
        for (int f = 0; f < 2; ++f) {
            int co = cb + f * 16 + l16;
            float bv = bias_f[co];
            #pragma unroll
            for (int reg = 0; reg < 4; ++reg) {
                int lp = lp0 + quad * 4 + reg;
                oCL[((long)n * HO * WO + lp) * COUT + co] = fToBits(acc[f][reg] + bv);
            }
        }
    } else {
        int bf = *dflag;
        #pragma unroll
        for (int f = 0; f < 2; ++f) {
            int co = cb + f * 16 + l16;
            float bv = bias_f[co];
            #pragma unroll
            for (int reg = 0; reg < 4; ++reg) {
                int lp = lp0 + quad * 4 + reg;
                int ho = lp / WO, wo = lp - ho * WO;
                long oi = obase + ((long)(n * COUT + co) * HO + ho) * WO + wo;
                if (bf) stT<1>(outp, oi, acc[f][reg] + bv);
                else    stT<0>(outp, oi, acc[f][reg] + bv);
            }
        }
    }
}

// ===========================================================================
// MFMA res-block 3x3 reflect conv v2 (validated round 4/8)
// ===========================================================================
__global__ __launch_bounds__(TPB) void resconv_mfma_kernel(
    const unsigned short* __restrict__ X, const unsigned short* __restrict__ W,
    const float* __restrict__ bias_f, bf16* __restrict__ Y)
{
    __shared__ __align__(16) unsigned short xs[3 * 66 * 64];   // 25344 B, swizzled
    int b = blockIdx.x;
    int coO = b & 7, r = (b >> 3) & 63, n = b >> 9;
    int t = threadIdx.x;
    int wv = t >> 6;
    int lane = t & 63;
    int quad = lane >> 4, l16 = lane & 15;
    int rows[3];
    rows[0] = (r == 0) ? 1 : r - 1;
    rows[1] = r;
    rows[2] = (r == 63) ? 62 : r + 1;

    f32x4 acc[2];
    acc[0] = (f32x4){0.f, 0.f, 0.f, 0.f};
    acc[1] = (f32x4){0.f, 0.f, 0.f, 0.f};

    long xbase = (long)n * 4096 * 256;

    for (int ci0 = 0; ci0 < 256; ci0 += 64) {
        __syncthreads();
        // stage [3ky][66col][64ci] via 16B loads; swizzled 16B slot per col
        for (int e = t; e < 3 * 66 * 8; e += TPB) {
            int oct = e & 7;
            int col = (e >> 3) % 66;
            int ky  = e / (66 * 8);
            int gx = col - 1;
            gx = (gx < 0) ? 1 : ((gx > 63) ? 62 : gx);
            bf16x8 v = *(const bf16x8*)&X[xbase + ((long)rows[ky] * 64 + gx) * 256 + ci0 + oct * 8];
            int slot = oct ^ (col & 7);
            *(bf16x8*)&xs[((ky * 66 + col) << 6) + slot * 8] = v;
        }
        __syncthreads();
        #pragma unroll
        for (int q = 0; q < 9; ++q) {
            int ky = q / 3, kx = q % 3;
            int col = wv * 16 + l16 + kx;        // lds col = global col +1
            int base = (ky * 66 + col) << 6;
            #pragma unroll
            for (int kh = 0; kh < 2; ++kh) {
                int slot = (kh * 4 + quad) ^ (col & 7);
                bf16x8 a = *(const bf16x8*)&xs[base + slot * 8];
                #pragma unroll
                for (int ct = 0; ct < 2; ++ct) {
                    int co = coO * 32 + ct * 16 + l16;
                    bf16x8 bw = *(const bf16x8*)&W[((long)q * 256 + co) * 256 + ci0 + kh * 32 + quad * 8];
                    acc[ct] = __builtin_amdgcn_mfma_f32_16x16x32_bf16(a, bw, acc[ct], 0, 0, 0);
                }
            }
        }
    }

    long ybase = ((long)n * 4096 + (long)r * 64) * 256;
    #pragma unroll
    for (int ct = 0; ct < 2; ++ct) {
        int co = coO * 32 + ct * 16 + l16;
        float bv = bias_f[co];
        #pragma unroll
        for (int reg = 0; reg < 4; ++reg) {
            int px = wv * 16 + quad * 4 + reg;
            Y[ybase + (long)px * 256 + co] = __float2bfloat16(acc[ct][reg] + bv);
        }
    }
}

// ===========================================================================
// Channels-last instance-norm: WIDE partial stats (validated round 10)
// ===========================================================================
__global__ __launch_bounds__(TPB) void cl_stats_kernel(
    const unsigned short* __restrict__ X, float* __restrict__ psum, float* __restrict__ psq)
{
    int blk = blockIdx.x;
    int chunk = blk & 63, n = blk >> 6;
    int co = threadIdx.x;
    float s = 0.f, sq = 0.f;
    const unsigned short* p = X + ((long)n * 4096 + chunk * 64) * 256 + co;
    #pragma unroll 8
    for (int i = 0; i < 64; ++i) {
        float v = bitsToF(p[(long)i * 256]);
        s += v; sq += v * v;
    }
    psum[(n * 64 + chunk) * 256 + co] = s;
    psq [(n * 64 + chunk) * 256 + co] = sq;
}

__device__ __forceinline__ void cl_load_stats(
    const float* psum, const float* psq, int n, float* mv, float* iv)
{
    int t = threadIdx.x;   // t = channel
    float s = 0.f, sq = 0.f;
    #pragma unroll 8
    for (int c = 0; c < 64; ++c) {
        s  += psum[(n * 64 + c) * 256 + t];
        sq += psq [(n * 64 + c) * 256 + t];
    }
    float mean = s / 4096.f;
    mv[t] = mean;
    iv[t] = rsqrtf(sq / 4096.f - mean * mean + 1e-5f);
    __syncthreads();
}

// grid 128 = n*64 + y; in-place X = relu?((X-m)*inv), uint-vectorized
__global__ __launch_bounds__(TPB) void cl_apply_kernel(
    unsigned short* __restrict__ X, const float* __restrict__ psum,
    const float* __restrict__ psq, int relu)
{
    __shared__ float mv[256], iv[256];
    int y = blockIdx.x & 63, n = blockIdx.x >> 6;
    cl_load_stats(psum, psq, n, mv, iv);
    unsigned* row = (unsigned*)(X + ((long)n * 4096 + y * 64) * 256);
    for (int e = threadIdx.x; e < 8192; e += TPB) {
        int co = (e * 2) & 255;
        unsigned u = row[e];
        float v0 = (bitsToF((unsigned short)(u & 0xffff)) - mv[co]) * iv[co];
        float v1 = (bitsToF((unsigned short)(u >> 16)) - mv[co + 1]) * iv[co + 1];
        if (relu) { v0 = fmaxf(v0, 0.f); v1 = fmaxf(v1, 0.f); }
        row[e] = (unsigned)fToBits(v0) | ((unsigned)fToBits(v1) << 16);
    }
}

// grid 128; H += IN(T), uint-vectorized
__global__ __launch_bounds__(TPB) void cl_apply_add_kernel(
    const unsigned short* __restrict__ T, unsigned short* __restrict__ H,
    const float* __restrict__ psum, const float* __restrict__ psq)
{
    __shared__ float mv[256], iv[256];
    int y = blockIdx.x & 63, n = blockIdx.x >> 6;
    cl_load_stats(psum, psq, n, mv, iv);
    long base = ((long)n * 4096 + y * 64) * 256;
    const unsigned* tr = (const unsigned*)(T + base);
    unsigned* hr = (unsigned*)(H + base);
    for (int e = threadIdx.x; e < 8192; e += TPB) {
        int co = (e * 2) & 255;
        unsigned ut = tr[e], uh = hr[e];
        float v0 = bitsToF((unsigned short)(uh & 0xffff))
                 + (bitsToF((unsigned short)(ut & 0xffff)) - mv[co]) * iv[co];
        float v1 = bitsToF((unsigned short)(uh >> 16))
                 + (bitsToF((unsigned short)(ut >> 16)) - mv[co + 1]) * iv[co + 1];
        hr[e] = (unsigned)fToBits(v0) | ((unsigned)fToBits(v1) << 16);
    }
}

// grid 128; out(NCHW, flag dtype) = H + IN(T)   (transposes channels-last)
__global__ __launch_bounds__(TPB) void cl_apply_final_kernel(
    const unsigned short* __restrict__ T, const unsigned short* __restrict__ H,
    void* __restrict__ outp, const float* __restrict__ psum,
    const float* __restrict__ psq, const int* __restrict__ dflag)
{
    __shared__ float mv[256], iv[256];
    int y = blockIdx.x & 63, n = blockIdx.x >> 6;
    cl_load_stats(psum, psq, n, mv, iv);
    int bf = *dflag;
    int x = threadIdx.x & 63, cg = threadIdx.x >> 6;
    for (int co = cg; co < 256; co += 4) {
        long cli = ((long)(n * 64 + y) * 64 + x) * 256 + co;
        float v = bitsToF(H[cli]) + (bitsToF(T[cli]) - mv[co]) * iv[co];
        long oi = (((long)(n * 256 + co)) * 64 + y) * 64 + x;
        if (bf) ((bf16*)outp)[oi] = __float2bfloat16(v);
        else    ((float*)outp)[oi] = v;
    }
}

// ---------------- block reduction (up to 16 waves) -------------------------
__device__ __forceinline__ void reduce2(float& sum, float& sq, float* s1, float* s2)
{
    for (int off = 32; off; off >>= 1) {
        sum += __shfl_down(sum, off, 64);
        sq  += __shfl_down(sq,  off, 64);
    }
    int nw = blockDim.x >> 6;
    int wid = threadIdx.x >> 6;
    if ((threadIdx.x & 63) == 0) { s1[wid] = sum; s2[wid] = sq; }
    __syncthreads();
    sum = 0.f; sq = 0.f;
    for (int w = 0; w < nw; ++w) { sum += s1[w]; sq += s2[w]; }
}

// ---------------- instance norm for skip1/skip2 (d_out, flag dtype) --------
__global__ void instnorm_kernel(
    void* __restrict__ buf, long base0, const int* __restrict__ dflag,
    int HW, int relu)
{
    __shared__ float s1[16], s2[16];
    int bf = *dflag;
    long base = base0 + (long)blockIdx.x * HW;
    float sum = 0.f, sq = 0.f;
    for (int i = threadIdx.x; i < HW; i += blockDim.x) {
        float v = bf ? bitsToF(((const unsigned short*)buf)[base + i])
                     : ((const float*)buf)[base + i];
        sum += v; sq += v * v;
    }
    reduce2(sum, sq, s1, s2);
    float mean = sum / HW;
    float inv = rsqrtf(sq / HW - mean * mean + 1e-5f);
    for (int i = threadIdx.x; i < HW; i += blockDim.x) {
        float v = bf ? bitsToF(((const unsigned short*)buf)[base + i])
                     : ((const float*)buf)[base + i];
        v = (v - mean) * inv;
        if (relu) v = fmaxf(v, 0.f);
        if (bf) ((bf16*)buf)[base + i] = __float2bfloat16(v);
        else    ((float*)buf)[base + i] = v;
    }
}

// ---------------------------------------------------------------------------
extern "C" void kernel_launch(void* const* d_in, const int* in_sizes, int n_in,
                              void* d_out, int out_size, void* d_ws, size_t ws_size,
                              hipStream_t stream) {
    const void* x = d_in[0];

    const long SKIP1 = 2097152;
    const long SKIP2 = 10485760;

    int* dflag = (int*)d_ws;
    float* fw = (float*)((char*)d_ws + 64);

    unsigned short* t1 = (unsigned short*)(fw + FB);
    unsigned short* t2 = (unsigned short*)(fw + FB + 1048576);
    unsigned short* h3 = (unsigned short*)(fw + H3F);
    float* offb = fw + OFFB;
    unsigned short* x4 = (unsigned short*)(fw + OFFB);   // layer-1 only; dead after
    float* psum = fw + PST1;
    float* psq  = fw + PST2;
    unsigned short* clbuf = (unsigned short*)(fw + CLBUF);    // skip1_cl then skip2_cl
    const unsigned short* wb1o = (const unsigned short*)(fw + WB1OT);
    const unsigned short* wb1d = (const unsigned short*)(fw + WB1DT);
    const unsigned short* wb2o = (const unsigned short*)(fw + WO2T);
    const unsigned short* wb3o = (const unsigned short*)(fw + WO3T);
    const unsigned short* wb2 = (const unsigned short*)(fw + WB2T);
    const unsigned short* wb3 = (const unsigned short*)(fw + WB3T);
    const unsigned short* rbw1 = (const unsigned short*)(fw + RB1W1T);
    const unsigned short* rbw2 = (const unsigned short*)(fw + RB1W2T);
    const unsigned short* rbw3 = (const unsigned short*)(fw + RB2W1T);
    const unsigned short* rbw4 = (const unsigned short*)(fw + RB2W2T);

    detect_kernel<<<1, 64, 0, stream>>>(x, dflag);

    // ---- weight/bias repack ----
    PtrPack pp;
    for (int i = 0; i < 10; ++i) pp.p[i] = nullptr;
    pp.p[10] = d_in[2];  pp.p[11] = d_in[4];  pp.p[12] = d_in[6];  pp.p[13] = d_in[8];
    pp.p[14] = d_in[10]; pp.p[15] = d_in[12]; pp.p[16] = d_in[14]; pp.p[17] = d_in[16];
    pp.p[18] = d_in[18]; pp.p[19] = d_in[20];
    repack_all_kernel<<<2, TPB, 0, stream>>>(pp, fw, dflag);
    repack_dcn_kernel<<<867, TPB, 0, stream>>>(
        d_in[7], d_in[11], d_in[1], d_in[3], d_in[5], d_in[9], fw, dflag);
    RbPack rp;
    rp.src[0] = d_in[13]; rp.src[1] = d_in[15]; rp.src[2] = d_in[17]; rp.src[3] = d_in[19];
    repack_rb_kernel<<<256, TPB, 0, stream>>>(rp, fw, dflag);

    // ---- Layer 1 fused MFMA: offsets + deform, 7x7 s1 p3 ----
    x_to_cl4_kernel<<<512, TPB, 0, stream>>>(x, x4, dflag);
    layer1_mfma_kernel<<<4096, TPB, 0, stream>>>(
        x4, wb1o, wb1d, fw + OFF1B, fw + DCN1B, d_out, SKIP1, dflag);
    instnorm_kernel<<<128, 1024, 0, stream>>>(d_out, SKIP1, dflag, 65536, 1);
    // skip1 -> channels-last bf16 for the MFMA conv gathers
    nchw_to_cl_kernel<64><<<2048, TPB, 0, stream>>>(d_out, SKIP1, clbuf, 65536, dflag);

    // ---- Layer 2: 4x4 s2 p1, Cin=64 ----
    offconv_mfma_kernel<64, 256, 256, 128, 128><<<2048, TPB, 0, stream>>>(
        clbuf, wb2o, fw + OFF2B, offb);
    deform_mfma_kernel<0, 64, 128, 4, 256, 256, 128, 128><<<2048, TPB, 0, stream>>>(
        clbuf, offb, wb2, fw + DCN2B, d_out, SKIP2, dflag);
    instnorm_kernel<<<256, 512, 0, stream>>>(d_out, SKIP2, dflag, 16384, 1);
    // skip2 -> channels-last bf16 (reuses clbuf; skip1_cl is dead now)
    nchw_to_cl_kernel<128><<<512, TPB, 0, stream>>>(d_out, SKIP2, clbuf, 16384, dflag);

    // ---- Layer 3: 4x4 s2 p1, Cin=128; output bf16 channels-last h3 ----
    offconv_mfma_kernel<128, 128, 128, 64, 64><<<512, TPB, 0, stream>>>(
        clbuf, wb3o, fw + OFF3B, offb);
    deform_mfma_kernel<1, 128, 256, 8, 128, 128, 64, 64><<<512, 512, 0, stream>>>(
        clbuf, offb, wb3, fw + DCN3B, h3, 0, dflag);
    cl_stats_kernel<<<128, TPB, 0, stream>>>(h3, psum, psq);
    cl_apply_kernel<<<128, TPB, 0, stream>>>(h3, psum, psq, 1);

    // ---- Res block 1 (MFMA) ----
    resconv_mfma_kernel<<<1024, TPB, 0, stream>>>(h3, rbw1, fw + RB1B1, (bf16*)t1);
    cl_stats_kernel<<<128, TPB, 0, stream>>>(t1, psum, psq);
    cl_apply_kernel<<<128, TPB, 0, stream>>>(t1, psum, psq, 1);
    resconv_mfma_kernel<<<1024, TPB, 0, stream>>>(t1, rbw2, fw + RB1B2, (bf16*)t2);
    cl_stats_kernel<<<128, TPB, 0, stream>>>(t2, psum, psq);
    cl_apply_add_kernel<<<128, TPB, 0, stream>>>(t2, h3, psum, psq);

    // ---- Res block 2 (MFMA; final writes NCHW d_out per flag) ----
    resconv_mfma_kernel<<<1024, TPB, 0, stream>>>(h3, rbw3, fw + RB2B1, (bf16*)t1);
    cl_stats_kernel<<<128, TPB, 0, stream>>>(t1, psum, psq);
    cl_apply_kernel<<<128, TPB, 0, stream>>>(t1, psum, psq, 1);
    resconv_mfma_kernel<<<1024, TPB, 0, stream>>>(t1, rbw4, fw + RB2B2, (bf16*)t2);
    cl_stats_kernel<<<128, TPB, 0, stream>>>(t2, psum, psq);
    cl_apply_final_kernel<<<128, TPB, 0, stream>>>(t2, h3, d_out, psum, psq, dflag);
}

// Round 15
// 843.209 us; speedup vs baseline: 1.1049x; 1.0295x over previous
//
#include <hip/hip_runtime.h>
#include <hip/hip_bf16.h>
#include <math.h>

#define TPB 256
typedef __hip_bfloat16 bf16;
typedef short bf16x8 __attribute__((ext_vector_type(8)));   // 8 bf16 (4 VGPRs)
typedef float f32x4 __attribute__((ext_vector_type(4)));

// ---------------- ws layout constants (fp32-element offsets from fw) -------
constexpr long BIASF  = 0;          // 1715 packed fp32 biases (pad to 2048)
constexpr long RB1W1T = 2048;       // res weights bf16 [9][256co][256ci]
constexpr long RB1W2T = 591872;
constexpr long RB2W1T = 1181696;
constexpr long RB2W2T = 1771520;
constexpr long FB     = 2361344;    // multi-use region
constexpr long WB1OT  = 2361344;    // bf16 [160][160] off1 weights (16B aligned)
constexpr long WB1DT  = 2382956;    // bf16 [64][160] dcn1 weights (16B aligned)
constexpr long WO2T   = 2392364;    // bf16 [64co pad][1024] off2 weights
constexpr long WB2T   = 2441516;    // bf16 [128co][1024] deform2 weights (16B aligned)
constexpr long WO3T   = 2572588;    // bf16 [64co pad][2048] off3 weights
constexpr long WB3T   = 2670892;    // bf16 [256co][2048] deform3 weights (16B aligned)
constexpr long OFFB   = 3221504;    // offsets layers 2/3; x4 during layer 1
constexpr long H3F    = 4458496;    // h3 bf16 channels-last, 1048576 floats
constexpr long CLBUF  = 5523456;    // channels-last bf16 skip1/skip2
constexpr long PST1   = 7620608;    // IN partial sums  [2][64][256]
constexpr long PST2   = 7653376;    // IN partial sumsq [2][64][256]
// bias sub-offsets
constexpr long OFF1B = 0,   DCN1B = 147;
constexpr long OFF2B = 211, DCN2B = 259;
constexpr long OFF3B = 387, DCN3B = 435;
constexpr long RB1B1 = 691, RB1B2 = 947;
constexpr long RB2B1 = 1203, RB2B2 = 1459;

// ---- compile-time dtype accessors (BF=1: bf16, BF=0: fp32) ----------------
template<int BF>
__device__ __forceinline__ float ldT(const void* p, long i) {
    if (BF) {
        unsigned short h = ((const unsigned short*)p)[i];
        return __uint_as_float(((unsigned int)h) << 16);
    }
    return ((const float*)p)[i];
}
template<int BF>
__device__ __forceinline__ void stT(void* p, long i, float v) {
    if (BF) ((bf16*)p)[i] = __float2bfloat16(v);
    else    ((float*)p)[i] = v;
}
__device__ __forceinline__ float bitsToF(unsigned short h) {
    return __uint_as_float(((unsigned int)h) << 16);
}
__device__ __forceinline__ unsigned short fToBits(float v) {
    bf16 h = __float2bfloat16(v);
    return *(unsigned short*)&h;
}

// ---- dtype detector (validated rounds 3-9) --------------------------------
__global__ void detect_kernel(const void* __restrict__ x, int* __restrict__ flag) {
    if (threadIdx.x == 0 && blockIdx.x == 0) {
        const unsigned short* u = (const unsigned short*)x;
        int sane = 0;
        for (int i = 0; i < 256; ++i) {
            float v = bitsToF(u[i]);
            float a = fabsf(v);
            if (a > 0.0009f && a < 1100.f) ++sane;
        }
        *flag = (sane >= 224) ? 1 : 0;
    }
}

// ===========================================================================
// Repack: biases -> packed fp32 (grid 2).
// ===========================================================================
struct PtrPack { const void* p[20]; };   // p[10..19]=biases

template<int BF>
__device__ void repack_all_body(PtrPack pp, float* __restrict__ fw)
{
    constexpr int  bcum  [11] = {0,147,211,259,387,435,691,947,1203,1459,1715};
    int j0 = blockIdx.x * 1024 + threadIdx.x * 4;
    #pragma unroll
    for (int q = 0; q < 4; ++q) {
        int j = j0 + q;
        if (j < 1715) {
            int v = 0;
            #pragma unroll
            for (int s = 1; s < 10; ++s) if (j >= bcum[s]) v = s;
            fw[BIASF + j] = ldT<BF>(pp.p[10 + v], j - bcum[v]);
        }
    }
}
__global__ __launch_bounds__(TPB) void repack_all_kernel(
    PtrPack pp, float* fw, const int* dflag) {
    if (*dflag) repack_all_body<1>(pp, fw);
    else        repack_all_body<0>(pp, fw);
}

// ---- conv weights -> bf16 [co][k*CIN+ci] (dst-contiguous writes) ----------
__global__ __launch_bounds__(TPB) void repack_dcn_kernel(
    const void* __restrict__ w2, const void* __restrict__ w3,
    const void* __restrict__ w1o, const void* __restrict__ w1d,
    const void* __restrict__ w2o, const void* __restrict__ w3o,
    float* __restrict__ fw, const int* __restrict__ dflag)
{
    int bf = *dflag;
    unsigned short* wb2 = (unsigned short*)(fw + WB2T);
    unsigned short* wb3 = (unsigned short*)(fw + WB3T);
    unsigned short* wb1o = (unsigned short*)(fw + WB1OT);
    unsigned short* wb1d = (unsigned short*)(fw + WB1DT);
    unsigned short* wb2o = (unsigned short*)(fw + WO2T);
    unsigned short* wb3o = (unsigned short*)(fw + WO3T);
    int b = blockIdx.x;
    if (b < 128) {                              // dcn2: 131072 = 128 blocks
        int e0 = b * 1024 + threadIdx.x * 4;
        #pragma unroll
        for (int j = 0; j < 4; ++j) {
            int e = e0 + j;
            int co = e >> 10, rem = e & 1023, k = rem >> 6, ci = rem & 63;
            long si = ((long)(co * 64 + ci)) * 16 + k;
            float v = bf ? ldT<1>(w2, si) : ldT<0>(w2, si);
            wb2[e] = fToBits(v);
        }
    } else if (b < 640) {                       // dcn3: 524288 = 512 blocks
        int e0 = (b - 128) * 1024 + threadIdx.x * 4;
        #pragma unroll
        for (int j = 0; j < 4; ++j) {
            int e = e0 + j;
            int co = e >> 11, rem = e & 2047, k = rem >> 7, ci = rem & 127;
            long si = ((long)(co * 128 + ci)) * 16 + k;
            float v = bf ? ldT<1>(w3, si) : ldT<0>(w3, si);
            wb3[e] = fToBits(v);
        }
    } else if (b < 665) {                       // off1: 160x160 = 25 blocks
        int e0 = (b - 640) * 1024 + threadIdx.x * 4;
        #pragma unroll
        for (int j = 0; j < 4; ++j) {
            int e = e0 + j;
            int co = e / 160, k = e - co * 160;
            float v = 0.f;
            if (co < 147 && k < 147) {
                long si = (long)co * 147 + k;
                v = bf ? ldT<1>(w1o, si) : ldT<0>(w1o, si);
            }
            wb1o[e] = fToBits(v);
        }
    } else if (b < 675) {                       // dcn1: 64x160 = 10 blocks
        int e0 = (b - 665) * 1024 + threadIdx.x * 4;
        #pragma unroll
        for (int j = 0; j < 4; ++j) {
            int e = e0 + j;
            int co = e / 160, k = e - co * 160;
            float v = 0.f;
            if (k < 147) {
                long si = (long)co * 147 + k;
                v = bf ? ldT<1>(w1d, si) : ldT<0>(w1d, si);
            }
            wb1d[e] = fToBits(v);
        }
    } else if (b < 739) {                       // off2 pad64: 65536 = 64 blocks
        int e0 = (b - 675) * 1024 + threadIdx.x * 4;
        #pragma unroll
        for (int j = 0; j < 4; ++j) {
            int e = e0 + j;
            int co = e >> 10, rem = e & 1023, k = rem >> 6, ci = rem & 63;
            float v = 0.f;
            if (co < 48) {
                long si = ((long)(co * 64 + ci)) * 16 + k;
                v = bf ? ldT<1>(w2o, si) : ldT<0>(w2o, si);
            }
            wb2o[e] = fToBits(v);
        }
    } else {                                    // off3 pad64: 131072 = 128 blocks
        int e0 = (b - 739) * 1024 + threadIdx.x * 4;
        #pragma unroll
        for (int j = 0; j < 4; ++j) {
            int e = e0 + j;
            int co = e >> 11, rem = e & 2047, k = rem >> 7, ci = rem & 127;
            float v = 0.f;
            if (co < 48) {
                long si = ((long)(co * 128 + ci)) * 16 + k;
                v = bf ? ldT<1>(w3o, si) : ldT<0>(w3o, si);
            }
            wb3o[e] = fToBits(v);
        }
    }
}

// ---- res weights: src[co][ci*9+q] (flag dtype) -> bf16 [q][co][ci] --------
struct RbPack { const void* src[4]; };
__global__ __launch_bounds__(TPB) void repack_rb_kernel(
    RbPack rp, float* fw, const int* dflag)
{
    __shared__ unsigned short lw[4 * 2304];
    int b = blockIdx.x;
    int ten = b >> 6;
    int co0 = (b & 63) * 4;
    const void* src = rp.src[ten];
    const long dstOff[4] = {RB1W1T, RB1W2T, RB2W1T, RB2W2T};
    unsigned short* dst = (unsigned short*)(fw + dstOff[ten]);
    int bf = *dflag;
    int t = threadIdx.x;
    for (int e = t; e < 4 * 2304; e += TPB) {
        int coL = e / 2304, i = e - coL * 2304;
        long si = (long)(co0 + coL) * 2304 + i;
        float v = bf ? ldT<1>(src, si) : ldT<0>(src, si);
        lw[e] = fToBits(v);
    }
    __syncthreads();
    for (int e = t; e < 9216; e += TPB) {     // 9216 = 9q * 4co * 256ci
        int ci = e & 255, coL = (e >> 8) & 3, q = e >> 10;
        dst[((long)q * 256 + co0 + coL) * 256 + ci] = lw[coL * 2304 + ci * 9 + q];
    }
}

// ===========================================================================
// x (NCHW flag dtype, 3ch) -> x4 bf16 [n][256][256][4] (ch 3 = 0 pad).
// ===========================================================================
template<int BF>
__device__ void x_to_cl4_body(const void* __restrict__ x, unsigned short* __restrict__ x4)
{
    long gid = (long)blockIdx.x * TPB + threadIdx.x;   // 0..131071
    int n = (int)(gid >> 16); int p = (int)(gid & 65535);
    long xb = (long)n * 3 * 65536 + p;
    unsigned c0 = fToBits(ldT<BF>(x, xb));
    unsigned c1 = fToBits(ldT<BF>(x, xb + 65536));
    unsigned c2 = fToBits(ldT<BF>(x, xb + 131072));
    uint2 v; v.x = c0 | (c1 << 16); v.y = c2;
    *(uint2*)&x4[gid * 4] = v;
}
__global__ __launch_bounds__(TPB) void x_to_cl4_kernel(
    const void* x, unsigned short* x4, const int* dflag)
{
    if (*dflag) x_to_cl4_body<1>(x, x4);
    else        x_to_cl4_body<0>(x, x4);
}

// ===========================================================================
// MFMA fused layer 1 v4 (validated round 8)
// ===========================================================================
template<int BF>
__device__ void layer1_mfma_body(
    const unsigned short* __restrict__ x4all, const unsigned short* __restrict__ wo,
    const unsigned short* __restrict__ wd, const float* __restrict__ bias1,
    const float* __restrict__ bias2, void* __restrict__ out, long obase,
    float* xs, unsigned short* A, float* offs)
{
    int b = blockIdx.x;
    int n = b >> 11;
    int ho = (b >> 3) & 255;
    int wo0 = (b & 7) << 5;
    const unsigned short* x4 = x4all + ((long)n << 16) * 4;
    int t = threadIdx.x;

    // ---- phase 1a: stage x patch [3ci][7ky][40 cols] from x4 (8B loads) --
    for (int e = t; e < 7 * 40; e += TPB) {
        int cc = e % 40, rr = e / 40;
        int yy = ho - 3 + rr; int xx = wo0 - 3 + cc;
        float c0 = 0.f, c1 = 0.f, c2 = 0.f;
        if (cc < 38 && yy >= 0 && yy < 256 && xx >= 0 && xx < 256) {
            uint2 v = *(const uint2*)&x4[((long)yy * 256 + xx) * 4];
            c0 = bitsToF((unsigned short)(v.x & 0xffff));
            c1 = bitsToF((unsigned short)(v.x >> 16));
            c2 = bitsToF((unsigned short)(v.y & 0xffff));
        }
        xs[(0 * 7 + rr) * 40 + cc] = c0;
        xs[(1 * 7 + rr) * 40 + cc] = c1;
        xs[(2 * 7 + rr) * 40 + cc] = c2;
    }
    __syncthreads();

    // ---- phase 1b: im2col -> A[kc][m][32] bf16, k = ci*49+ky*7+kx --------
    for (int e = t; e < 5120; e += TPB) {
        int kin = e & 31, m = (e >> 5) & 31, kc = e >> 10;
        int k = kc * 32 + kin;
        float v = 0.f;
        if (k < 147) {
            int ci = k / 49, q = k - ci * 49;
            int ky = q / 7, kx = q - ky * 7;
            v = xs[(ci * 7 + ky) * 40 + m + kx];
        }
        A[kc * 1024 + m * 32 + kin] = fToBits(v);
    }
    __syncthreads();

    int wv = t >> 6, lane = t & 63;
    int quad = lane >> 4, l16 = lane & 15;
    int mt = wv & 1, ntb = wv >> 1;

    // ---- phase 2: MFMA offset conv (N=160, 10 n-tiles over 2 wave-groups)-
    {
        f32x4 acc[5];
        #pragma unroll
        for (int j = 0; j < 5; ++j) acc[j] = (f32x4){0.f, 0.f, 0.f, 0.f};
        #pragma unroll
        for (int kc = 0; kc < 5; ++kc) {
            bf16x8 a = *(const bf16x8*)&A[(kc * 32 + mt * 16 + l16) * 32 + quad * 8];
            #pragma unroll
            for (int j = 0; j < 5; ++j) {
                int ch = (ntb + 2 * j) * 16 + l16;
                bf16x8 bw = *(const bf16x8*)&wo[ch * 160 + kc * 32 + quad * 8];
                acc[j] = __builtin_amdgcn_mfma_f32_16x16x32_bf16(a, bw, acc[j], 0, 0, 0);
            }
        }
        #pragma unroll
        for (int j = 0; j < 5; ++j) {
            int ch = (ntb + 2 * j) * 16 + l16;
            if (ch < 147) {
                float bv = bias1[ch];
                #pragma unroll
                for (int reg = 0; reg < 4; ++reg) {
                    int m = mt * 16 + quad * 4 + reg;
                    offs[ch * 33 + m] = acc[j][reg] + bv;
                }
            }
        }
    }
    __syncthreads();

    // ---- phase 3: p in lane (coalesced 8B taps); in-place sample write ----
    for (int e = t; e < 49 * 32; e += TPB) {
        int p = e & 31; int k = e >> 5;
        float oy = offs[k * 33 + p];
        float ox = offs[(49 + k) * 33 + p];
        float mr = offs[(98 + k) * 33 + p];
        float m = 1.f / (1.f + expf(-mr));
        float py = (float)(ho - 3 + k / 7) + oy;
        float px = (float)(wo0 + p - 3 + k % 7) + ox;
        float y0f = floorf(py), x0f = floorf(px);
        float wy = py - y0f, wx = px - x0f;
        int y0 = (int)y0f, x0 = (int)x0f;
        bool yv0 = (y0 >= 0) && (y0 < 256);
        bool yv1 = (y0 + 1 >= 0) && (y0 + 1 < 256);
        bool xv0 = (x0 >= 0) && (x0 < 256);
        bool xv1 = (x0 + 1 >= 0) && (x0 + 1 < 256);
        int y0c = min(max(y0, 0), 255), y1c = min(max(y0 + 1, 0), 255);
        int x0c = min(max(x0, 0), 255), x1c = min(max(x0 + 1, 0), 255);
        float w00 = (yv0 && xv0) ? (1.f - wy) * (1.f - wx) * m : 0.f;
        float w01 = (yv0 && xv1) ? (1.f - wy) * wx * m : 0.f;
        float w10 = (yv1 && xv0) ? wy * (1.f - wx) * m : 0.f;
        float w11 = (yv1 && xv1) ? wy * wx * m : 0.f;
        uint2 a00 = *(const uint2*)&x4[((long)y0c * 256 + x0c) * 4];
        uint2 a01 = *(const uint2*)&x4[((long)y0c * 256 + x1c) * 4];
        uint2 a10 = *(const uint2*)&x4[((long)y1c * 256 + x0c) * 4];
        uint2 a11 = *(const uint2*)&x4[((long)y1c * 256 + x1c) * 4];
        float s0 = w00 * bitsToF((unsigned short)(a00.x & 0xffff))
                 + w01 * bitsToF((unsigned short)(a01.x & 0xffff))
                 + w10 * bitsToF((unsigned short)(a10.x & 0xffff))
                 + w11 * bitsToF((unsigned short)(a11.x & 0xffff));
        float s1 = w00 * bitsToF((unsigned short)(a00.x >> 16))
                 + w01 * bitsToF((unsigned short)(a01.x >> 16))
                 + w10 * bitsToF((unsigned short)(a10.x >> 16))
                 + w11 * bitsToF((unsigned short)(a11.x >> 16));
        float s2 = w00 * bitsToF((unsigned short)(a00.y & 0xffff))
                 + w01 * bitsToF((unsigned short)(a01.y & 0xffff))
                 + w10 * bitsToF((unsigned short)(a10.y & 0xffff))
                 + w11 * bitsToF((unsigned short)(a11.y & 0xffff));
        offs[k * 33 + p] = s0;               // in-place, thread-local RAW
        offs[(49 + k) * 33 + p] = s1;
        offs[(98 + k) * 33 + p] = s2;
    }
    __syncthreads();

    // ---- phase 3.5: repack offs(f32) -> A(bf16 MFMA layout) --------------
    for (int e = t; e < 5120; e += TPB) {
        int kin = e & 31, m = (e >> 5) & 31, kc = e >> 10;
        int k = kc * 32 + kin;
        float v = 0.f;
        if (k < 147) v = offs[k * 33 + m];
        A[kc * 1024 + m * 32 + kin] = fToBits(v);
    }
    __syncthreads();

    // ---- phase 4: MFMA deform conv (N=64, 4 n-tiles) ---------------------
    f32x4 acc2[2];
    acc2[0] = (f32x4){0.f, 0.f, 0.f, 0.f};
    acc2[1] = (f32x4){0.f, 0.f, 0.f, 0.f};
    #pragma unroll
    for (int kc = 0; kc < 5; ++kc) {
        bf16x8 a = *(const bf16x8*)&A[(kc * 32 + mt * 16 + l16) * 32 + quad * 8];
        #pragma unroll
        for (int j = 0; j < 2; ++j) {
            int co = (ntb + 2 * j) * 16 + l16;
            bf16x8 bw = *(const bf16x8*)&wd[co * 160 + kc * 32 + quad * 8];
            acc2[j] = __builtin_amdgcn_mfma_f32_16x16x32_bf16(a, bw, acc2[j], 0, 0, 0);
        }
    }
    #pragma unroll
    for (int j = 0; j < 2; ++j) {
        int co = (ntb + 2 * j) * 16 + l16;
        float bv = bias2[co];
        #pragma unroll
        for (int reg = 0; reg < 4; ++reg) {
            int wox = wo0 + mt * 16 + quad * 4 + reg;
            long oi = obase + ((long)(n * 64 + co) * 256 + ho) * 256 + wox;
            stT<BF>(out, oi, acc2[j][reg] + bv);
        }
    }
}

__global__ __launch_bounds__(TPB) void layer1_mfma_kernel(
    const unsigned short* x4, const unsigned short* wo, const unsigned short* wd,
    const float* bias1, const float* bias2, void* out, long obase, const int* dflag)
{
    __shared__ __align__(16) float xs[3 * 7 * 40];
    __shared__ __align__(16) unsigned short A[5120];
    __shared__ __align__(16) float offs[147 * 33];
    if (*dflag) layer1_mfma_body<1>(x4, wo, wd, bias1, bias2, out, obase, xs, A, offs);
    else        layer1_mfma_body<0>(x4, wo, wd, bias1, bias2, out, obase, xs, A, offs);
}

// ===========================================================================
// MFMA offset conv (layers 2/3) v3: staging vectorized to 16B uint4
// (8 channels per load; UN halved vs v2). Tap base multiple of CIN and
// ci multiple of 8 keep all loads/stores 16B-aligned.
// ===========================================================================
template<int CIN, int HH, int WW, int HO, int WO>
__global__ __launch_bounds__(TPB) void offconv_mfma_kernel(
    const unsigned short* __restrict__ xcl, const unsigned short* __restrict__ wb,
    const float* __restrict__ bias_f, float* __restrict__ out)
{
    constexpr int S   = 16 * CIN;
    constexpr int KL  = 512 / CIN;       // taps per 512-i chunk
    constexpr int NCH = 16 / KL;
    constexpr int CH8 = CIN / 8;         // 16B units per (pair, tap)
    constexpr int UN  = (KL * 16 * CH8) / TPB;   // 16B units per thread/chunk
    constexpr int TILES = (HO * WO) / 16;

    __shared__ int tp[256];
    __shared__ __align__(16) unsigned short smp[16 * 512];

    int tile = blockIdx.x % TILES;
    int n    = blockIdx.x / TILES;
    int lp0  = tile * 16;

    // ---- fixed-tap address table: one (k,p) per thread ----
    {
        int pr = threadIdx.x;
        int k = pr >> 4, p = pr & 15;
        int lp = lp0 + p;
        int ho = lp / WO, wo = lp - ho * WO;
        int yy = ho * 2 - 1 + (k >> 2);
        int xx = wo * 2 - 1 + (k & 3);
        bool valid = (yy >= 0) && (yy < HH) && (xx >= 0) && (xx < WW);
        tp[pr] = valid ? (yy * WW + xx) * CIN : -1;
    }

    int wv = threadIdx.x >> 6, lane = threadIdx.x & 63;
    int quad = lane >> 4, l16 = lane & 15;
    const unsigned short* xn = xcl + (long)n * HH * WW * CIN;

    f32x4 acc = (f32x4){0.f, 0.f, 0.f, 0.f};

    for (int ch = 0; ch < NCH; ++ch) {
        __syncthreads();
        #pragma unroll
        for (int u = 0; u < UN; ++u) {
            int e   = u * TPB + threadIdx.x;
            int prl = e / CH8;
            int ci  = (e - prl * CH8) * 8;
            int pi  = ch * (KL * 16) + prl;
            int kl = prl >> 4, p = prl & 15;
            int t0 = tp[pi];
            uint4 v = {0u, 0u, 0u, 0u};
            if (t0 >= 0) v = *(const uint4*)(xn + t0 + ci);
            int il = kl * CIN + ci;
            *(uint4*)&smp[((il >> 5) * 16 + p) * 32 + (il & 31)] = v;
        }
        __syncthreads();
        #pragma unroll 4
        for (int kk = 0; kk < 16; ++kk) {
            bf16x8 a = *(const bf16x8*)&smp[(kk * 16 + l16) * 32 + quad * 8];
            int co = wv * 16 + l16;
            bf16x8 b = *(const bf16x8*)&wb[(long)co * S + ch * 512 + kk * 32 + quad * 8];
            acc = __builtin_amdgcn_mfma_f32_16x16x32_bf16(a, b, acc, 0, 0, 0);
        }
    }

    int co = wv * 16 + l16;
    if (co < 48) {
        float bv = bias_f[co];
        #pragma unroll
        for (int reg = 0; reg < 4; ++reg) {
            int lp = lp0 + quad * 4 + reg;
            int ho = lp / WO, wo = lp - ho * WO;
            out[((long)(n * 48 + co) * HO + ho) * WO + wo] = acc[reg] + bv;
        }
    }
}

// ===========================================================================
// NCHW (flag dtype) -> channels-last bf16 transpose. 64 pixels x C per block.
// ===========================================================================
template<int C>
__global__ __launch_bounds__(TPB) void nchw_to_cl_kernel(
    const void* __restrict__ in, long ibase, unsigned short* __restrict__ out,
    int HW, const int* __restrict__ dflag)
{
    __shared__ unsigned short tile[C * 65];
    int bf = *dflag;
    int n   = (blockIdx.x * 64) / HW;
    int px0 = (blockIdx.x * 64) % HW;
    for (int e = threadIdx.x; e < C * 64; e += TPB) {
        int c = e >> 6, p = e & 63;
        long si = ibase + (long)(n * C + c) * HW + px0 + p;
        float v = bf ? ldT<1>(in, si) : ldT<0>(in, si);
        tile[c * 65 + p] = fToBits(v);
    }
    __syncthreads();
    for (int e = threadIdx.x; e < C * 64; e += TPB) {
        int p = e / C, c = e - p * C;
        out[((long)n * HW + px0 + p) * C + c] = tile[c * 65 + p];
    }
}

// ===========================================================================
// MFMA deformable conv v4 (layers 2/3): gather vectorized to 16B uint4
// (8 channels per tap load; ITER halved vs v3). Tap base multiple of CIN
// and ci multiple of 8 keep all loads/stores 16B-aligned; LDS writes land
// at (il&31) in {0,8,16,24} -> inside one 32-elem row, consecutive.
// ===========================================================================
template<int MODE, int CIN, int COUT, int NWAVES, int HH, int WW, int HO, int WO>
__global__ __launch_bounds__(NWAVES * 64) void deform_mfma_kernel(
    const unsigned short* __restrict__ xcl, const float* __restrict__ off,
    const unsigned short* __restrict__ wb, const float* __restrict__ bias_f,
    void* __restrict__ outp, long obase, const int* __restrict__ dflag)
{
    constexpr int TPBk = NWAVES * 64;
    constexpr int S    = 16 * CIN;       // reduction length
    constexpr int KL   = 512 / CIN;      // kernel-points per 512-i chunk
    constexpr int NCH  = 16 / KL;        // chunks
    constexpr int CH8  = CIN / 8;        // 16B units per (pair, tap)
    constexpr int ITER = (KL * 16 * CH8) / TPBk;   // 16B units per thread/chunk
    constexpr int TILES = (HO * WO) / 16;

    __shared__ __align__(16) int tpw[256][8];      // [pair]{tp0..3, w0..3bits}
    __shared__ __align__(16) unsigned short smp[16 * 512];

    int tile = blockIdx.x % TILES;
    int n    = blockIdx.x / TILES;
    int lp0  = tile * 16;
    int tid  = threadIdx.x;

    // ---- phase A: per-(k,p) offset decode, one pair per thread (first 256)-
    if (tid < 256) {
        int pr = tid;
        int k = pr >> 4, p = pr & 15;
        int lp = lp0 + p;
        int ho = lp / WO, wo = lp - ho * WO;
        long plane = (long)HO * WO;
        const float* offn = off + (long)n * 48 * plane;
        float oy = offn[(long)k * plane + lp];
        float ox = offn[(long)(16 + k) * plane + lp];
        float mr = offn[(long)(32 + k) * plane + lp];
        float m = 1.f / (1.f + expf(-mr));
        float py = (float)(ho * 2 - 1 + (k >> 2)) + oy;
        float px = (float)(wo * 2 - 1 + (k & 3)) + ox;
        float y0f = floorf(py), x0f = floorf(px);
        float wy = py - y0f, wx = px - x0f;
        int y0 = (int)y0f, x0 = (int)x0f;
        bool yv0 = (y0 >= 0) && (y0 < HH);
        bool yv1 = (y0 + 1 >= 0) && (y0 + 1 < HH);
        bool xv0 = (x0 >= 0) && (x0 < WW);
        bool xv1 = (x0 + 1 >= 0) && (x0 + 1 < WW);
        int y0c = min(max(y0, 0), HH - 1), y1c = min(max(y0 + 1, 0), HH - 1);
        int x0c = min(max(x0, 0), WW - 1), x1c = min(max(x0 + 1, 0), WW - 1);
        tpw[pr][0] = (y0c * WW + x0c) * CIN;
        tpw[pr][1] = (y0c * WW + x1c) * CIN;
        tpw[pr][2] = (y1c * WW + x0c) * CIN;
        tpw[pr][3] = (y1c * WW + x1c) * CIN;
        tpw[pr][4] = __float_as_int((yv0 && xv0) ? (1.f - wy) * (1.f - wx) * m : 0.f);
        tpw[pr][5] = __float_as_int((yv0 && xv1) ? (1.f - wy) * wx * m : 0.f);
        tpw[pr][6] = __float_as_int((yv1 && xv0) ? wy * (1.f - wx) * m : 0.f);
        tpw[pr][7] = __float_as_int((yv1 && xv1) ? wy * wx * m : 0.f);
    }

    int wv = tid >> 6, lane = tid & 63;
    int quad = lane >> 4, l16 = lane & 15;
    int cb = (wv & 3) * 32 + (wv >> 2) * (COUT / 2);
    const unsigned short* xn = xcl + (long)n * HH * WW * CIN;

    f32x4 acc[2];
    acc[0] = (f32x4){0.f, 0.f, 0.f, 0.f};
    acc[1] = (f32x4){0.f, 0.f, 0.f, 0.f};

    for (int ch = 0; ch < NCH; ++ch) {
        __syncthreads();   // covers phase A (ch=0) and prev MFMA reads
        #pragma unroll
        for (int it = 0; it < ITER; ++it) {
            int e   = it * TPBk + tid;
            int prl = e / CH8;                  // pair within chunk
            int ci  = (e - prl * CH8) * 8;      // ci multiple of 8
            int pi  = ch * (KL * 16) + prl;
            const int4   tp4 = *(const int4*)&tpw[pi][0];
            const float4 tw4 = *(const float4*)&tpw[pi][4];
            uint4 u0 = *(const uint4*)(xn + tp4.x + ci);
            uint4 u1 = *(const uint4*)(xn + tp4.y + ci);
            uint4 u2 = *(const uint4*)(xn + tp4.z + ci);
            uint4 u3 = *(const uint4*)(xn + tp4.w + ci);
            float r[8];
            #pragma unroll
            for (int jj = 0; jj < 8; ++jj) {
                unsigned w0 = ((const unsigned*)&u0)[jj >> 1];
                unsigned w1 = ((const unsigned*)&u1)[jj >> 1];
                unsigned w2 = ((const unsigned*)&u2)[jj >> 1];
                unsigned w3 = ((const unsigned*)&u3)[jj >> 1];
                int sh = (jj & 1) << 4;
                r[jj] = tw4.x * bitsToF((unsigned short)(w0 >> sh))
                      + tw4.y * bitsToF((unsigned short)(w1 >> sh))
                      + tw4.z * bitsToF((unsigned short)(w2 >> sh))
                      + tw4.w * bitsToF((unsigned short)(w3 >> sh));
            }
            uint4 ov;
            ((unsigned*)&ov)[0] = (unsigned)fToBits(r[0]) | ((unsigned)fToBits(r[1]) << 16);
            ((unsigned*)&ov)[1] = (unsigned)fToBits(r[2]) | ((unsigned)fToBits(r[3]) << 16);
            ((unsigned*)&ov)[2] = (unsigned)fToBits(r[4]) | ((unsigned)fToBits(r[5]) << 16);
            ((unsigned*)&ov)[3] = (unsigned)fToBits(r[6]) | ((unsigned)fToBits(r[7]) << 16);
            int il = (prl >> 4) * CIN + ci;     // i within chunk [0,512)
            int p  = prl & 15;
            *(uint4*)&smp[((il >> 5) * 16 + p) * 32 + (il & 31)] = ov;
        }
        __syncthreads();
        #pragma unroll 4
        for (int kk = 0; kk < 16; ++kk) {
            bf16x8 a = *(const bf16x8*)&smp[(kk * 16 + l16) * 32 + quad * 8];
            #pragma unroll
            for (int f = 0; f < 2; ++f) {
                int co = cb + f * 16 + l16;
                bf16x8 b = *(const bf16x8*)&wb[(long)co * S + ch * 512 + kk * 32 + quad * 8];
                acc[f] = __builtin_amdgcn_mfma_f32_16x16x32_bf16(a, b, acc[f], 0, 0, 0);
            }
        }
    }

    // ---- epilogue: pixel = quad*4+reg, co = cb + f*16 + l16 ----
    if (MODE == 1) {
        unsigned short* oCL = (unsigned short*)outp;
        #pragma unroll
        for (int f = 0; f < 2; ++f) {
            int co = cb + f * 16 + l16;
            float bv = bias_f[co];
            #pragma unroll
            for (int reg = 0; reg < 4; ++reg) {
                int lp = lp0 + quad * 4 + reg;
                oCL[((long)n * HO * WO + lp) * COUT + co] = fToBits(acc[f][reg] + bv);
            }
        }
    } else {
        int bf = *dflag;
        #pragma unroll
        for (int f = 0; f < 2; ++f) {
            int co = cb + f * 16 + l16;
            float bv = bias_f[co];
            #pragma unroll
            for (int reg = 0; reg < 4; ++reg) {
                int lp = lp0 + quad * 4 + reg;
                int ho = lp / WO, wo = lp - ho * WO;
                long oi = obase + ((long)(n * COUT + co) * HO + ho) * WO + wo;
                if (bf) stT<1>(outp, oi, acc[f][reg] + bv);
                else    stT<0>(outp, oi, acc[f][reg] + bv);
            }
        }
    }
}

// ===========================================================================
// MFMA res-block 3x3 reflect conv v2 (validated round 4/8)
// ===========================================================================
__global__ __launch_bounds__(TPB) void resconv_mfma_kernel(
    const unsigned short* __restrict__ X, const unsigned short* __restrict__ W,
    const float* __restrict__ bias_f, bf16* __restrict__ Y)
{
    __shared__ __align__(16) unsigned short xs[3 * 66 * 64];   // 25344 B, swizzled
    int b = blockIdx.x;
    int coO = b & 7, r = (b >> 3) & 63, n = b >> 9;
    int t = threadIdx.x;
    int wv = t >> 6;
    int lane = t & 63;
    int quad = lane >> 4, l16 = lane & 15;
    int rows[3];
    rows[0] = (r == 0) ? 1 : r - 1;
    rows[1] = r;
    rows[2] = (r == 63) ? 62 : r + 1;

    f32x4 acc[2];
    acc[0] = (f32x4){0.f, 0.f, 0.f, 0.f};
    acc[1] = (f32x4){0.f, 0.f, 0.f, 0.f};

    long xbase = (long)n * 4096 * 256;

    for (int ci0 = 0; ci0 < 256; ci0 += 64) {
        __syncthreads();
        // stage [3ky][66col][64ci] via 16B loads; swizzled 16B slot per col
        for (int e = t; e < 3 * 66 * 8; e += TPB) {
            int oct = e & 7;
            int col = (e >> 3) % 66;
            int ky  = e / (66 * 8);
            int gx = col - 1;
            gx = (gx < 0) ? 1 : ((gx > 63) ? 62 : gx);
            bf16x8 v = *(const bf16x8*)&X[xbase + ((long)rows[ky] * 64 + gx) * 256 + ci0 + oct * 8];
            int slot = oct ^ (col & 7);
            *(bf16x8*)&xs[((ky * 66 + col) << 6) + slot * 8] = v;
        }
        __syncthreads();
        #pragma unroll
        for (int q = 0; q < 9; ++q) {
            int ky = q / 3, kx = q % 3;
            int col = wv * 16 + l16 + kx;        // lds col = global col +1
            int base = (ky * 66 + col) << 6;
            #pragma unroll
            for (int kh = 0; kh < 2; ++kh) {
                int slot = (kh * 4 + quad) ^ (col & 7);
                bf16x8 a = *(const bf16x8*)&xs[base + slot * 8];
                #pragma unroll
                for (int ct = 0; ct < 2; ++ct) {
                    int co = coO * 32 + ct * 16 + l16;
                    bf16x8 bw = *(const bf16x8*)&W[((long)q * 256 + co) * 256 + ci0 + kh * 32 + quad * 8];
                    acc[ct] = __builtin_amdgcn_mfma_f32_16x16x32_bf16(a, bw, acc[ct], 0, 0, 0);
                }
            }
        }
    }

    long ybase = ((long)n * 4096 + (long)r * 64) * 256;
    #pragma unroll
    for (int ct = 0; ct < 2; ++ct) {
        int co = coO * 32 + ct * 16 + l16;
        float bv = bias_f[co];
        #pragma unroll
        for (int reg = 0; reg < 4; ++reg) {
            int px = wv * 16 + quad * 4 + reg;
            Y[ybase + (long)px * 256 + co] = __float2bfloat16(acc[ct][reg] + bv);
        }
    }
}

// ===========================================================================
// Channels-last instance-norm: WIDE partial stats (validated round 10)
// ===========================================================================
__global__ __launch_bounds__(TPB) void cl_stats_kernel(
    const unsigned short* __restrict__ X, float* __restrict__ psum, float* __restrict__ psq)
{
    int blk = blockIdx.x;
    int chunk = blk & 63, n = blk >> 6;
    int co = threadIdx.x;
    float s = 0.f, sq = 0.f;
    const unsigned short* p = X + ((long)n * 4096 + chunk * 64) * 256 + co;
    #pragma unroll 8
    for (int i = 0; i < 64; ++i) {
        float v = bitsToF(p[(long)i * 256]);
        s += v; sq += v * v;
    }
    psum[(n * 64 + chunk) * 256 + co] = s;
    psq [(n * 64 + chunk) * 256 + co] = sq;
}

__device__ __forceinline__ void cl_load_stats(
    const float* psum, const float* psq, int n, float* mv, float* iv)
{
    int t = threadIdx.x;   // t = channel
    float s = 0.f, sq = 0.f;
    #pragma unroll 8
    for (int c = 0; c < 64; ++c) {
        s  += psum[(n * 64 + c) * 256 + t];
        sq += psq [(n * 64 + c) * 256 + t];
    }
    float mean = s / 4096.f;
    mv[t] = mean;
    iv[t] = rsqrtf(sq / 4096.f - mean * mean + 1e-5f);
    __syncthreads();
}

// grid 128 = n*64 + y; in-place X = relu?((X-m)*inv), uint-vectorized
__global__ __launch_bounds__(TPB) void cl_apply_kernel(
    unsigned short* __restrict__ X, const float* __restrict__ psum,
    const float* __restrict__ psq, int relu)
{
    __shared__ float mv[256], iv[256];
    int y = blockIdx.x & 63, n = blockIdx.x >> 6;
    cl_load_stats(psum, psq, n, mv, iv);
    unsigned* row = (unsigned*)(X + ((long)n * 4096 + y * 64) * 256);
    for (int e = threadIdx.x; e < 8192; e += TPB) {
        int co = (e * 2) & 255;
        unsigned u = row[e];
        float v0 = (bitsToF((unsigned short)(u & 0xffff)) - mv[co]) * iv[co];
        float v1 = (bitsToF((unsigned short)(u >> 16)) - mv[co + 1]) * iv[co + 1];
        if (relu) { v0 = fmaxf(v0, 0.f); v1 = fmaxf(v1, 0.f); }
        row[e] = (unsigned)fToBits(v0) | ((unsigned)fToBits(v1) << 16);
    }
}

// grid 128; H += IN(T), uint-vectorized
__global__ __launch_bounds__(TPB) void cl_apply_add_kernel(
    const unsigned short* __restrict__ T, unsigned short* __restrict__ H,
    const float* __restrict__ psum, const float* __restrict__ psq)
{
    __shared__ float mv[256], iv[256];
    int y = blockIdx.x & 63, n = blockIdx.x >> 6;
    cl_load_stats(psum, psq, n, mv, iv);
    long base = ((long)n * 4096 + y * 64) * 256;
    const unsigned* tr = (const unsigned*)(T + base);
    unsigned* hr = (unsigned*)(H + base);
    for (int e = threadIdx.x; e < 8192; e += TPB) {
        int co = (e * 2) & 255;
        unsigned ut = tr[e], uh = hr[e];
        float v0 = bitsToF((unsigned short)(uh & 0xffff))
                 + (bitsToF((unsigned short)(ut & 0xffff)) - mv[co]) * iv[co];
        float v1 = bitsToF((unsigned short)(uh >> 16))
                 + (bitsToF((unsigned short)(ut >> 16)) - mv[co + 1]) * iv[co + 1];
        hr[e] = (unsigned)fToBits(v0) | ((unsigned)fToBits(v1) << 16);
    }
}

// grid 128; out(NCHW, flag dtype) = H + IN(T)   (transposes channels-last)
__global__ __launch_bounds__(TPB) void cl_apply_final_kernel(
    const unsigned short* __restrict__ T, const unsigned short* __restrict__ H,
    void* __restrict__ outp, const float* __restrict__ psum,
    const float* __restrict__ psq, const int* __restrict__ dflag)
{
    __shared__ float mv[256], iv[256];
    int y = blockIdx.x & 63, n = blockIdx.x >> 6;
    cl_load_stats(psum, psq, n, mv, iv);
    int bf = *dflag;
    int x = threadIdx.x & 63, cg = threadIdx.x >> 6;
    for (int co = cg; co < 256; co += 4) {
        long cli = ((long)(n * 64 + y) * 64 + x) * 256 + co;
        float v = bitsToF(H[cli]) + (bitsToF(T[cli]) - mv[co]) * iv[co];
        long oi = (((long)(n * 256 + co)) * 64 + y) * 64 + x;
        if (bf) ((bf16*)outp)[oi] = __float2bfloat16(v);
        else    ((float*)outp)[oi] = v;
    }
}

// ---------------- block reduction (up to 16 waves) -------------------------
__device__ __forceinline__ void reduce2(float& sum, float& sq, float* s1, float* s2)
{
    for (int off = 32; off; off >>= 1) {
        sum += __shfl_down(sum, off, 64);
        sq  += __shfl_down(sq,  off, 64);
    }
    int nw = blockDim.x >> 6;
    int wid = threadIdx.x >> 6;
    if ((threadIdx.x & 63) == 0) { s1[wid] = sum; s2[wid] = sq; }
    __syncthreads();
    sum = 0.f; sq = 0.f;
    for (int w = 0; w < nw; ++w) { sum += s1[w]; sq += s2[w]; }
}

// ---------------- instance norm for skip1/skip2 (d_out, flag dtype) --------
__global__ void instnorm_kernel(
    void* __restrict__ buf, long base0, const int* __restrict__ dflag,
    int HW, int relu)
{
    __shared__ float s1[16], s2[16];
    int bf = *dflag;
    long base = base0 + (long)blockIdx.x * HW;
    float sum = 0.f, sq = 0.f;
    for (int i = threadIdx.x; i < HW; i += blockDim.x) {
        float v = bf ? bitsToF(((const unsigned short*)buf)[base + i])
                     : ((const float*)buf)[base + i];
        sum += v; sq += v * v;
    }
    reduce2(sum, sq, s1, s2);
    float mean = sum / HW;
    float inv = rsqrtf(sq / HW - mean * mean + 1e-5f);
    for (int i = threadIdx.x; i < HW; i += blockDim.x) {
        float v = bf ? bitsToF(((const unsigned short*)buf)[base + i])
                     : ((const float*)buf)[base + i];
        v = (v - mean) * inv;
        if (relu) v = fmaxf(v, 0.f);
        if (bf) ((bf16*)buf)[base + i] = __float2bfloat16(v);
        else    ((float*)buf)[base + i] = v;
    }
}

// ---------------------------------------------------------------------------
extern "C" void kernel_launch(void* const* d_in, const int* in_sizes, int n_in,
                              void* d_out, int out_size, void* d_ws, size_t ws_size,
                              hipStream_t stream) {
    const void* x = d_in[0];

    const long SKIP1 = 2097152;
    const long SKIP2 = 10485760;

    int* dflag = (int*)d_ws;
    float* fw = (float*)((char*)d_ws + 64);

    unsigned short* t1 = (unsigned short*)(fw + FB);
    unsigned short* t2 = (unsigned short*)(fw + FB + 1048576);
    unsigned short* h3 = (unsigned short*)(fw + H3F);
    float* offb = fw + OFFB;
    unsigned short* x4 = (unsigned short*)(fw + OFFB);   // layer-1 only; dead after
    float* psum = fw + PST1;
    float* psq  = fw + PST2;
    unsigned short* clbuf = (unsigned short*)(fw + CLBUF);    // skip1_cl then skip2_cl
    const unsigned short* wb1o = (const unsigned short*)(fw + WB1OT);
    const unsigned short* wb1d = (const unsigned short*)(fw + WB1DT);
    const unsigned short* wb2o = (const unsigned short*)(fw + WO2T);
    const unsigned short* wb3o = (const unsigned short*)(fw + WO3T);
    const unsigned short* wb2 = (const unsigned short*)(fw + WB2T);
    const unsigned short* wb3 = (const unsigned short*)(fw + WB3T);
    const unsigned short* rbw1 = (const unsigned short*)(fw + RB1W1T);
    const unsigned short* rbw2 = (const unsigned short*)(fw + RB1W2T);
    const unsigned short* rbw3 = (const unsigned short*)(fw + RB2W1T);
    const unsigned short* rbw4 = (const unsigned short*)(fw + RB2W2T);

    detect_kernel<<<1, 64, 0, stream>>>(x, dflag);

    // ---- weight/bias repack ----
    PtrPack pp;
    for (int i = 0; i < 10; ++i) pp.p[i] = nullptr;
    pp.p[10] = d_in[2];  pp.p[11] = d_in[4];  pp.p[12] = d_in[6];  pp.p[13] = d_in[8];
    pp.p[14] = d_in[10]; pp.p[15] = d_in[12]; pp.p[16] = d_in[14]; pp.p[17] = d_in[16];
    pp.p[18] = d_in[18]; pp.p[19] = d_in[20];
    repack_all_kernel<<<2, TPB, 0, stream>>>(pp, fw, dflag);
    repack_dcn_kernel<<<867, TPB, 0, stream>>>(
        d_in[7], d_in[11], d_in[1], d_in[3], d_in[5], d_in[9], fw, dflag);
    RbPack rp;
    rp.src[0] = d_in[13]; rp.src[1] = d_in[15]; rp.src[2] = d_in[17]; rp.src[3] = d_in[19];
    repack_rb_kernel<<<256, TPB, 0, stream>>>(rp, fw, dflag);

    // ---- Layer 1 fused MFMA: offsets + deform, 7x7 s1 p3 ----
    x_to_cl4_kernel<<<512, TPB, 0, stream>>>(x, x4, dflag);
    layer1_mfma_kernel<<<4096, TPB, 0, stream>>>(
        x4, wb1o, wb1d, fw + OFF1B, fw + DCN1B, d_out, SKIP1, dflag);
    instnorm_kernel<<<128, 1024, 0, stream>>>(d_out, SKIP1, dflag, 65536, 1);
    // skip1 -> channels-last bf16 for the MFMA conv gathers
    nchw_to_cl_kernel<64><<<2048, TPB, 0, stream>>>(d_out, SKIP1, clbuf, 65536, dflag);

    // ---- Layer 2: 4x4 s2 p1, Cin=64 ----
    offconv_mfma_kernel<64, 256, 256, 128, 128><<<2048, TPB, 0, stream>>>(
        clbuf, wb2o, fw + OFF2B, offb);
    deform_mfma_kernel<0, 64, 128, 4, 256, 256, 128, 128><<<2048, TPB, 0, stream>>>(
        clbuf, offb, wb2, fw + DCN2B, d_out, SKIP2, dflag);
    instnorm_kernel<<<256, 512, 0, stream>>>(d_out, SKIP2, dflag, 16384, 1);
    // skip2 -> channels-last bf16 (reuses clbuf; skip1_cl is dead now)
    nchw_to_cl_kernel<128><<<512, TPB, 0, stream>>>(d_out, SKIP2, clbuf, 16384, dflag);

    // ---- Layer 3: 4x4 s2 p1, Cin=128; output bf16 channels-last h3 ----
    offconv_mfma_kernel<128, 128, 128, 64, 64><<<512, TPB, 0, stream>>>(
        clbuf, wb3o, fw + OFF3B, offb);
    deform_mfma_kernel<1, 128, 256, 8, 128, 128, 64, 64><<<512, 512, 0, stream>>>(
        clbuf, offb, wb3, fw + DCN3B, h3, 0, dflag);
    cl_stats_kernel<<<128, TPB, 0, stream>>>(h3, psum, psq);
    cl_apply_kernel<<<128, TPB, 0, stream>>>(h3, psum, psq, 1);

    // ---- Res block 1 (MFMA) ----
    resconv_mfma_kernel<<<1024, TPB, 0, stream>>>(h3, rbw1, fw + RB1B1, (bf16*)t1);
    cl_stats_kernel<<<128, TPB, 0, stream>>>(t1, psum, psq);
    cl_apply_kernel<<<128, TPB, 0, stream>>>(t1, psum, psq, 1);
    resconv_mfma_kernel<<<1024, TPB, 0, stream>>>(t1, rbw2, fw + RB1B2, (bf16*)t2);
    cl_stats_kernel<<<128, TPB, 0, stream>>>(t2, psum, psq);
    cl_apply_add_kernel<<<128, TPB, 0, stream>>>(t2, h3, psum, psq);

    // ---- Res block 2 (MFMA; final writes NCHW d_out per flag) ----
    resconv_mfma_kernel<<<1024, TPB, 0, stream>>>(h3, rbw3, fw + RB2B1, (bf16*)t1);
    cl_stats_kernel<<<128, TPB, 0, stream>>>(t1, psum, psq);
    cl_apply_kernel<<<128, TPB, 0, stream>>>(t1, psum, psq, 1);
    resconv_mfma_kernel<<<1024, TPB, 0, stream>>>(t1, rbw4, fw + RB2B2, (bf16*)t2);
    cl_stats_kernel<<<128, TPB, 0, stream>>>(t2, psum, psq);
    cl_apply_final_kernel<<<128, TPB, 0, stream>>>(t2, h3, d_out, psum, psq, dflag);
}

// Round 16
// 817.789 us; speedup vs baseline: 1.1392x; 1.0311x over previous
//
#include <hip/hip_runtime.h>
#include <hip/hip_bf16.h>
#include <math.h>

#define TPB 256
typedef __hip_bfloat16 bf16;
typedef short bf16x8 __attribute__((ext_vector_type(8)));   // 8 bf16 (4 VGPRs)
typedef float f32x4 __attribute__((ext_vector_type(4)));

// ---------------- ws layout constants (fp32-element offsets from fw) -------
constexpr long BIASF  = 0;          // 1715 packed fp32 biases (pad to 2048)
constexpr long RB1W1T = 2048;       // res weights bf16 [9][256co][256ci]
constexpr long RB1W2T = 591872;
constexpr long RB2W1T = 1181696;
constexpr long RB2W2T = 1771520;
constexpr long FB     = 2361344;    // multi-use region
constexpr long WB1OT  = 2361344;    // bf16 [160][160] off1 weights (16B aligned)
constexpr long WB1DT  = 2382956;    // bf16 [64][160] dcn1 weights (16B aligned)
constexpr long WO2T   = 2392364;    // bf16 [64co pad][1024] off2 weights
constexpr long WB2T   = 2441516;    // bf16 [128co][1024] deform2 weights (16B aligned)
constexpr long WO3T   = 2572588;    // bf16 [64co pad][2048] off3 weights
constexpr long WB3T   = 2670892;    // bf16 [256co][2048] deform3 weights (16B aligned)
constexpr long OFFB   = 3221504;    // offsets layers 2/3; x4 during layer 1
constexpr long H3F    = 4458496;    // h3 bf16 channels-last, 1048576 floats
constexpr long CLBUF  = 5523456;    // channels-last bf16 skip1/skip2
constexpr long PST1   = 7620608;    // IN partial sums  (cl: [2][64][256]; nchw: [2][C][8])
constexpr long PST2   = 7653376;    // IN partial sumsq
// bias sub-offsets
constexpr long OFF1B = 0,   DCN1B = 147;
constexpr long OFF2B = 211, DCN2B = 259;
constexpr long OFF3B = 387, DCN3B = 435;
constexpr long RB1B1 = 691, RB1B2 = 947;
constexpr long RB2B1 = 1203, RB2B2 = 1459;

// ---- compile-time dtype accessors (BF=1: bf16, BF=0: fp32) ----------------
template<int BF>
__device__ __forceinline__ float ldT(const void* p, long i) {
    if (BF) {
        unsigned short h = ((const unsigned short*)p)[i];
        return __uint_as_float(((unsigned int)h) << 16);
    }
    return ((const float*)p)[i];
}
template<int BF>
__device__ __forceinline__ void stT(void* p, long i, float v) {
    if (BF) ((bf16*)p)[i] = __float2bfloat16(v);
    else    ((float*)p)[i] = v;
}
__device__ __forceinline__ float bitsToF(unsigned short h) {
    return __uint_as_float(((unsigned int)h) << 16);
}
__device__ __forceinline__ unsigned short fToBits(float v) {
    bf16 h = __float2bfloat16(v);
    return *(unsigned short*)&h;
}

// ---- dtype detector (validated rounds 3-9) --------------------------------
__global__ void detect_kernel(const void* __restrict__ x, int* __restrict__ flag) {
    if (threadIdx.x == 0 && blockIdx.x == 0) {
        const unsigned short* u = (const unsigned short*)x;
        int sane = 0;
        for (int i = 0; i < 256; ++i) {
            float v = bitsToF(u[i]);
            float a = fabsf(v);
            if (a > 0.0009f && a < 1100.f) ++sane;
        }
        *flag = (sane >= 224) ? 1 : 0;
    }
}

// ===========================================================================
// Repack: biases -> packed fp32 (grid 2).
// ===========================================================================
struct PtrPack { const void* p[20]; };   // p[10..19]=biases

template<int BF>
__device__ void repack_all_body(PtrPack pp, float* __restrict__ fw)
{
    constexpr int  bcum  [11] = {0,147,211,259,387,435,691,947,1203,1459,1715};
    int j0 = blockIdx.x * 1024 + threadIdx.x * 4;
    #pragma unroll
    for (int q = 0; q < 4; ++q) {
        int j = j0 + q;
        if (j < 1715) {
            int v = 0;
            #pragma unroll
            for (int s = 1; s < 10; ++s) if (j >= bcum[s]) v = s;
            fw[BIASF + j] = ldT<BF>(pp.p[10 + v], j - bcum[v]);
        }
    }
}
__global__ __launch_bounds__(TPB) void repack_all_kernel(
    PtrPack pp, float* fw, const int* dflag) {
    if (*dflag) repack_all_body<1>(pp, fw);
    else        repack_all_body<0>(pp, fw);
}

// ---- conv weights -> bf16 [co][k*CIN+ci] (dst-contiguous writes) ----------
__global__ __launch_bounds__(TPB) void repack_dcn_kernel(
    const void* __restrict__ w2, const void* __restrict__ w3,
    const void* __restrict__ w1o, const void* __restrict__ w1d,
    const void* __restrict__ w2o, const void* __restrict__ w3o,
    float* __restrict__ fw, const int* __restrict__ dflag)
{
    int bf = *dflag;
    unsigned short* wb2 = (unsigned short*)(fw + WB2T);
    unsigned short* wb3 = (unsigned short*)(fw + WB3T);
    unsigned short* wb1o = (unsigned short*)(fw + WB1OT);
    unsigned short* wb1d = (unsigned short*)(fw + WB1DT);
    unsigned short* wb2o = (unsigned short*)(fw + WO2T);
    unsigned short* wb3o = (unsigned short*)(fw + WO3T);
    int b = blockIdx.x;
    if (b < 128) {                              // dcn2: 131072 = 128 blocks
        int e0 = b * 1024 + threadIdx.x * 4;
        #pragma unroll
        for (int j = 0; j < 4; ++j) {
            int e = e0 + j;
            int co = e >> 10, rem = e & 1023, k = rem >> 6, ci = rem & 63;
            long si = ((long)(co * 64 + ci)) * 16 + k;
            float v = bf ? ldT<1>(w2, si) : ldT<0>(w2, si);
            wb2[e] = fToBits(v);
        }
    } else if (b < 640) {                       // dcn3: 524288 = 512 blocks
        int e0 = (b - 128) * 1024 + threadIdx.x * 4;
        #pragma unroll
        for (int j = 0; j < 4; ++j) {
            int e = e0 + j;
            int co = e >> 11, rem = e & 2047, k = rem >> 7, ci = rem & 127;
            long si = ((long)(co * 128 + ci)) * 16 + k;
            float v = bf ? ldT<1>(w3, si) : ldT<0>(w3, si);
            wb3[e] = fToBits(v);
        }
    } else if (b < 665) {                       // off1: 160x160 = 25 blocks
        int e0 = (b - 640) * 1024 + threadIdx.x * 4;
        #pragma unroll
        for (int j = 0; j < 4; ++j) {
            int e = e0 + j;
            int co = e / 160, k = e - co * 160;
            float v = 0.f;
            if (co < 147 && k < 147) {
                long si = (long)co * 147 + k;
                v = bf ? ldT<1>(w1o, si) : ldT<0>(w1o, si);
            }
            wb1o[e] = fToBits(v);
        }
    } else if (b < 675) {                       // dcn1: 64x160 = 10 blocks
        int e0 = (b - 665) * 1024 + threadIdx.x * 4;
        #pragma unroll
        for (int j = 0; j < 4; ++j) {
            int e = e0 + j;
            int co = e / 160, k = e - co * 160;
            float v = 0.f;
            if (k < 147) {
                long si = (long)co * 147 + k;
                v = bf ? ldT<1>(w1d, si) : ldT<0>(w1d, si);
            }
            wb1d[e] = fToBits(v);
        }
    } else if (b < 739) {                       // off2 pad64: 65536 = 64 blocks
        int e0 = (b - 675) * 1024 + threadIdx.x * 4;
        #pragma unroll
        for (int j = 0; j < 4; ++j) {
            int e = e0 + j;
            int co = e >> 10, rem = e & 1023, k = rem >> 6, ci = rem & 63;
            float v = 0.f;
            if (co < 48) {
                long si = ((long)(co * 64 + ci)) * 16 + k;
                v = bf ? ldT<1>(w2o, si) : ldT<0>(w2o, si);
            }
            wb2o[e] = fToBits(v);
        }
    } else {                                    // off3 pad64: 131072 = 128 blocks
        int e0 = (b - 739) * 1024 + threadIdx.x * 4;
        #pragma unroll
        for (int j = 0; j < 4; ++j) {
            int e = e0 + j;
            int co = e >> 11, rem = e & 2047, k = rem >> 7, ci = rem & 127;
            float v = 0.f;
            if (co < 48) {
                long si = ((long)(co * 128 + ci)) * 16 + k;
                v = bf ? ldT<1>(w3o, si) : ldT<0>(w3o, si);
            }
            wb3o[e] = fToBits(v);
        }
    }
}

// ---- res weights: src[co][ci*9+q] (flag dtype) -> bf16 [q][co][ci] --------
struct RbPack { const void* src[4]; };
__global__ __launch_bounds__(TPB) void repack_rb_kernel(
    RbPack rp, float* fw, const int* dflag)
{
    __shared__ unsigned short lw[4 * 2304];
    int b = blockIdx.x;
    int ten = b >> 6;
    int co0 = (b & 63) * 4;
    const void* src = rp.src[ten];
    const long dstOff[4] = {RB1W1T, RB1W2T, RB2W1T, RB2W2T};
    unsigned short* dst = (unsigned short*)(fw + dstOff[ten]);
    int bf = *dflag;
    int t = threadIdx.x;
    for (int e = t; e < 4 * 2304; e += TPB) {
        int coL = e / 2304, i = e - coL * 2304;
        long si = (long)(co0 + coL) * 2304 + i;
        float v = bf ? ldT<1>(src, si) : ldT<0>(src, si);
        lw[e] = fToBits(v);
    }
    __syncthreads();
    for (int e = t; e < 9216; e += TPB) {     // 9216 = 9q * 4co * 256ci
        int ci = e & 255, coL = (e >> 8) & 3, q = e >> 10;
        dst[((long)q * 256 + co0 + coL) * 256 + ci] = lw[coL * 2304 + ci * 9 + q];
    }
}

// ===========================================================================
// x (NCHW flag dtype, 3ch) -> x4 bf16 [n][256][256][4] (ch 3 = 0 pad).
// ===========================================================================
template<int BF>
__device__ void x_to_cl4_body(const void* __restrict__ x, unsigned short* __restrict__ x4)
{
    long gid = (long)blockIdx.x * TPB + threadIdx.x;   // 0..131071
    int n = (int)(gid >> 16); int p = (int)(gid & 65535);
    long xb = (long)n * 3 * 65536 + p;
    unsigned c0 = fToBits(ldT<BF>(x, xb));
    unsigned c1 = fToBits(ldT<BF>(x, xb + 65536));
    unsigned c2 = fToBits(ldT<BF>(x, xb + 131072));
    uint2 v; v.x = c0 | (c1 << 16); v.y = c2;
    *(uint2*)&x4[gid * 4] = v;
}
__global__ __launch_bounds__(TPB) void x_to_cl4_kernel(
    const void* x, unsigned short* x4, const int* dflag)
{
    if (*dflag) x_to_cl4_body<1>(x, x4);
    else        x_to_cl4_body<0>(x, x4);
}

// ===========================================================================
// MFMA fused layer 1 v4 (validated round 8)
// ===========================================================================
template<int BF>
__device__ void layer1_mfma_body(
    const unsigned short* __restrict__ x4all, const unsigned short* __restrict__ wo,
    const unsigned short* __restrict__ wd, const float* __restrict__ bias1,
    const float* __restrict__ bias2, void* __restrict__ out, long obase,
    float* xs, unsigned short* A, float* offs)
{
    int b = blockIdx.x;
    int n = b >> 11;
    int ho = (b >> 3) & 255;
    int wo0 = (b & 7) << 5;
    const unsigned short* x4 = x4all + ((long)n << 16) * 4;
    int t = threadIdx.x;

    // ---- phase 1a: stage x patch [3ci][7ky][40 cols] from x4 (8B loads) --
    for (int e = t; e < 7 * 40; e += TPB) {
        int cc = e % 40, rr = e / 40;
        int yy = ho - 3 + rr; int xx = wo0 - 3 + cc;
        float c0 = 0.f, c1 = 0.f, c2 = 0.f;
        if (cc < 38 && yy >= 0 && yy < 256 && xx >= 0 && xx < 256) {
            uint2 v = *(const uint2*)&x4[((long)yy * 256 + xx) * 4];
            c0 = bitsToF((unsigned short)(v.x & 0xffff));
            c1 = bitsToF((unsigned short)(v.x >> 16));
            c2 = bitsToF((unsigned short)(v.y & 0xffff));
        }
        xs[(0 * 7 + rr) * 40 + cc] = c0;
        xs[(1 * 7 + rr) * 40 + cc] = c1;
        xs[(2 * 7 + rr) * 40 + cc] = c2;
    }
    __syncthreads();

    // ---- phase 1b: im2col -> A[kc][m][32] bf16, k = ci*49+ky*7+kx --------
    for (int e = t; e < 5120; e += TPB) {
        int kin = e & 31, m = (e >> 5) & 31, kc = e >> 10;
        int k = kc * 32 + kin;
        float v = 0.f;
        if (k < 147) {
            int ci = k / 49, q = k - ci * 49;
            int ky = q / 7, kx = q - ky * 7;
            v = xs[(ci * 7 + ky) * 40 + m + kx];
        }
        A[kc * 1024 + m * 32 + kin] = fToBits(v);
    }
    __syncthreads();

    int wv = t >> 6, lane = t & 63;
    int quad = lane >> 4, l16 = lane & 15;
    int mt = wv & 1, ntb = wv >> 1;

    // ---- phase 2: MFMA offset conv (N=160, 10 n-tiles over 2 wave-groups)-
    {
        f32x4 acc[5];
        #pragma unroll
        for (int j = 0; j < 5; ++j) acc[j] = (f32x4){0.f, 0.f, 0.f, 0.f};
        #pragma unroll
        for (int kc = 0; kc < 5; ++kc) {
            bf16x8 a = *(const bf16x8*)&A[(kc * 32 + mt * 16 + l16) * 32 + quad * 8];
            #pragma unroll
            for (int j = 0; j < 5; ++j) {
                int ch = (ntb + 2 * j) * 16 + l16;
                bf16x8 bw = *(const bf16x8*)&wo[ch * 160 + kc * 32 + quad * 8];
                acc[j] = __builtin_amdgcn_mfma_f32_16x16x32_bf16(a, bw, acc[j], 0, 0, 0);
            }
        }
        #pragma unroll
        for (int j = 0; j < 5; ++j) {
            int ch = (ntb + 2 * j) * 16 + l16;
            if (ch < 147) {
                float bv = bias1[ch];
                #pragma unroll
                for (int reg = 0; reg < 4; ++reg) {
                    int m = mt * 16 + quad * 4 + reg;
                    offs[ch * 33 + m] = acc[j][reg] + bv;
                }
            }
        }
    }
    __syncthreads();

    // ---- phase 3: p in lane (coalesced 8B taps); in-place sample write ----
    for (int e = t; e < 49 * 32; e += TPB) {
        int p = e & 31; int k = e >> 5;
        float oy = offs[k * 33 + p];
        float ox = offs[(49 + k) * 33 + p];
        float mr = offs[(98 + k) * 33 + p];
        float m = 1.f / (1.f + expf(-mr));
        float py = (float)(ho - 3 + k / 7) + oy;
        float px = (float)(wo0 + p - 3 + k % 7) + ox;
        float y0f = floorf(py), x0f = floorf(px);
        float wy = py - y0f, wx = px - x0f;
        int y0 = (int)y0f, x0 = (int)x0f;
        bool yv0 = (y0 >= 0) && (y0 < 256);
        bool yv1 = (y0 + 1 >= 0) && (y0 + 1 < 256);
        bool xv0 = (x0 >= 0) && (x0 < 256);
        bool xv1 = (x0 + 1 >= 0) && (x0 + 1 < 256);
        int y0c = min(max(y0, 0), 255), y1c = min(max(y0 + 1, 0), 255);
        int x0c = min(max(x0, 0), 255), x1c = min(max(x0 + 1, 0), 255);
        float w00 = (yv0 && xv0) ? (1.f - wy) * (1.f - wx) * m : 0.f;
        float w01 = (yv0 && xv1) ? (1.f - wy) * wx * m : 0.f;
        float w10 = (yv1 && xv0) ? wy * (1.f - wx) * m : 0.f;
        float w11 = (yv1 && xv1) ? wy * wx * m : 0.f;
        uint2 a00 = *(const uint2*)&x4[((long)y0c * 256 + x0c) * 4];
        uint2 a01 = *(const uint2*)&x4[((long)y0c * 256 + x1c) * 4];
        uint2 a10 = *(const uint2*)&x4[((long)y1c * 256 + x0c) * 4];
        uint2 a11 = *(const uint2*)&x4[((long)y1c * 256 + x1c) * 4];
        float s0 = w00 * bitsToF((unsigned short)(a00.x & 0xffff))
                 + w01 * bitsToF((unsigned short)(a01.x & 0xffff))
                 + w10 * bitsToF((unsigned short)(a10.x & 0xffff))
                 + w11 * bitsToF((unsigned short)(a11.x & 0xffff));
        float s1 = w00 * bitsToF((unsigned short)(a00.x >> 16))
                 + w01 * bitsToF((unsigned short)(a01.x >> 16))
                 + w10 * bitsToF((unsigned short)(a10.x >> 16))
                 + w11 * bitsToF((unsigned short)(a11.x >> 16));
        float s2 = w00 * bitsToF((unsigned short)(a00.y & 0xffff))
                 + w01 * bitsToF((unsigned short)(a01.y & 0xffff))
                 + w10 * bitsToF((unsigned short)(a10.y & 0xffff))
                 + w11 * bitsToF((unsigned short)(a11.y & 0xffff));
        offs[k * 33 + p] = s0;               // in-place, thread-local RAW
        offs[(49 + k) * 33 + p] = s1;
        offs[(98 + k) * 33 + p] = s2;
    }
    __syncthreads();

    // ---- phase 3.5: repack offs(f32) -> A(bf16 MFMA layout) --------------
    for (int e = t; e < 5120; e += TPB) {
        int kin = e & 31, m = (e >> 5) & 31, kc = e >> 10;
        int k = kc * 32 + kin;
        float v = 0.f;
        if (k < 147) v = offs[k * 33 + m];
        A[kc * 1024 + m * 32 + kin] = fToBits(v);
    }
    __syncthreads();

    // ---- phase 4: MFMA deform conv (N=64, 4 n-tiles) ---------------------
    f32x4 acc2[2];
    acc2[0] = (f32x4){0.f, 0.f, 0.f, 0.f};
    acc2[1] = (f32x4){0.f, 0.f, 0.f, 0.f};
    #pragma unroll
    for (int kc = 0; kc < 5; ++kc) {
        bf16x8 a = *(const bf16x8*)&A[(kc * 32 + mt * 16 + l16) * 32 + quad * 8];
        #pragma unroll
        for (int j = 0; j < 2; ++j) {
            int co = (ntb + 2 * j) * 16 + l16;
            bf16x8 bw = *(const bf16x8*)&wd[co * 160 + kc * 32 + quad * 8];
            acc2[j] = __builtin_amdgcn_mfma_f32_16x16x32_bf16(a, bw, acc2[j], 0, 0, 0);
        }
    }
    #pragma unroll
    for (int j = 0; j < 2; ++j) {
        int co = (ntb + 2 * j) * 16 + l16;
        float bv = bias2[co];
        #pragma unroll
        for (int reg = 0; reg < 4; ++reg) {
            int wox = wo0 + mt * 16 + quad * 4 + reg;
            long oi = obase + ((long)(n * 64 + co) * 256 + ho) * 256 + wox;
            stT<BF>(out, oi, acc2[j][reg] + bv);
        }
    }
}

__global__ __launch_bounds__(TPB) void layer1_mfma_kernel(
    const unsigned short* x4, const unsigned short* wo, const unsigned short* wd,
    const float* bias1, const float* bias2, void* out, long obase, const int* dflag)
{
    __shared__ __align__(16) float xs[3 * 7 * 40];
    __shared__ __align__(16) unsigned short A[5120];
    __shared__ __align__(16) float offs[147 * 33];
    if (*dflag) layer1_mfma_body<1>(x4, wo, wd, bias1, bias2, out, obase, xs, A, offs);
    else        layer1_mfma_body<0>(x4, wo, wd, bias1, bias2, out, obase, xs, A, offs);
}

// ===========================================================================
// MFMA offset conv (layers 2/3) v3: 16B uint4 staging (validated round 15)
// ===========================================================================
template<int CIN, int HH, int WW, int HO, int WO>
__global__ __launch_bounds__(TPB) void offconv_mfma_kernel(
    const unsigned short* __restrict__ xcl, const unsigned short* __restrict__ wb,
    const float* __restrict__ bias_f, float* __restrict__ out)
{
    constexpr int S   = 16 * CIN;
    constexpr int KL  = 512 / CIN;       // taps per 512-i chunk
    constexpr int NCH = 16 / KL;
    constexpr int CH8 = CIN / 8;         // 16B units per (pair, tap)
    constexpr int UN  = (KL * 16 * CH8) / TPB;   // 16B units per thread/chunk
    constexpr int TILES = (HO * WO) / 16;

    __shared__ int tp[256];
    __shared__ __align__(16) unsigned short smp[16 * 512];

    int tile = blockIdx.x % TILES;
    int n    = blockIdx.x / TILES;
    int lp0  = tile * 16;

    // ---- fixed-tap address table: one (k,p) per thread ----
    {
        int pr = threadIdx.x;
        int k = pr >> 4, p = pr & 15;
        int lp = lp0 + p;
        int ho = lp / WO, wo = lp - ho * WO;
        int yy = ho * 2 - 1 + (k >> 2);
        int xx = wo * 2 - 1 + (k & 3);
        bool valid = (yy >= 0) && (yy < HH) && (xx >= 0) && (xx < WW);
        tp[pr] = valid ? (yy * WW + xx) * CIN : -1;
    }

    int wv = threadIdx.x >> 6, lane = threadIdx.x & 63;
    int quad = lane >> 4, l16 = lane & 15;
    const unsigned short* xn = xcl + (long)n * HH * WW * CIN;

    f32x4 acc = (f32x4){0.f, 0.f, 0.f, 0.f};

    for (int ch = 0; ch < NCH; ++ch) {
        __syncthreads();
        #pragma unroll
        for (int u = 0; u < UN; ++u) {
            int e   = u * TPB + threadIdx.x;
            int prl = e / CH8;
            int ci  = (e - prl * CH8) * 8;
            int pi  = ch * (KL * 16) + prl;
            int kl = prl >> 4, p = prl & 15;
            int t0 = tp[pi];
            uint4 v = {0u, 0u, 0u, 0u};
            if (t0 >= 0) v = *(const uint4*)(xn + t0 + ci);
            int il = kl * CIN + ci;
            *(uint4*)&smp[((il >> 5) * 16 + p) * 32 + (il & 31)] = v;
        }
        __syncthreads();
        #pragma unroll 4
        for (int kk = 0; kk < 16; ++kk) {
            bf16x8 a = *(const bf16x8*)&smp[(kk * 16 + l16) * 32 + quad * 8];
            int co = wv * 16 + l16;
            bf16x8 b = *(const bf16x8*)&wb[(long)co * S + ch * 512 + kk * 32 + quad * 8];
            acc = __builtin_amdgcn_mfma_f32_16x16x32_bf16(a, b, acc, 0, 0, 0);
        }
    }

    int co = wv * 16 + l16;
    if (co < 48) {
        float bv = bias_f[co];
        #pragma unroll
        for (int reg = 0; reg < 4; ++reg) {
            int lp = lp0 + quad * 4 + reg;
            int ho = lp / WO, wo = lp - ho * WO;
            out[((long)(n * 48 + co) * HO + ho) * WO + wo] = acc[reg] + bv;
        }
    }
}

// ===========================================================================
// NCHW per-channel partial stats: grid = 2n x C x 8 chunks, 256 thr.
// Coalesced strided reads; reduce2 per block -> ps[(n*C+c)*8+chunk].
// ===========================================================================
template<int C, int HW>
__global__ __launch_bounds__(TPB) void nchw_stats_kernel(
    const void* __restrict__ buf, long base0, const int* __restrict__ dflag,
    float* __restrict__ ps1, float* __restrict__ ps2)
{
    __shared__ float s1[16], s2[16];
    constexpr int CH = HW / 8;            // elements per chunk
    int b = blockIdx.x;
    int chunk = b & 7;
    int nc = b >> 3;                      // n*C + c
    int bf = *dflag;
    long base = base0 + (long)nc * HW + (long)chunk * CH;
    float sum = 0.f, sq = 0.f;
    for (int i = threadIdx.x; i < CH; i += TPB) {
        float v = bf ? bitsToF(((const unsigned short*)buf)[base + i])
                     : ((const float*)buf)[base + i];
        sum += v; sq += v * v;
    }
    // wave + block reduce (reduce2 pattern)
    for (int off = 32; off; off >>= 1) {
        sum += __shfl_down(sum, off, 64);
        sq  += __shfl_down(sq,  off, 64);
    }
    int wid = threadIdx.x >> 6;
    if ((threadIdx.x & 63) == 0) { s1[wid] = sum; s2[wid] = sq; }
    __syncthreads();
    if (threadIdx.x == 0) {
        float S = 0.f, Q = 0.f;
        for (int w = 0; w < 4; ++w) { S += s1[w]; Q += s2[w]; }
        ps1[nc * 8 + chunk] = S;
        ps2[nc * 8 + chunk] = Q;
    }
}

// ===========================================================================
// Fused IN-apply + NCHW->CL transpose: reads raw NCHW once, writes
// normalized (relu) NCHW back in place AND channels-last bf16 tile.
// grid = 2*HW/64 blocks (same as old nchw_to_cl).
// ===========================================================================
template<int C, int HW>
__global__ __launch_bounds__(TPB) void nchw_to_cl_norm_kernel(
    void* __restrict__ buf, long ibase, unsigned short* __restrict__ out,
    const float* __restrict__ ps1, const float* __restrict__ ps2,
    const int* __restrict__ dflag)
{
    __shared__ unsigned short tile[C * 65];
    __shared__ float mv[C], iv[C];
    int bf = *dflag;
    int n   = (blockIdx.x * 64) / HW;
    int px0 = (blockIdx.x * 64) % HW;
    if (threadIdx.x < C) {
        int c = threadIdx.x;
        float s = 0.f, q = 0.f;
        #pragma unroll
        for (int j = 0; j < 8; ++j) {
            s += ps1[(n * C + c) * 8 + j];
            q += ps2[(n * C + c) * 8 + j];
        }
        float mean = s / (float)HW;
        mv[c] = mean;
        iv[c] = rsqrtf(q / (float)HW - mean * mean + 1e-5f);
    }
    __syncthreads();
    for (int e = threadIdx.x; e < C * 64; e += TPB) {
        int c = e >> 6, p = e & 63;
        long si = ibase + (long)(n * C + c) * HW + px0 + p;
        float v = bf ? ldT<1>(buf, si) : ldT<0>(buf, si);
        v = fmaxf((v - mv[c]) * iv[c], 0.f);
        if (bf) stT<1>(buf, si, v); else stT<0>(buf, si, v);
        tile[c * 65 + p] = fToBits(v);
    }
    __syncthreads();
    for (int e = threadIdx.x; e < C * 64; e += TPB) {
        int p = e / C, c = e - p * C;
        out[((long)n * HW + px0 + p) * C + c] = tile[c * 65 + p];
    }
}

// ===========================================================================
// MFMA deformable conv v4 (layers 2/3): 16B uint4 gather (validated R15)
// ===========================================================================
template<int MODE, int CIN, int COUT, int NWAVES, int HH, int WW, int HO, int WO>
__global__ __launch_bounds__(NWAVES * 64) void deform_mfma_kernel(
    const unsigned short* __restrict__ xcl, const float* __restrict__ off,
    const unsigned short* __restrict__ wb, const float* __restrict__ bias_f,
    void* __restrict__ outp, long obase, const int* __restrict__ dflag)
{
    constexpr int TPBk = NWAVES * 64;
    constexpr int S    = 16 * CIN;       // reduction length
    constexpr int KL   = 512 / CIN;      // kernel-points per 512-i chunk
    constexpr int NCH  = 16 / KL;        // chunks
    constexpr int CH8  = CIN / 8;        // 16B units per (pair, tap)
    constexpr int ITER = (KL * 16 * CH8) / TPBk;   // 16B units per thread/chunk
    constexpr int TILES = (HO * WO) / 16;

    __shared__ __align__(16) int tpw[256][8];      // [pair]{tp0..3, w0..3bits}
    __shared__ __align__(16) unsigned short smp[16 * 512];

    int tile = blockIdx.x % TILES;
    int n    = blockIdx.x / TILES;
    int lp0  = tile * 16;
    int tid  = threadIdx.x;

    // ---- phase A: per-(k,p) offset decode, one pair per thread (first 256)-
    if (tid < 256) {
        int pr = tid;
        int k = pr >> 4, p = pr & 15;
        int lp = lp0 + p;
        int ho = lp / WO, wo = lp - ho * WO;
        long plane = (long)HO * WO;
        const float* offn = off + (long)n * 48 * plane;
        float oy = offn[(long)k * plane + lp];
        float ox = offn[(long)(16 + k) * plane + lp];
        float mr = offn[(long)(32 + k) * plane + lp];
        float m = 1.f / (1.f + expf(-mr));
        float py = (float)(ho * 2 - 1 + (k >> 2)) + oy;
        float px = (float)(wo * 2 - 1 + (k & 3)) + ox;
        float y0f = floorf(py), x0f = floorf(px);
        float wy = py - y0f, wx = px - x0f;
        int y0 = (int)y0f, x0 = (int)x0f;
        bool yv0 = (y0 >= 0) && (y0 < HH);
        bool yv1 = (y0 + 1 >= 0) && (y0 + 1 < HH);
        bool xv0 = (x0 >= 0) && (x0 < WW);
        bool xv1 = (x0 + 1 >= 0) && (x0 + 1 < WW);
        int y0c = min(max(y0, 0), HH - 1), y1c = min(max(y0 + 1, 0), HH - 1);
        int x0c = min(max(x0, 0), WW - 1), x1c = min(max(x0 + 1, 0), WW - 1);
        tpw[pr][0] = (y0c * WW + x0c) * CIN;
        tpw[pr][1] = (y0c * WW + x1c) * CIN;
        tpw[pr][2] = (y1c * WW + x0c) * CIN;
        tpw[pr][3] = (y1c * WW + x1c) * CIN;
        tpw[pr][4] = __float_as_int((yv0 && xv0) ? (1.f - wy) * (1.f - wx) * m : 0.f);
        tpw[pr][5] = __float_as_int((yv0 && xv1) ? (1.f - wy) * wx * m : 0.f);
        tpw[pr][6] = __float_as_int((yv1 && xv0) ? wy * (1.f - wx) * m : 0.f);
        tpw[pr][7] = __float_as_int((yv1 && xv1) ? wy * wx * m : 0.f);
    }

    int wv = tid >> 6, lane = tid & 63;
    int quad = lane >> 4, l16 = lane & 15;
    int cb = (wv & 3) * 32 + (wv >> 2) * (COUT / 2);
    const unsigned short* xn = xcl + (long)n * HH * WW * CIN;

    f32x4 acc[2];
    acc[0] = (f32x4){0.f, 0.f, 0.f, 0.f};
    acc[1] = (f32x4){0.f, 0.f, 0.f, 0.f};

    for (int ch = 0; ch < NCH; ++ch) {
        __syncthreads();   // covers phase A (ch=0) and prev MFMA reads
        #pragma unroll
        for (int it = 0; it < ITER; ++it) {
            int e   = it * TPBk + tid;
            int prl = e / CH8;                  // pair within chunk
            int ci  = (e - prl * CH8) * 8;      // ci multiple of 8
            int pi  = ch * (KL * 16) + prl;
            const int4   tp4 = *(const int4*)&tpw[pi][0];
            const float4 tw4 = *(const float4*)&tpw[pi][4];
            uint4 u0 = *(const uint4*)(xn + tp4.x + ci);
            uint4 u1 = *(const uint4*)(xn + tp4.y + ci);
            uint4 u2 = *(const uint4*)(xn + tp4.z + ci);
            uint4 u3 = *(const uint4*)(xn + tp4.w + ci);
            float r[8];
            #pragma unroll
            for (int jj = 0; jj < 8; ++jj) {
                unsigned w0 = ((const unsigned*)&u0)[jj >> 1];
                unsigned w1 = ((const unsigned*)&u1)[jj >> 1];
                unsigned w2 = ((const unsigned*)&u2)[jj >> 1];
                unsigned w3 = ((const unsigned*)&u3)[jj >> 1];
                int sh = (jj & 1) << 4;
                r[jj] = tw4.x * bitsToF((unsigned short)(w0 >> sh))
                      + tw4.y * bitsToF((unsigned short)(w1 >> sh))
                      + tw4.z * bitsToF((unsigned short)(w2 >> sh))
                      + tw4.w * bitsToF((unsigned short)(w3 >> sh));
            }
            uint4 ov;
            ((unsigned*)&ov)[0] = (unsigned)fToBits(r[0]) | ((unsigned)fToBits(r[1]) << 16);
            ((unsigned*)&ov)[1] = (unsigned)fToBits(r[2]) | ((unsigned)fToBits(r[3]) << 16);
            ((unsigned*)&ov)[2] = (unsigned)fToBits(r[4]) | ((unsigned)fToBits(r[5]) << 16);
            ((unsigned*)&ov)[3] = (unsigned)fToBits(r[6]) | ((unsigned)fToBits(r[7]) << 16);
            int il = (prl >> 4) * CIN + ci;     // i within chunk [0,512)
            int p  = prl & 15;
            *(uint4*)&smp[((il >> 5) * 16 + p) * 32 + (il & 31)] = ov;
        }
        __syncthreads();
        #pragma unroll 4
        for (int kk = 0; kk < 16; ++kk) {
            bf16x8 a = *(const bf16x8*)&smp[(kk * 16 + l16) * 32 + quad * 8];
            #pragma unroll
            for (int f = 0; f < 2; ++f) {
                int co = cb + f * 16 + l16;
                bf16x8 b = *(const bf16x8*)&wb[(long)co * S + ch * 512 + kk * 32 + quad * 8];
                acc[f] = __builtin_amdgcn_mfma_f32_16x16x32_bf16(a, b, acc[f], 0, 0, 0);
            }
        }
    }

    // ---- epilogue: pixel = quad*4+reg, co = cb + f*16 + l16 ----
    if (MODE == 1) {
        unsigned short* oCL = (unsigned short*)outp;
        #pragma unroll
        for (int f = 0; f < 2; ++f) {
            int co = cb + f * 16 + l16;
            float bv = bias_f[co];
            #pragma unroll
            for (int reg = 0; reg < 4; ++reg) {
                int lp = lp0 + quad * 4 + reg;
                oCL[((long)n * HO * WO + lp) * COUT + co] = fToBits(acc[f][reg] + bv);
            }
        }
    } else {
        int bf = *dflag;
        #pragma unroll
        for (int f = 0; f < 2; ++f) {
            int co = cb + f * 16 + l16;
            float bv = bias_f[co];
            #pragma unroll
            for (int reg = 0; reg < 4; ++reg) {
                int lp = lp0 + quad * 4 + reg;
                int ho = lp / WO, wo = lp - ho * WO;
                long oi = obase + ((long)(n * COUT + co) * HO + ho) * WO + wo;
                if (bf) stT<1>(outp, oi, acc[f][reg] + bv);
                else    stT<0>(outp, oi, acc[f][reg] + bv);
            }
        }
    }
}

// ===========================================================================
// MFMA res-block 3x3 reflect conv v2 (validated round 4/8)
// ===========================================================================
__global__ __launch_bounds__(TPB) void resconv_mfma_kernel(
    const unsigned short* __restrict__ X, const unsigned short* __restrict__ W,
    const float* __restrict__ bias_f, bf16* __restrict__ Y)
{
    __shared__ __align__(16) unsigned short xs[3 * 66 * 64];   // 25344 B, swizzled
    int b = blockIdx.x;
    int coO = b & 7, r = (b >> 3) & 63, n = b >> 9;
    int t = threadIdx.x;
    int wv = t >> 6;
    int lane = t & 63;
    int quad = lane >> 4, l16 = lane & 15;
    int rows[3];
    rows[0] = (r == 0) ? 1 : r - 1;
    rows[1] = r;
    rows[2] = (r == 63) ? 62 : r + 1;

    f32x4 acc[2];
    acc[0] = (f32x4){0.f, 0.f, 0.f, 0.f};
    acc[1] = (f32x4){0.f, 0.f, 0.f, 0.f};

    long xbase = (long)n * 4096 * 256;

    for (int ci0 = 0; ci0 < 256; ci0 += 64) {
        __syncthreads();
        // stage [3ky][66col][64ci] via 16B loads; swizzled 16B slot per col
        for (int e = t; e < 3 * 66 * 8; e += TPB) {
            int oct = e & 7;
            int col = (e >> 3) % 66;
            int ky  = e / (66 * 8);
            int gx = col - 1;
            gx = (gx < 0) ? 1 : ((gx > 63) ? 62 : gx);
            bf16x8 v = *(const bf16x8*)&X[xbase + ((long)rows[ky] * 64 + gx) * 256 + ci0 + oct * 8];
            int slot = oct ^ (col & 7);
            *(bf16x8*)&xs[((ky * 66 + col) << 6) + slot * 8] = v;
        }
        __syncthreads();
        #pragma unroll
        for (int q = 0; q < 9; ++q) {
            int ky = q / 3, kx = q % 3;
            int col = wv * 16 + l16 + kx;        // lds col = global col +1
            int base = (ky * 66 + col) << 6;
            #pragma unroll
            for (int kh = 0; kh < 2; ++kh) {
                int slot = (kh * 4 + quad) ^ (col & 7);
                bf16x8 a = *(const bf16x8*)&xs[base + slot * 8];
                #pragma unroll
                for (int ct = 0; ct < 2; ++ct) {
                    int co = coO * 32 + ct * 16 + l16;
                    bf16x8 bw = *(const bf16x8*)&W[((long)q * 256 + co) * 256 + ci0 + kh * 32 + quad * 8];
                    acc[ct] = __builtin_amdgcn_mfma_f32_16x16x32_bf16(a, bw, acc[ct], 0, 0, 0);
                }
            }
        }
    }

    long ybase = ((long)n * 4096 + (long)r * 64) * 256;
    #pragma unroll
    for (int ct = 0; ct < 2; ++ct) {
        int co = coO * 32 + ct * 16 + l16;
        float bv = bias_f[co];
        #pragma unroll
        for (int reg = 0; reg < 4; ++reg) {
            int px = wv * 16 + quad * 4 + reg;
            Y[ybase + (long)px * 256 + co] = __float2bfloat16(acc[ct][reg] + bv);
        }
    }
}

// ===========================================================================
// Channels-last instance-norm: WIDE partial stats (validated round 10)
// ===========================================================================
__global__ __launch_bounds__(TPB) void cl_stats_kernel(
    const unsigned short* __restrict__ X, float* __restrict__ psum, float* __restrict__ psq)
{
    int blk = blockIdx.x;
    int chunk = blk & 63, n = blk >> 6;
    int co = threadIdx.x;
    float s = 0.f, sq = 0.f;
    const unsigned short* p = X + ((long)n * 4096 + chunk * 64) * 256 + co;
    #pragma unroll 8
    for (int i = 0; i < 64; ++i) {
        float v = bitsToF(p[(long)i * 256]);
        s += v; sq += v * v;
    }
    psum[(n * 64 + chunk) * 256 + co] = s;
    psq [(n * 64 + chunk) * 256 + co] = sq;
}

__device__ __forceinline__ void cl_load_stats(
    const float* psum, const float* psq, int n, float* mv, float* iv)
{
    int t = threadIdx.x;   // t = channel
    float s = 0.f, sq = 0.f;
    #pragma unroll 8
    for (int c = 0; c < 64; ++c) {
        s  += psum[(n * 64 + c) * 256 + t];
        sq += psq [(n * 64 + c) * 256 + t];
    }
    float mean = s / 4096.f;
    mv[t] = mean;
    iv[t] = rsqrtf(sq / 4096.f - mean * mean + 1e-5f);
    __syncthreads();
}

// grid 128 = n*64 + y; in-place X = relu?((X-m)*inv), uint-vectorized
__global__ __launch_bounds__(TPB) void cl_apply_kernel(
    unsigned short* __restrict__ X, const float* __restrict__ psum,
    const float* __restrict__ psq, int relu)
{
    __shared__ float mv[256], iv[256];
    int y = blockIdx.x & 63, n = blockIdx.x >> 6;
    cl_load_stats(psum, psq, n, mv, iv);
    unsigned* row = (unsigned*)(X + ((long)n * 4096 + y * 64) * 256);
    for (int e = threadIdx.x; e < 8192; e += TPB) {
        int co = (e * 2) & 255;
        unsigned u = row[e];
        float v0 = (bitsToF((unsigned short)(u & 0xffff)) - mv[co]) * iv[co];
        float v1 = (bitsToF((unsigned short)(u >> 16)) - mv[co + 1]) * iv[co + 1];
        if (relu) { v0 = fmaxf(v0, 0.f); v1 = fmaxf(v1, 0.f); }
        row[e] = (unsigned)fToBits(v0) | ((unsigned)fToBits(v1) << 16);
    }
}

// grid 128; H += IN(T), uint-vectorized
__global__ __launch_bounds__(TPB) void cl_apply_add_kernel(
    const unsigned short* __restrict__ T, unsigned short* __restrict__ H,
    const float* __restrict__ psum, const float* __restrict__ psq)
{
    __shared__ float mv[256], iv[256];
    int y = blockIdx.x & 63, n = blockIdx.x >> 6;
    cl_load_stats(psum, psq, n, mv, iv);
    long base = ((long)n * 4096 + y * 64) * 256;
    const unsigned* tr = (const unsigned*)(T + base);
    unsigned* hr = (unsigned*)(H + base);
    for (int e = threadIdx.x; e < 8192; e += TPB) {
        int co = (e * 2) & 255;
        unsigned ut = tr[e], uh = hr[e];
        float v0 = bitsToF((unsigned short)(uh & 0xffff))
                 + (bitsToF((unsigned short)(ut & 0xffff)) - mv[co]) * iv[co];
        float v1 = bitsToF((unsigned short)(uh >> 16))
                 + (bitsToF((unsigned short)(ut >> 16)) - mv[co + 1]) * iv[co + 1];
        hr[e] = (unsigned)fToBits(v0) | ((unsigned)fToBits(v1) << 16);
    }
}

// grid 128; out(NCHW, flag dtype) = H + IN(T)   (transposes channels-last)
__global__ __launch_bounds__(TPB) void cl_apply_final_kernel(
    const unsigned short* __restrict__ T, const unsigned short* __restrict__ H,
    void* __restrict__ outp, const float* __restrict__ psum,
    const float* __restrict__ psq, const int* __restrict__ dflag)
{
    __shared__ float mv[256], iv[256];
    int y = blockIdx.x & 63, n = blockIdx.x >> 6;
    cl_load_stats(psum, psq, n, mv, iv);
    int bf = *dflag;
    int x = threadIdx.x & 63, cg = threadIdx.x >> 6;
    for (int co = cg; co < 256; co += 4) {
        long cli = ((long)(n * 64 + y) * 64 + x) * 256 + co;
        float v = bitsToF(H[cli]) + (bitsToF(T[cli]) - mv[co]) * iv[co];
        long oi = (((long)(n * 256 + co)) * 64 + y) * 64 + x;
        if (bf) ((bf16*)outp)[oi] = __float2bfloat16(v);
        else    ((float*)outp)[oi] = v;
    }
}

// ---------------------------------------------------------------------------
extern "C" void kernel_launch(void* const* d_in, const int* in_sizes, int n_in,
                              void* d_out, int out_size, void* d_ws, size_t ws_size,
                              hipStream_t stream) {
    const void* x = d_in[0];

    const long SKIP1 = 2097152;
    const long SKIP2 = 10485760;

    int* dflag = (int*)d_ws;
    float* fw = (float*)((char*)d_ws + 64);

    unsigned short* t1 = (unsigned short*)(fw + FB);
    unsigned short* t2 = (unsigned short*)(fw + FB + 1048576);
    unsigned short* h3 = (unsigned short*)(fw + H3F);
    float* offb = fw + OFFB;
    unsigned short* x4 = (unsigned short*)(fw + OFFB);   // layer-1 only; dead after
    float* psum = fw + PST1;
    float* psq  = fw + PST2;
    unsigned short* clbuf = (unsigned short*)(fw + CLBUF);    // skip1_cl then skip2_cl
    const unsigned short* wb1o = (const unsigned short*)(fw + WB1OT);
    const unsigned short* wb1d = (const unsigned short*)(fw + WB1DT);
    const unsigned short* wb2o = (const unsigned short*)(fw + WO2T);
    const unsigned short* wb3o = (const unsigned short*)(fw + WO3T);
    const unsigned short* wb2 = (const unsigned short*)(fw + WB2T);
    const unsigned short* wb3 = (const unsigned short*)(fw + WB3T);
    const unsigned short* rbw1 = (const unsigned short*)(fw + RB1W1T);
    const unsigned short* rbw2 = (const unsigned short*)(fw + RB1W2T);
    const unsigned short* rbw3 = (const unsigned short*)(fw + RB2W1T);
    const unsigned short* rbw4 = (const unsigned short*)(fw + RB2W2T);

    detect_kernel<<<1, 64, 0, stream>>>(x, dflag);

    // ---- weight/bias repack ----
    PtrPack pp;
    for (int i = 0; i < 10; ++i) pp.p[i] = nullptr;
    pp.p[10] = d_in[2];  pp.p[11] = d_in[4];  pp.p[12] = d_in[6];  pp.p[13] = d_in[8];
    pp.p[14] = d_in[10]; pp.p[15] = d_in[12]; pp.p[16] = d_in[14]; pp.p[17] = d_in[16];
    pp.p[18] = d_in[18]; pp.p[19] = d_in[20];
    repack_all_kernel<<<2, TPB, 0, stream>>>(pp, fw, dflag);
    repack_dcn_kernel<<<867, TPB, 0, stream>>>(
        d_in[7], d_in[11], d_in[1], d_in[3], d_in[5], d_in[9], fw, dflag);
    RbPack rp;
    rp.src[0] = d_in[13]; rp.src[1] = d_in[15]; rp.src[2] = d_in[17]; rp.src[3] = d_in[19];
    repack_rb_kernel<<<256, TPB, 0, stream>>>(rp, fw, dflag);

    // ---- Layer 1 fused MFMA: offsets + deform, 7x7 s1 p3 ----
    x_to_cl4_kernel<<<512, TPB, 0, stream>>>(x, x4, dflag);
    layer1_mfma_kernel<<<4096, TPB, 0, stream>>>(
        x4, wb1o, wb1d, fw + OFF1B, fw + DCN1B, d_out, SKIP1, dflag);
    // skip1 IN: wide partial stats + fused apply/transpose (writes d_out + clbuf)
    nchw_stats_kernel<64, 65536><<<1024, TPB, 0, stream>>>(d_out, SKIP1, dflag, psum, psq);
    nchw_to_cl_norm_kernel<64, 65536><<<2048, TPB, 0, stream>>>(
        d_out, SKIP1, clbuf, psum, psq, dflag);

    // ---- Layer 2: 4x4 s2 p1, Cin=64 ----
    offconv_mfma_kernel<64, 256, 256, 128, 128><<<2048, TPB, 0, stream>>>(
        clbuf, wb2o, fw + OFF2B, offb);
    deform_mfma_kernel<0, 64, 128, 4, 256, 256, 128, 128><<<2048, TPB, 0, stream>>>(
        clbuf, offb, wb2, fw + DCN2B, d_out, SKIP2, dflag);
    // skip2 IN: wide partial stats + fused apply/transpose (reuses clbuf)
    nchw_stats_kernel<128, 16384><<<2048, TPB, 0, stream>>>(d_out, SKIP2, dflag, psum, psq);
    nchw_to_cl_norm_kernel<128, 16384><<<512, TPB, 0, stream>>>(
        d_out, SKIP2, clbuf, psum, psq, dflag);

    // ---- Layer 3: 4x4 s2 p1, Cin=128; output bf16 channels-last h3 ----
    offconv_mfma_kernel<128, 128, 128, 64, 64><<<512, TPB, 0, stream>>>(
        clbuf, wb3o, fw + OFF3B, offb);
    deform_mfma_kernel<1, 128, 256, 8, 128, 128, 64, 64><<<512, 512, 0, stream>>>(
        clbuf, offb, wb3, fw + DCN3B, h3, 0, dflag);
    cl_stats_kernel<<<128, TPB, 0, stream>>>(h3, psum, psq);
    cl_apply_kernel<<<128, TPB, 0, stream>>>(h3, psum, psq, 1);

    // ---- Res block 1 (MFMA) ----
    resconv_mfma_kernel<<<1024, TPB, 0, stream>>>(h3, rbw1, fw + RB1B1, (bf16*)t1);
    cl_stats_kernel<<<128, TPB, 0, stream>>>(t1, psum, psq);
    cl_apply_kernel<<<128, TPB, 0, stream>>>(t1, psum, psq, 1);
    resconv_mfma_kernel<<<1024, TPB, 0, stream>>>(t1, rbw2, fw + RB1B2, (bf16*)t2);
    cl_stats_kernel<<<128, TPB, 0, stream>>>(t2, psum, psq);
    cl_apply_add_kernel<<<128, TPB, 0, stream>>>(t2, h3, psum, psq);

    // ---- Res block 2 (MFMA; final writes NCHW d_out per flag) ----
    resconv_mfma_kernel<<<1024, TPB, 0, stream>>>(h3, rbw3, fw + RB2B1, (bf16*)t1);
    cl_stats_kernel<<<128, TPB, 0, stream>>>(t1, psum, psq);
    cl_apply_kernel<<<128, TPB, 0, stream>>>(t1, psum, psq, 1);
    resconv_mfma_kernel<<<1024, TPB, 0, stream>>>(t1, rbw4, fw + RB2B2, (bf16*)t2);
    cl_stats_kernel<<<128, TPB, 0, stream>>>(t2, psum, psq);
    cl_apply_final_kernel<<<128, TPB, 0, stream>>>(t2, h3, d_out, psum, psq, dflag);
}

// Round 17
// 816.689 us; speedup vs baseline: 1.1407x; 1.0013x over previous
//
#include <hip/hip_runtime.h>
#include <hip/hip_bf16.h>
#include <math.h>

#define TPB 256
typedef __hip_bfloat16 bf16;
typedef short bf16x8 __attribute__((ext_vector_type(8)));   // 8 bf16 (4 VGPRs)
typedef float f32x4 __attribute__((ext_vector_type(4)));

// ---------------- ws layout constants (fp32-element offsets from fw) -------
constexpr long BIASF  = 0;          // 1715 packed fp32 biases (pad to 2048)
constexpr long RB1W1T = 2048;       // res weights bf16 [9][256co][256ci]
constexpr long RB1W2T = 591872;
constexpr long RB2W1T = 1181696;
constexpr long RB2W2T = 1771520;
constexpr long FB     = 2361344;    // multi-use region
constexpr long WB1OT  = 2361344;    // bf16 [160][160] off1 weights (16B aligned)
constexpr long WB1DT  = 2382956;    // bf16 [64][160] dcn1 weights (16B aligned)
constexpr long WO2T   = 2392364;    // bf16 [64co pad][1024] off2 weights
constexpr long WB2T   = 2441516;    // bf16 [128co][1024] deform2 weights (16B aligned)
constexpr long WO3T   = 2572588;    // bf16 [64co pad][2048] off3 weights
constexpr long WB3T   = 2670892;    // bf16 [256co][2048] deform3 weights (16B aligned)
constexpr long OFFB   = 3221504;    // offsets layers 2/3; x4 during layer 1
constexpr long H3F    = 4458496;    // h3 bf16 channels-last, 1048576 floats
constexpr long CLBUF  = 5523456;    // channels-last bf16 skip1/skip2
constexpr long PST1   = 7620608;    // IN partial sums  (cl: [2][64][256]; nchw: [2][C][8])
constexpr long PST2   = 7653376;    // IN partial sumsq
// bias sub-offsets
constexpr long OFF1B = 0,   DCN1B = 147;
constexpr long OFF2B = 211, DCN2B = 259;
constexpr long OFF3B = 387, DCN3B = 435;
constexpr long RB1B1 = 691, RB1B2 = 947;
constexpr long RB2B1 = 1203, RB2B2 = 1459;

// ---- compile-time dtype accessors (BF=1: bf16, BF=0: fp32) ----------------
template<int BF>
__device__ __forceinline__ float ldT(const void* p, long i) {
    if (BF) {
        unsigned short h = ((const unsigned short*)p)[i];
        return __uint_as_float(((unsigned int)h) << 16);
    }
    return ((const float*)p)[i];
}
template<int BF>
__device__ __forceinline__ void stT(void* p, long i, float v) {
    if (BF) ((bf16*)p)[i] = __float2bfloat16(v);
    else    ((float*)p)[i] = v;
}
__device__ __forceinline__ float bitsToF(unsigned short h) {
    return __uint_as_float(((unsigned int)h) << 16);
}
__device__ __forceinline__ unsigned short fToBits(float v) {
    bf16 h = __float2bfloat16(v);
    return *(unsigned short*)&h;
}

// ---- dtype detector (validated rounds 3-9) --------------------------------
__global__ void detect_kernel(const void* __restrict__ x, int* __restrict__ flag) {
    if (threadIdx.x == 0 && blockIdx.x == 0) {
        const unsigned short* u = (const unsigned short*)x;
        int sane = 0;
        for (int i = 0; i < 256; ++i) {
            float v = bitsToF(u[i]);
            float a = fabsf(v);
            if (a > 0.0009f && a < 1100.f) ++sane;
        }
        *flag = (sane >= 224) ? 1 : 0;
    }
}

// ===========================================================================
// Repack: biases -> packed fp32 (grid 2).
// ===========================================================================
struct PtrPack { const void* p[20]; };   // p[10..19]=biases

template<int BF>
__device__ void repack_all_body(PtrPack pp, float* __restrict__ fw)
{
    constexpr int  bcum  [11] = {0,147,211,259,387,435,691,947,1203,1459,1715};
    int j0 = blockIdx.x * 1024 + threadIdx.x * 4;
    #pragma unroll
    for (int q = 0; q < 4; ++q) {
        int j = j0 + q;
        if (j < 1715) {
            int v = 0;
            #pragma unroll
            for (int s = 1; s < 10; ++s) if (j >= bcum[s]) v = s;
            fw[BIASF + j] = ldT<BF>(pp.p[10 + v], j - bcum[v]);
        }
    }
}
__global__ __launch_bounds__(TPB) void repack_all_kernel(
    PtrPack pp, float* fw, const int* dflag) {
    if (*dflag) repack_all_body<1>(pp, fw);
    else        repack_all_body<0>(pp, fw);
}

// ---- conv weights -> bf16 [co][k*CIN+ci] (dst-contiguous writes) ----------
__global__ __launch_bounds__(TPB) void repack_dcn_kernel(
    const void* __restrict__ w2, const void* __restrict__ w3,
    const void* __restrict__ w1o, const void* __restrict__ w1d,
    const void* __restrict__ w2o, const void* __restrict__ w3o,
    float* __restrict__ fw, const int* __restrict__ dflag)
{
    int bf = *dflag;
    unsigned short* wb2 = (unsigned short*)(fw + WB2T);
    unsigned short* wb3 = (unsigned short*)(fw + WB3T);
    unsigned short* wb1o = (unsigned short*)(fw + WB1OT);
    unsigned short* wb1d = (unsigned short*)(fw + WB1DT);
    unsigned short* wb2o = (unsigned short*)(fw + WO2T);
    unsigned short* wb3o = (unsigned short*)(fw + WO3T);
    int b = blockIdx.x;
    if (b < 128) {                              // dcn2: 131072 = 128 blocks
        int e0 = b * 1024 + threadIdx.x * 4;
        #pragma unroll
        for (int j = 0; j < 4; ++j) {
            int e = e0 + j;
            int co = e >> 10, rem = e & 1023, k = rem >> 6, ci = rem & 63;
            long si = ((long)(co * 64 + ci)) * 16 + k;
            float v = bf ? ldT<1>(w2, si) : ldT<0>(w2, si);
            wb2[e] = fToBits(v);
        }
    } else if (b < 640) {                       // dcn3: 524288 = 512 blocks
        int e0 = (b - 128) * 1024 + threadIdx.x * 4;
        #pragma unroll
        for (int j = 0; j < 4; ++j) {
            int e = e0 + j;
            int co = e >> 11, rem = e & 2047, k = rem >> 7, ci = rem & 127;
            long si = ((long)(co * 128 + ci)) * 16 + k;
            float v = bf ? ldT<1>(w3, si) : ldT<0>(w3, si);
            wb3[e] = fToBits(v);
        }
    } else if (b < 665) {                       // off1: 160x160 = 25 blocks
        int e0 = (b - 640) * 1024 + threadIdx.x * 4;
        #pragma unroll
        for (int j = 0; j < 4; ++j) {
            int e = e0 + j;
            int co = e / 160, k = e - co * 160;
            float v = 0.f;
            if (co < 147 && k < 147) {
                long si = (long)co * 147 + k;
                v = bf ? ldT<1>(w1o, si) : ldT<0>(w1o, si);
            }
            wb1o[e] = fToBits(v);
        }
    } else if (b < 675) {                       // dcn1: 64x160 = 10 blocks
        int e0 = (b - 665) * 1024 + threadIdx.x * 4;
        #pragma unroll
        for (int j = 0; j < 4; ++j) {
            int e = e0 + j;
            int co = e / 160, k = e - co * 160;
            float v = 0.f;
            if (k < 147) {
                long si = (long)co * 147 + k;
                v = bf ? ldT<1>(w1d, si) : ldT<0>(w1d, si);
            }
            wb1d[e] = fToBits(v);
        }
    } else if (b < 739) {                       // off2 pad64: 65536 = 64 blocks
        int e0 = (b - 675) * 1024 + threadIdx.x * 4;
        #pragma unroll
        for (int j = 0; j < 4; ++j) {
            int e = e0 + j;
            int co = e >> 10, rem = e & 1023, k = rem >> 6, ci = rem & 63;
            float v = 0.f;
            if (co < 48) {
                long si = ((long)(co * 64 + ci)) * 16 + k;
                v = bf ? ldT<1>(w2o, si) : ldT<0>(w2o, si);
            }
            wb2o[e] = fToBits(v);
        }
    } else {                                    // off3 pad64: 131072 = 128 blocks
        int e0 = (b - 739) * 1024 + threadIdx.x * 4;
        #pragma unroll
        for (int j = 0; j < 4; ++j) {
            int e = e0 + j;
            int co = e >> 11, rem = e & 2047, k = rem >> 7, ci = rem & 127;
            float v = 0.f;
            if (co < 48) {
                long si = ((long)(co * 128 + ci)) * 16 + k;
                v = bf ? ldT<1>(w3o, si) : ldT<0>(w3o, si);
            }
            wb3o[e] = fToBits(v);
        }
    }
}

// ---- res weights: src[co][ci*9+q] (flag dtype) -> bf16 [q][co][ci] --------
struct RbPack { const void* src[4]; };
__global__ __launch_bounds__(TPB) void repack_rb_kernel(
    RbPack rp, float* fw, const int* dflag)
{
    __shared__ unsigned short lw[4 * 2304];
    int b = blockIdx.x;
    int ten = b >> 6;
    int co0 = (b & 63) * 4;
    const void* src = rp.src[ten];
    const long dstOff[4] = {RB1W1T, RB1W2T, RB2W1T, RB2W2T};
    unsigned short* dst = (unsigned short*)(fw + dstOff[ten]);
    int bf = *dflag;
    int t = threadIdx.x;
    for (int e = t; e < 4 * 2304; e += TPB) {
        int coL = e / 2304, i = e - coL * 2304;
        long si = (long)(co0 + coL) * 2304 + i;
        float v = bf ? ldT<1>(src, si) : ldT<0>(src, si);
        lw[e] = fToBits(v);
    }
    __syncthreads();
    for (int e = t; e < 9216; e += TPB) {     // 9216 = 9q * 4co * 256ci
        int ci = e & 255, coL = (e >> 8) & 3, q = e >> 10;
        dst[((long)q * 256 + co0 + coL) * 256 + ci] = lw[coL * 2304 + ci * 9 + q];
    }
}

// ===========================================================================
// x (NCHW flag dtype, 3ch) -> x4 bf16 [n][256][256][4] (ch 3 = 0 pad).
// ===========================================================================
template<int BF>
__device__ void x_to_cl4_body(const void* __restrict__ x, unsigned short* __restrict__ x4)
{
    long gid = (long)blockIdx.x * TPB + threadIdx.x;   // 0..131071
    int n = (int)(gid >> 16); int p = (int)(gid & 65535);
    long xb = (long)n * 3 * 65536 + p;
    unsigned c0 = fToBits(ldT<BF>(x, xb));
    unsigned c1 = fToBits(ldT<BF>(x, xb + 65536));
    unsigned c2 = fToBits(ldT<BF>(x, xb + 131072));
    uint2 v; v.x = c0 | (c1 << 16); v.y = c2;
    *(uint2*)&x4[gid * 4] = v;
}
__global__ __launch_bounds__(TPB) void x_to_cl4_kernel(
    const void* x, unsigned short* x4, const int* dflag)
{
    if (*dflag) x_to_cl4_body<1>(x, x4);
    else        x_to_cl4_body<0>(x, x4);
}

// ===========================================================================
// MFMA fused layer 1 v4 (validated round 8)
// ===========================================================================
template<int BF>
__device__ void layer1_mfma_body(
    const unsigned short* __restrict__ x4all, const unsigned short* __restrict__ wo,
    const unsigned short* __restrict__ wd, const float* __restrict__ bias1,
    const float* __restrict__ bias2, void* __restrict__ out, long obase,
    float* xs, unsigned short* A, float* offs)
{
    int b = blockIdx.x;
    int n = b >> 11;
    int ho = (b >> 3) & 255;
    int wo0 = (b & 7) << 5;
    const unsigned short* x4 = x4all + ((long)n << 16) * 4;
    int t = threadIdx.x;

    // ---- phase 1a: stage x patch [3ci][7ky][40 cols] from x4 (8B loads) --
    for (int e = t; e < 7 * 40; e += TPB) {
        int cc = e % 40, rr = e / 40;
        int yy = ho - 3 + rr; int xx = wo0 - 3 + cc;
        float c0 = 0.f, c1 = 0.f, c2 = 0.f;
        if (cc < 38 && yy >= 0 && yy < 256 && xx >= 0 && xx < 256) {
            uint2 v = *(const uint2*)&x4[((long)yy * 256 + xx) * 4];
            c0 = bitsToF((unsigned short)(v.x & 0xffff));
            c1 = bitsToF((unsigned short)(v.x >> 16));
            c2 = bitsToF((unsigned short)(v.y & 0xffff));
        }
        xs[(0 * 7 + rr) * 40 + cc] = c0;
        xs[(1 * 7 + rr) * 40 + cc] = c1;
        xs[(2 * 7 + rr) * 40 + cc] = c2;
    }
    __syncthreads();

    // ---- phase 1b: im2col -> A[kc][m][32] bf16, k = ci*49+ky*7+kx --------
    for (int e = t; e < 5120; e += TPB) {
        int kin = e & 31, m = (e >> 5) & 31, kc = e >> 10;
        int k = kc * 32 + kin;
        float v = 0.f;
        if (k < 147) {
            int ci = k / 49, q = k - ci * 49;
            int ky = q / 7, kx = q - ky * 7;
            v = xs[(ci * 7 + ky) * 40 + m + kx];
        }
        A[kc * 1024 + m * 32 + kin] = fToBits(v);
    }
    __syncthreads();

    int wv = t >> 6, lane = t & 63;
    int quad = lane >> 4, l16 = lane & 15;
    int mt = wv & 1, ntb = wv >> 1;

    // ---- phase 2: MFMA offset conv (N=160, 10 n-tiles over 2 wave-groups)-
    {
        f32x4 acc[5];
        #pragma unroll
        for (int j = 0; j < 5; ++j) acc[j] = (f32x4){0.f, 0.f, 0.f, 0.f};
        #pragma unroll
        for (int kc = 0; kc < 5; ++kc) {
            bf16x8 a = *(const bf16x8*)&A[(kc * 32 + mt * 16 + l16) * 32 + quad * 8];
            #pragma unroll
            for (int j = 0; j < 5; ++j) {
                int ch = (ntb + 2 * j) * 16 + l16;
                bf16x8 bw = *(const bf16x8*)&wo[ch * 160 + kc * 32 + quad * 8];
                acc[j] = __builtin_amdgcn_mfma_f32_16x16x32_bf16(a, bw, acc[j], 0, 0, 0);
            }
        }
        #pragma unroll
        for (int j = 0; j < 5; ++j) {
            int ch = (ntb + 2 * j) * 16 + l16;
            if (ch < 147) {
                float bv = bias1[ch];
                #pragma unroll
                for (int reg = 0; reg < 4; ++reg) {
                    int m = mt * 16 + quad * 4 + reg;
                    offs[ch * 33 + m] = acc[j][reg] + bv;
                }
            }
        }
    }
    __syncthreads();

    // ---- phase 3: p in lane (coalesced 8B taps); in-place sample write ----
    for (int e = t; e < 49 * 32; e += TPB) {
        int p = e & 31; int k = e >> 5;
        float oy = offs[k * 33 + p];
        float ox = offs[(49 + k) * 33 + p];
        float mr = offs[(98 + k) * 33 + p];
        float m = 1.f / (1.f + expf(-mr));
        float py = (float)(ho - 3 + k / 7) + oy;
        float px = (float)(wo0 + p - 3 + k % 7) + ox;
        float y0f = floorf(py), x0f = floorf(px);
        float wy = py - y0f, wx = px - x0f;
        int y0 = (int)y0f, x0 = (int)x0f;
        bool yv0 = (y0 >= 0) && (y0 < 256);
        bool yv1 = (y0 + 1 >= 0) && (y0 + 1 < 256);
        bool xv0 = (x0 >= 0) && (x0 < 256);
        bool xv1 = (x0 + 1 >= 0) && (x0 + 1 < 256);
        int y0c = min(max(y0, 0), 255), y1c = min(max(y0 + 1, 0), 255);
        int x0c = min(max(x0, 0), 255), x1c = min(max(x0 + 1, 0), 255);
        float w00 = (yv0 && xv0) ? (1.f - wy) * (1.f - wx) * m : 0.f;
        float w01 = (yv0 && xv1) ? (1.f - wy) * wx * m : 0.f;
        float w10 = (yv1 && xv0) ? wy * (1.f - wx) * m : 0.f;
        float w11 = (yv1 && xv1) ? wy * wx * m : 0.f;
        uint2 a00 = *(const uint2*)&x4[((long)y0c * 256 + x0c) * 4];
        uint2 a01 = *(const uint2*)&x4[((long)y0c * 256 + x1c) * 4];
        uint2 a10 = *(const uint2*)&x4[((long)y1c * 256 + x0c) * 4];
        uint2 a11 = *(const uint2*)&x4[((long)y1c * 256 + x1c) * 4];
        float s0 = w00 * bitsToF((unsigned short)(a00.x & 0xffff))
                 + w01 * bitsToF((unsigned short)(a01.x & 0xffff))
                 + w10 * bitsToF((unsigned short)(a10.x & 0xffff))
                 + w11 * bitsToF((unsigned short)(a11.x & 0xffff));
        float s1 = w00 * bitsToF((unsigned short)(a00.x >> 16))
                 + w01 * bitsToF((unsigned short)(a01.x >> 16))
                 + w10 * bitsToF((unsigned short)(a10.x >> 16))
                 + w11 * bitsToF((unsigned short)(a11.x >> 16));
        float s2 = w00 * bitsToF((unsigned short)(a00.y & 0xffff))
                 + w01 * bitsToF((unsigned short)(a01.y & 0xffff))
                 + w10 * bitsToF((unsigned short)(a10.y & 0xffff))
                 + w11 * bitsToF((unsigned short)(a11.y & 0xffff));
        offs[k * 33 + p] = s0;               // in-place, thread-local RAW
        offs[(49 + k) * 33 + p] = s1;
        offs[(98 + k) * 33 + p] = s2;
    }
    __syncthreads();

    // ---- phase 3.5: repack offs(f32) -> A(bf16 MFMA layout) --------------
    for (int e = t; e < 5120; e += TPB) {
        int kin = e & 31, m = (e >> 5) & 31, kc = e >> 10;
        int k = kc * 32 + kin;
        float v = 0.f;
        if (k < 147) v = offs[k * 33 + m];
        A[kc * 1024 + m * 32 + kin] = fToBits(v);
    }
    __syncthreads();

    // ---- phase 4: MFMA deform conv (N=64, 4 n-tiles) ---------------------
    f32x4 acc2[2];
    acc2[0] = (f32x4){0.f, 0.f, 0.f, 0.f};
    acc2[1] = (f32x4){0.f, 0.f, 0.f, 0.f};
    #pragma unroll
    for (int kc = 0; kc < 5; ++kc) {
        bf16x8 a = *(const bf16x8*)&A[(kc * 32 + mt * 16 + l16) * 32 + quad * 8];
        #pragma unroll
        for (int j = 0; j < 2; ++j) {
            int co = (ntb + 2 * j) * 16 + l16;
            bf16x8 bw = *(const bf16x8*)&wd[co * 160 + kc * 32 + quad * 8];
            acc2[j] = __builtin_amdgcn_mfma_f32_16x16x32_bf16(a, bw, acc2[j], 0, 0, 0);
        }
    }
    #pragma unroll
    for (int j = 0; j < 2; ++j) {
        int co = (ntb + 2 * j) * 16 + l16;
        float bv = bias2[co];
        #pragma unroll
        for (int reg = 0; reg < 4; ++reg) {
            int wox = wo0 + mt * 16 + quad * 4 + reg;
            long oi = obase + ((long)(n * 64 + co) * 256 + ho) * 256 + wox;
            stT<BF>(out, oi, acc2[j][reg] + bv);
        }
    }
}

__global__ __launch_bounds__(TPB) void layer1_mfma_kernel(
    const unsigned short* x4, const unsigned short* wo, const unsigned short* wd,
    const float* bias1, const float* bias2, void* out, long obase, const int* dflag)
{
    __shared__ __align__(16) float xs[3 * 7 * 40];
    __shared__ __align__(16) unsigned short A[5120];
    __shared__ __align__(16) float offs[147 * 33];
    if (*dflag) layer1_mfma_body<1>(x4, wo, wd, bias1, bias2, out, obase, xs, A, offs);
    else        layer1_mfma_body<0>(x4, wo, wd, bias1, bias2, out, obase, xs, A, offs);
}

// ===========================================================================
// MFMA offset conv (layers 2/3) v3: 16B uint4 staging (validated round 15)
// ===========================================================================
template<int CIN, int HH, int WW, int HO, int WO>
__global__ __launch_bounds__(TPB) void offconv_mfma_kernel(
    const unsigned short* __restrict__ xcl, const unsigned short* __restrict__ wb,
    const float* __restrict__ bias_f, float* __restrict__ out)
{
    constexpr int S   = 16 * CIN;
    constexpr int KL  = 512 / CIN;       // taps per 512-i chunk
    constexpr int NCH = 16 / KL;
    constexpr int CH8 = CIN / 8;         // 16B units per (pair, tap)
    constexpr int UN  = (KL * 16 * CH8) / TPB;   // 16B units per thread/chunk
    constexpr int TILES = (HO * WO) / 16;

    __shared__ int tp[256];
    __shared__ __align__(16) unsigned short smp[16 * 512];

    int tile = blockIdx.x % TILES;
    int n    = blockIdx.x / TILES;
    int lp0  = tile * 16;

    // ---- fixed-tap address table: one (k,p) per thread ----
    {
        int pr = threadIdx.x;
        int k = pr >> 4, p = pr & 15;
        int lp = lp0 + p;
        int ho = lp / WO, wo = lp - ho * WO;
        int yy = ho * 2 - 1 + (k >> 2);
        int xx = wo * 2 - 1 + (k & 3);
        bool valid = (yy >= 0) && (yy < HH) && (xx >= 0) && (xx < WW);
        tp[pr] = valid ? (yy * WW + xx) * CIN : -1;
    }

    int wv = threadIdx.x >> 6, lane = threadIdx.x & 63;
    int quad = lane >> 4, l16 = lane & 15;
    const unsigned short* xn = xcl + (long)n * HH * WW * CIN;

    f32x4 acc = (f32x4){0.f, 0.f, 0.f, 0.f};

    for (int ch = 0; ch < NCH; ++ch) {
        __syncthreads();
        #pragma unroll
        for (int u = 0; u < UN; ++u) {
            int e   = u * TPB + threadIdx.x;
            int prl = e / CH8;
            int ci  = (e - prl * CH8) * 8;
            int pi  = ch * (KL * 16) + prl;
            int kl = prl >> 4, p = prl & 15;
            int t0 = tp[pi];
            uint4 v = {0u, 0u, 0u, 0u};
            if (t0 >= 0) v = *(const uint4*)(xn + t0 + ci);
            int il = kl * CIN + ci;
            *(uint4*)&smp[((il >> 5) * 16 + p) * 32 + (il & 31)] = v;
        }
        __syncthreads();
        #pragma unroll 4
        for (int kk = 0; kk < 16; ++kk) {
            bf16x8 a = *(const bf16x8*)&smp[(kk * 16 + l16) * 32 + quad * 8];
            int co = wv * 16 + l16;
            bf16x8 b = *(const bf16x8*)&wb[(long)co * S + ch * 512 + kk * 32 + quad * 8];
            acc = __builtin_amdgcn_mfma_f32_16x16x32_bf16(a, b, acc, 0, 0, 0);
        }
    }

    int co = wv * 16 + l16;
    if (co < 48) {
        float bv = bias_f[co];
        #pragma unroll
        for (int reg = 0; reg < 4; ++reg) {
            int lp = lp0 + quad * 4 + reg;
            int ho = lp / WO, wo = lp - ho * WO;
            out[((long)(n * 48 + co) * HO + ho) * WO + wo] = acc[reg] + bv;
        }
    }
}

// ===========================================================================
// NCHW per-channel partial stats (validated round 16)
// ===========================================================================
template<int C, int HW>
__global__ __launch_bounds__(TPB) void nchw_stats_kernel(
    const void* __restrict__ buf, long base0, const int* __restrict__ dflag,
    float* __restrict__ ps1, float* __restrict__ ps2)
{
    __shared__ float s1[16], s2[16];
    constexpr int CH = HW / 8;            // elements per chunk
    int b = blockIdx.x;
    int chunk = b & 7;
    int nc = b >> 3;                      // n*C + c
    int bf = *dflag;
    long base = base0 + (long)nc * HW + (long)chunk * CH;
    float sum = 0.f, sq = 0.f;
    for (int i = threadIdx.x; i < CH; i += TPB) {
        float v = bf ? bitsToF(((const unsigned short*)buf)[base + i])
                     : ((const float*)buf)[base + i];
        sum += v; sq += v * v;
    }
    for (int off = 32; off; off >>= 1) {
        sum += __shfl_down(sum, off, 64);
        sq  += __shfl_down(sq,  off, 64);
    }
    int wid = threadIdx.x >> 6;
    if ((threadIdx.x & 63) == 0) { s1[wid] = sum; s2[wid] = sq; }
    __syncthreads();
    if (threadIdx.x == 0) {
        float S = 0.f, Q = 0.f;
        for (int w = 0; w < 4; ++w) { S += s1[w]; Q += s2[w]; }
        ps1[nc * 8 + chunk] = S;
        ps2[nc * 8 + chunk] = Q;
    }
}

// ===========================================================================
// Fused IN-apply + NCHW->CL transpose (validated round 16)
// ===========================================================================
template<int C, int HW>
__global__ __launch_bounds__(TPB) void nchw_to_cl_norm_kernel(
    void* __restrict__ buf, long ibase, unsigned short* __restrict__ out,
    const float* __restrict__ ps1, const float* __restrict__ ps2,
    const int* __restrict__ dflag)
{
    __shared__ unsigned short tile[C * 65];
    __shared__ float mv[C], iv[C];
    int bf = *dflag;
    int n   = (blockIdx.x * 64) / HW;
    int px0 = (blockIdx.x * 64) % HW;
    if (threadIdx.x < C) {
        int c = threadIdx.x;
        float s = 0.f, q = 0.f;
        #pragma unroll
        for (int j = 0; j < 8; ++j) {
            s += ps1[(n * C + c) * 8 + j];
            q += ps2[(n * C + c) * 8 + j];
        }
        float mean = s / (float)HW;
        mv[c] = mean;
        iv[c] = rsqrtf(q / (float)HW - mean * mean + 1e-5f);
    }
    __syncthreads();
    for (int e = threadIdx.x; e < C * 64; e += TPB) {
        int c = e >> 6, p = e & 63;
        long si = ibase + (long)(n * C + c) * HW + px0 + p;
        float v = bf ? ldT<1>(buf, si) : ldT<0>(buf, si);
        v = fmaxf((v - mv[c]) * iv[c], 0.f);
        if (bf) stT<1>(buf, si, v); else stT<0>(buf, si, v);
        tile[c * 65 + p] = fToBits(v);
    }
    __syncthreads();
    for (int e = threadIdx.x; e < C * 64; e += TPB) {
        int p = e / C, c = e - p * C;
        out[((long)n * HW + px0 + p) * C + c] = tile[c * 65 + p];
    }
}

// ===========================================================================
// MFMA deformable conv v5 (layers 2/3): 16B uint4 gather; NF = couts per
// wave / 16 (NF=1: co = wv*16, single acc — mirrors offconv; NF=2: the
// validated deform3 split). deform2 now runs 8 waves (ITER halved to 2).
// ===========================================================================
template<int MODE, int CIN, int COUT, int NWAVES, int HH, int WW, int HO, int WO>
__global__ __launch_bounds__(NWAVES * 64) void deform_mfma_kernel(
    const unsigned short* __restrict__ xcl, const float* __restrict__ off,
    const unsigned short* __restrict__ wb, const float* __restrict__ bias_f,
    void* __restrict__ outp, long obase, const int* __restrict__ dflag)
{
    constexpr int TPBk = NWAVES * 64;
    constexpr int NF   = COUT / (NWAVES * 16);   // co-tiles per wave (1 or 2)
    constexpr int S    = 16 * CIN;       // reduction length
    constexpr int KL   = 512 / CIN;      // kernel-points per 512-i chunk
    constexpr int NCH  = 16 / KL;        // chunks
    constexpr int CH8  = CIN / 8;        // 16B units per (pair, tap)
    constexpr int ITER = (KL * 16 * CH8) / TPBk;   // 16B units per thread/chunk
    constexpr int TILES = (HO * WO) / 16;

    __shared__ __align__(16) int tpw[256][8];      // [pair]{tp0..3, w0..3bits}
    __shared__ __align__(16) unsigned short smp[16 * 512];

    int tile = blockIdx.x % TILES;
    int n    = blockIdx.x / TILES;
    int lp0  = tile * 16;
    int tid  = threadIdx.x;

    // ---- phase A: per-(k,p) offset decode, one pair per thread (first 256)-
    if (tid < 256) {
        int pr = tid;
        int k = pr >> 4, p = pr & 15;
        int lp = lp0 + p;
        int ho = lp / WO, wo = lp - ho * WO;
        long plane = (long)HO * WO;
        const float* offn = off + (long)n * 48 * plane;
        float oy = offn[(long)k * plane + lp];
        float ox = offn[(long)(16 + k) * plane + lp];
        float mr = offn[(long)(32 + k) * plane + lp];
        float m = 1.f / (1.f + expf(-mr));
        float py = (float)(ho * 2 - 1 + (k >> 2)) + oy;
        float px = (float)(wo * 2 - 1 + (k & 3)) + ox;
        float y0f = floorf(py), x0f = floorf(px);
        float wy = py - y0f, wx = px - x0f;
        int y0 = (int)y0f, x0 = (int)x0f;
        bool yv0 = (y0 >= 0) && (y0 < HH);
        bool yv1 = (y0 + 1 >= 0) && (y0 + 1 < HH);
        bool xv0 = (x0 >= 0) && (x0 < WW);
        bool xv1 = (x0 + 1 >= 0) && (x0 + 1 < WW);
        int y0c = min(max(y0, 0), HH - 1), y1c = min(max(y0 + 1, 0), HH - 1);
        int x0c = min(max(x0, 0), WW - 1), x1c = min(max(x0 + 1, 0), WW - 1);
        tpw[pr][0] = (y0c * WW + x0c) * CIN;
        tpw[pr][1] = (y0c * WW + x1c) * CIN;
        tpw[pr][2] = (y1c * WW + x0c) * CIN;
        tpw[pr][3] = (y1c * WW + x1c) * CIN;
        tpw[pr][4] = __float_as_int((yv0 && xv0) ? (1.f - wy) * (1.f - wx) * m : 0.f);
        tpw[pr][5] = __float_as_int((yv0 && xv1) ? (1.f - wy) * wx * m : 0.f);
        tpw[pr][6] = __float_as_int((yv1 && xv0) ? wy * (1.f - wx) * m : 0.f);
        tpw[pr][7] = __float_as_int((yv1 && xv1) ? wy * wx * m : 0.f);
    }

    int wv = tid >> 6, lane = tid & 63;
    int quad = lane >> 4, l16 = lane & 15;
    int cb = (NF == 1) ? (wv * 16) : ((wv & 3) * 32 + (wv >> 2) * (COUT / 2));
    const unsigned short* xn = xcl + (long)n * HH * WW * CIN;

    f32x4 acc[NF];
    #pragma unroll
    for (int f = 0; f < NF; ++f) acc[f] = (f32x4){0.f, 0.f, 0.f, 0.f};

    for (int ch = 0; ch < NCH; ++ch) {
        __syncthreads();   // covers phase A (ch=0) and prev MFMA reads
        #pragma unroll
        for (int it = 0; it < ITER; ++it) {
            int e   = it * TPBk + tid;
            int prl = e / CH8;                  // pair within chunk
            int ci  = (e - prl * CH8) * 8;      // ci multiple of 8
            int pi  = ch * (KL * 16) + prl;
            const int4   tp4 = *(const int4*)&tpw[pi][0];
            const float4 tw4 = *(const float4*)&tpw[pi][4];
            uint4 u0 = *(const uint4*)(xn + tp4.x + ci);
            uint4 u1 = *(const uint4*)(xn + tp4.y + ci);
            uint4 u2 = *(const uint4*)(xn + tp4.z + ci);
            uint4 u3 = *(const uint4*)(xn + tp4.w + ci);
            float r[8];
            #pragma unroll
            for (int jj = 0; jj < 8; ++jj) {
                unsigned w0 = ((const unsigned*)&u0)[jj >> 1];
                unsigned w1 = ((const unsigned*)&u1)[jj >> 1];
                unsigned w2 = ((const unsigned*)&u2)[jj >> 1];
                unsigned w3 = ((const unsigned*)&u3)[jj >> 1];
                int sh = (jj & 1) << 4;
                r[jj] = tw4.x * bitsToF((unsigned short)(w0 >> sh))
                      + tw4.y * bitsToF((unsigned short)(w1 >> sh))
                      + tw4.z * bitsToF((unsigned short)(w2 >> sh))
                      + tw4.w * bitsToF((unsigned short)(w3 >> sh));
            }
            uint4 ov;
            ((unsigned*)&ov)[0] = (unsigned)fToBits(r[0]) | ((unsigned)fToBits(r[1]) << 16);
            ((unsigned*)&ov)[1] = (unsigned)fToBits(r[2]) | ((unsigned)fToBits(r[3]) << 16);
            ((unsigned*)&ov)[2] = (unsigned)fToBits(r[4]) | ((unsigned)fToBits(r[5]) << 16);
            ((unsigned*)&ov)[3] = (unsigned)fToBits(r[6]) | ((unsigned)fToBits(r[7]) << 16);
            int il = (prl >> 4) * CIN + ci;     // i within chunk [0,512)
            int p  = prl & 15;
            *(uint4*)&smp[((il >> 5) * 16 + p) * 32 + (il & 31)] = ov;
        }
        __syncthreads();
        #pragma unroll 4
        for (int kk = 0; kk < 16; ++kk) {
            bf16x8 a = *(const bf16x8*)&smp[(kk * 16 + l16) * 32 + quad * 8];
            #pragma unroll
            for (int f = 0; f < NF; ++f) {
                int co = cb + f * 16 + l16;
                bf16x8 b = *(const bf16x8*)&wb[(long)co * S + ch * 512 + kk * 32 + quad * 8];
                acc[f] = __builtin_amdgcn_mfma_f32_16x16x32_bf16(a, b, acc[f], 0, 0, 0);
            }
        }
    }

    // ---- epilogue: pixel = quad*4+reg, co = cb + f*16 + l16 ----
    if (MODE == 1) {
        unsigned short* oCL = (unsigned short*)outp;
        #pragma unroll
        for (int f = 0; f < NF; ++f) {
            int co = cb + f * 16 + l16;
            float bv = bias_f[co];
            #pragma unroll
            for (int reg = 0; reg < 4; ++reg) {
                int lp = lp0 + quad * 4 + reg;
                oCL[((long)n * HO * WO + lp) * COUT + co] = fToBits(acc[f][reg] + bv);
            }
        }
    } else {
        int bf = *dflag;
        #pragma unroll
        for (int f = 0; f < NF; ++f) {
            int co = cb + f * 16 + l16;
            float bv = bias_f[co];
            #pragma unroll
            for (int reg = 0; reg < 4; ++reg) {
                int lp = lp0 + quad * 4 + reg;
                int ho = lp / WO, wo = lp - ho * WO;
                long oi = obase + ((long)(n * COUT + co) * HO + ho) * WO + wo;
                if (bf) stT<1>(outp, oi, acc[f][reg] + bv);
                else    stT<0>(outp, oi, acc[f][reg] + bv);
            }
        }
    }
}

// ===========================================================================
// MFMA res-block 3x3 reflect conv v2 (validated round 4/8)
// ===========================================================================
__global__ __launch_bounds__(TPB) void resconv_mfma_kernel(
    const unsigned short* __restrict__ X, const unsigned short* __restrict__ W,
    const float* __restrict__ bias_f, bf16* __restrict__ Y)
{
    __shared__ __align__(16) unsigned short xs[3 * 66 * 64];   // 25344 B, swizzled
    int b = blockIdx.x;
    int coO = b & 7, r = (b >> 3) & 63, n = b >> 9;
    int t = threadIdx.x;
    int wv = t >> 6;
    int lane = t & 63;
    int quad = lane >> 4, l16 = lane & 15;
    int rows[3];
    rows[0] = (r == 0) ? 1 : r - 1;
    rows[1] = r;
    rows[2] = (r == 63) ? 62 : r + 1;

    f32x4 acc[2];
    acc[0] = (f32x4){0.f, 0.f, 0.f, 0.f};
    acc[1] = (f32x4){0.f, 0.f, 0.f, 0.f};

    long xbase = (long)n * 4096 * 256;

    for (int ci0 = 0; ci0 < 256; ci0 += 64) {
        __syncthreads();
        // stage [3ky][66col][64ci] via 16B loads; swizzled 16B slot per col
        for (int e = t; e < 3 * 66 * 8; e += TPB) {
            int oct = e & 7;
            int col = (e >> 3) % 66;
            int ky  = e / (66 * 8);
            int gx = col - 1;
            gx = (gx < 0) ? 1 : ((gx > 63) ? 62 : gx);
            bf16x8 v = *(const bf16x8*)&X[xbase + ((long)rows[ky] * 64 + gx) * 256 + ci0 + oct * 8];
            int slot = oct ^ (col & 7);
            *(bf16x8*)&xs[((ky * 66 + col) << 6) + slot * 8] = v;
        }
        __syncthreads();
        #pragma unroll
        for (int q = 0; q < 9; ++q) {
            int ky = q / 3, kx = q % 3;
            int col = wv * 16 + l16 + kx;        // lds col = global col +1
            int base = (ky * 66 + col) << 6;
            #pragma unroll
            for (int kh = 0; kh < 2; ++kh) {
                int slot = (kh * 4 + quad) ^ (col & 7);
                bf16x8 a = *(const bf16x8*)&xs[base + slot * 8];
                #pragma unroll
                for (int ct = 0; ct < 2; ++ct) {
                    int co = coO * 32 + ct * 16 + l16;
                    bf16x8 bw = *(const bf16x8*)&W[((long)q * 256 + co) * 256 + ci0 + kh * 32 + quad * 8];
                    acc[ct] = __builtin_amdgcn_mfma_f32_16x16x32_bf16(a, bw, acc[ct], 0, 0, 0);
                }
            }
        }
    }

    long ybase = ((long)n * 4096 + (long)r * 64) * 256;
    #pragma unroll
    for (int ct = 0; ct < 2; ++ct) {
        int co = coO * 32 + ct * 16 + l16;
        float bv = bias_f[co];
        #pragma unroll
        for (int reg = 0; reg < 4; ++reg) {
            int px = wv * 16 + quad * 4 + reg;
            Y[ybase + (long)px * 256 + co] = __float2bfloat16(acc[ct][reg] + bv);
        }
    }
}

// ===========================================================================
// Channels-last instance-norm: WIDE partial stats (validated round 10)
// ===========================================================================
__global__ __launch_bounds__(TPB) void cl_stats_kernel(
    const unsigned short* __restrict__ X, float* __restrict__ psum, float* __restrict__ psq)
{
    int blk = blockIdx.x;
    int chunk = blk & 63, n = blk >> 6;
    int co = threadIdx.x;
    float s = 0.f, sq = 0.f;
    const unsigned short* p = X + ((long)n * 4096 + chunk * 64) * 256 + co;
    #pragma unroll 8
    for (int i = 0; i < 64; ++i) {
        float v = bitsToF(p[(long)i * 256]);
        s += v; sq += v * v;
    }
    psum[(n * 64 + chunk) * 256 + co] = s;
    psq [(n * 64 + chunk) * 256 + co] = sq;
}

__device__ __forceinline__ void cl_load_stats(
    const float* psum, const float* psq, int n, float* mv, float* iv)
{
    int t = threadIdx.x;   // t = channel
    float s = 0.f, sq = 0.f;
    #pragma unroll 8
    for (int c = 0; c < 64; ++c) {
        s  += psum[(n * 64 + c) * 256 + t];
        sq += psq [(n * 64 + c) * 256 + t];
    }
    float mean = s / 4096.f;
    mv[t] = mean;
    iv[t] = rsqrtf(sq / 4096.f - mean * mean + 1e-5f);
    __syncthreads();
}

// grid 128 = n*64 + y; in-place X = relu?((X-m)*inv), uint-vectorized
__global__ __launch_bounds__(TPB) void cl_apply_kernel(
    unsigned short* __restrict__ X, const float* __restrict__ psum,
    const float* __restrict__ psq, int relu)
{
    __shared__ float mv[256], iv[256];
    int y = blockIdx.x & 63, n = blockIdx.x >> 6;
    cl_load_stats(psum, psq, n, mv, iv);
    unsigned* row = (unsigned*)(X + ((long)n * 4096 + y * 64) * 256);
    for (int e = threadIdx.x; e < 8192; e += TPB) {
        int co = (e * 2) & 255;
        unsigned u = row[e];
        float v0 = (bitsToF((unsigned short)(u & 0xffff)) - mv[co]) * iv[co];
        float v1 = (bitsToF((unsigned short)(u >> 16)) - mv[co + 1]) * iv[co + 1];
        if (relu) { v0 = fmaxf(v0, 0.f); v1 = fmaxf(v1, 0.f); }
        row[e] = (unsigned)fToBits(v0) | ((unsigned)fToBits(v1) << 16);
    }
}

// grid 128; H += IN(T), uint-vectorized
__global__ __launch_bounds__(TPB) void cl_apply_add_kernel(
    const unsigned short* __restrict__ T, unsigned short* __restrict__ H,
    const float* __restrict__ psum, const float* __restrict__ psq)
{
    __shared__ float mv[256], iv[256];
    int y = blockIdx.x & 63, n = blockIdx.x >> 6;
    cl_load_stats(psum, psq, n, mv, iv);
    long base = ((long)n * 4096 + y * 64) * 256;
    const unsigned* tr = (const unsigned*)(T + base);
    unsigned* hr = (unsigned*)(H + base);
    for (int e = threadIdx.x; e < 8192; e += TPB) {
        int co = (e * 2) & 255;
        unsigned ut = tr[e], uh = hr[e];
        float v0 = bitsToF((unsigned short)(uh & 0xffff))
                 + (bitsToF((unsigned short)(ut & 0xffff)) - mv[co]) * iv[co];
        float v1 = bitsToF((unsigned short)(uh >> 16))
                 + (bitsToF((unsigned short)(ut >> 16)) - mv[co + 1]) * iv[co + 1];
        hr[e] = (unsigned)fToBits(v0) | ((unsigned)fToBits(v1) << 16);
    }
}

// grid 128; out(NCHW, flag dtype) = H + IN(T)   (transposes channels-last)
__global__ __launch_bounds__(TPB) void cl_apply_final_kernel(
    const unsigned short* __restrict__ T, const unsigned short* __restrict__ H,
    void* __restrict__ outp, const float* __restrict__ psum,
    const float* __restrict__ psq, const int* __restrict__ dflag)
{
    __shared__ float mv[256], iv[256];
    int y = blockIdx.x & 63, n = blockIdx.x >> 6;
    cl_load_stats(psum, psq, n, mv, iv);
    int bf = *dflag;
    int x = threadIdx.x & 63, cg = threadIdx.x >> 6;
    for (int co = cg; co < 256; co += 4) {
        long cli = ((long)(n * 64 + y) * 64 + x) * 256 + co;
        float v = bitsToF(H[cli]) + (bitsToF(T[cli]) - mv[co]) * iv[co];
        long oi = (((long)(n * 256 + co)) * 64 + y) * 64 + x;
        if (bf) ((bf16*)outp)[oi] = __float2bfloat16(v);
        else    ((float*)outp)[oi] = v;
    }
}

// ---------------------------------------------------------------------------
extern "C" void kernel_launch(void* const* d_in, const int* in_sizes, int n_in,
                              void* d_out, int out_size, void* d_ws, size_t ws_size,
                              hipStream_t stream) {
    const void* x = d_in[0];

    const long SKIP1 = 2097152;
    const long SKIP2 = 10485760;

    int* dflag = (int*)d_ws;
    float* fw = (float*)((char*)d_ws + 64);

    unsigned short* t1 = (unsigned short*)(fw + FB);
    unsigned short* t2 = (unsigned short*)(fw + FB + 1048576);
    unsigned short* h3 = (unsigned short*)(fw + H3F);
    float* offb = fw + OFFB;
    unsigned short* x4 = (unsigned short*)(fw + OFFB);   // layer-1 only; dead after
    float* psum = fw + PST1;
    float* psq  = fw + PST2;
    unsigned short* clbuf = (unsigned short*)(fw + CLBUF);    // skip1_cl then skip2_cl
    const unsigned short* wb1o = (const unsigned short*)(fw + WB1OT);
    const unsigned short* wb1d = (const unsigned short*)(fw + WB1DT);
    const unsigned short* wb2o = (const unsigned short*)(fw + WO2T);
    const unsigned short* wb3o = (const unsigned short*)(fw + WO3T);
    const unsigned short* wb2 = (const unsigned short*)(fw + WB2T);
    const unsigned short* wb3 = (const unsigned short*)(fw + WB3T);
    const unsigned short* rbw1 = (const unsigned short*)(fw + RB1W1T);
    const unsigned short* rbw2 = (const unsigned short*)(fw + RB1W2T);
    const unsigned short* rbw3 = (const unsigned short*)(fw + RB2W1T);
    const unsigned short* rbw4 = (const unsigned short*)(fw + RB2W2T);

    detect_kernel<<<1, 64, 0, stream>>>(x, dflag);

    // ---- weight/bias repack ----
    PtrPack pp;
    for (int i = 0; i < 10; ++i) pp.p[i] = nullptr;
    pp.p[10] = d_in[2];  pp.p[11] = d_in[4];  pp.p[12] = d_in[6];  pp.p[13] = d_in[8];
    pp.p[14] = d_in[10]; pp.p[15] = d_in[12]; pp.p[16] = d_in[14]; pp.p[17] = d_in[16];
    pp.p[18] = d_in[18]; pp.p[19] = d_in[20];
    repack_all_kernel<<<2, TPB, 0, stream>>>(pp, fw, dflag);
    repack_dcn_kernel<<<867, TPB, 0, stream>>>(
        d_in[7], d_in[11], d_in[1], d_in[3], d_in[5], d_in[9], fw, dflag);
    RbPack rp;
    rp.src[0] = d_in[13]; rp.src[1] = d_in[15]; rp.src[2] = d_in[17]; rp.src[3] = d_in[19];
    repack_rb_kernel<<<256, TPB, 0, stream>>>(rp, fw, dflag);

    // ---- Layer 1 fused MFMA: offsets + deform, 7x7 s1 p3 ----
    x_to_cl4_kernel<<<512, TPB, 0, stream>>>(x, x4, dflag);
    layer1_mfma_kernel<<<4096, TPB, 0, stream>>>(
        x4, wb1o, wb1d, fw + OFF1B, fw + DCN1B, d_out, SKIP1, dflag);
    // skip1 IN: wide partial stats + fused apply/transpose (writes d_out + clbuf)
    nchw_stats_kernel<64, 65536><<<1024, TPB, 0, stream>>>(d_out, SKIP1, dflag, psum, psq);
    nchw_to_cl_norm_kernel<64, 65536><<<2048, TPB, 0, stream>>>(
        d_out, SKIP1, clbuf, psum, psq, dflag);

    // ---- Layer 2: 4x4 s2 p1, Cin=64 ----
    offconv_mfma_kernel<64, 256, 256, 128, 128><<<2048, TPB, 0, stream>>>(
        clbuf, wb2o, fw + OFF2B, offb);
    deform_mfma_kernel<0, 64, 128, 8, 256, 256, 128, 128><<<2048, 512, 0, stream>>>(
        clbuf, offb, wb2, fw + DCN2B, d_out, SKIP2, dflag);
    // skip2 IN: wide partial stats + fused apply/transpose (reuses clbuf)
    nchw_stats_kernel<128, 16384><<<2048, TPB, 0, stream>>>(d_out, SKIP2, dflag, psum, psq);
    nchw_to_cl_norm_kernel<128, 16384><<<512, TPB, 0, stream>>>(
        d_out, SKIP2, clbuf, psum, psq, dflag);

    // ---- Layer 3: 4x4 s2 p1, Cin=128; output bf16 channels-last h3 ----
    offconv_mfma_kernel<128, 128, 128, 64, 64><<<512, TPB, 0, stream>>>(
        clbuf, wb3o, fw + OFF3B, offb);
    deform_mfma_kernel<1, 128, 256, 8, 128, 128, 64, 64><<<512, 512, 0, stream>>>(
        clbuf, offb, wb3, fw + DCN3B, h3, 0, dflag);
    cl_stats_kernel<<<128, TPB, 0, stream>>>(h3, psum, psq);
    cl_apply_kernel<<<128, TPB, 0, stream>>>(h3, psum, psq, 1);

    // ---- Res block 1 (MFMA) ----
    resconv_mfma_kernel<<<1024, TPB, 0, stream>>>(h3, rbw1, fw + RB1B1, (bf16*)t1);
    cl_stats_kernel<<<128, TPB, 0, stream>>>(t1, psum, psq);
    cl_apply_kernel<<<128, TPB, 0, stream>>>(t1, psum, psq, 1);
    resconv_mfma_kernel<<<1024, TPB, 0, stream>>>(t1, rbw2, fw + RB1B2, (bf16*)t2);
    cl_stats_kernel<<<128, TPB, 0, stream>>>(t2, psum, psq);
    cl_apply_add_kernel<<<128, TPB, 0, stream>>>(t2, h3, psum, psq);

    // ---- Res block 2 (MFMA; final writes NCHW d_out per flag) ----
    resconv_mfma_kernel<<<1024, TPB, 0, stream>>>(h3, rbw3, fw + RB2B1, (bf16*)t1);
    cl_stats_kernel<<<128, TPB, 0, stream>>>(t1, psum, psq);
    cl_apply_kernel<<<128, TPB, 0, stream>>>(t1, psum, psq, 1);
    resconv_mfma_kernel<<<1024, TPB, 0, stream>>>(t1, rbw4, fw + RB2B2, (bf16*)t2);
    cl_stats_kernel<<<128, TPB, 0, stream>>>(t2, psum, psq);
    cl_apply_final_kernel<<<128, TPB, 0, stream>>>(t2, h3, d_out, psum, psq, dflag);
}